// Round 4
// baseline (936.534 us; speedup 1.0000x reference)
//
#include <hip/hip_runtime.h>
#include <math.h>

constexpr int kDM   = 512;
constexpr int kDI   = 1024;
constexpr int kDS   = 16;
constexpr int kDC   = 4;
constexpr int kDTR  = 32;
constexpr int kL    = 2;
constexpr int kB    = 4;
constexpr int kN    = 1024;
constexpr int kB2   = 8;              // combined batch: rows 0-3 fwd, 4-7 bwd
constexpr int kROWS = kB2 * kN;       // 8192
constexpr int kMDIR = kB * kN;        // 4096 rows per direction

enum { EPI_NONE=0, EPI_SOFTPLUS=1, EPI_RESID=2, EPI_GELU=3, EPI_RESID_BIAS=4, EPI_TANH=5 };
enum { MODE_N=0, MODE_OTR=1, MODE_DBL=2, MODE_GATE=3 };

typedef __attribute__((ext_vector_type(8))) short bf16x8;
typedef __attribute__((ext_vector_type(4))) short bf16x4;
typedef __attribute__((ext_vector_type(4))) float f32x4;

__device__ __forceinline__ unsigned short f2bf(float f) {
    unsigned int u = __float_as_uint(f);
    return (unsigned short)((u + 0x7FFFu + ((u >> 16) & 1u)) >> 16);
}
__device__ __forceinline__ float b2f(unsigned short u) {
    return __uint_as_float((unsigned int)u << 16);
}
__device__ __forceinline__ float bflo(unsigned int u) {          // low bf16 -> f32
    return __uint_as_float(u << 16);
}
__device__ __forceinline__ float bfhi(unsigned int u) {          // high bf16 -> f32
    return __uint_as_float(u & 0xffff0000u);
}
__device__ __forceinline__ bf16x4 pack4(const float* v) {
    union { unsigned short u[4]; bf16x4 t; } p;
#pragma unroll
    for (int j = 0; j < 4; j++) p.u[j] = f2bf(v[j]);
    return p.t;
}
__device__ __forceinline__ unsigned int u4c(const uint4 v, int i) {
    return i == 0 ? v.x : i == 1 ? v.y : i == 2 ? v.z : v.w;
}

// ------------------------------------------------------- weight prep --------
// Convert all GEMM weights fp32 [L][K][N] -> bf16 [L][N][K] (transposed) so
// the GEMM B-staging is contiguous 16-B bf16 loads with zero conversion math.
struct WJobs { const float* s[13]; };
// job order: f_inw b_inw f_xpw b_xpw f_dtw b_dtw f_ow b_ow f_w1 b_w1 f_w2 b_w2 aw1
constexpr size_t O_INW_F = 0;
constexpr size_t O_INW_B = O_INW_F + 2u*512*2048;
constexpr size_t O_XPW_F = O_INW_B + 2u*512*2048;
constexpr size_t O_XPW_B = O_XPW_F + 2u*1024*64;
constexpr size_t O_DTW_F = O_XPW_B + 2u*1024*64;
constexpr size_t O_DTW_B = O_DTW_F + 2u*32*1024;
constexpr size_t O_OW_F  = O_DTW_B + 2u*32*1024;
constexpr size_t O_OW_B  = O_OW_F  + 2u*1024*512;
constexpr size_t O_W1_F  = O_OW_B  + 2u*1024*512;
constexpr size_t O_W1_B  = O_W1_F  + 2u*512*2048;
constexpr size_t O_W2_F  = O_W1_B  + 2u*512*2048;
constexpr size_t O_W2_B  = O_W2_F  + 2u*2048*512;
constexpr size_t O_AW1   = O_W2_B  + 2u*2048*512;
constexpr size_t O_WTOT  = O_AW1   + 1u*512*256;

__global__ __launch_bounds__(256) void wprep_k(WJobs jobs, unsigned short* __restrict__ dst)
{
    const int wK[13] = {512,512,1024,1024,32,32,1024,1024,512,512,2048,2048,512};
    const int wN[13] = {2048,2048,64,64,1024,1024,512,512,2048,2048,512,512,256};
    const int wL[13] = {2,2,2,2,2,2,2,2,2,2,2,2,1};
    int blk = blockIdx.x;
    int j = 0; int base = 0; size_t doff = 0;
    for (; j < 13; j++) {
        int nb = wL[j] * (wK[j] / 32) * (wN[j] / 32);
        if (blk < base + nb) break;
        base += nb;
        doff += (size_t)wL[j] * wK[j] * wN[j];
    }
    int rel = blk - base;
    int K = wK[j], N = wN[j];
    int tk = K / 32, tn = N / 32;
    int l = rel / (tk * tn); rel -= l * tk * tn;
    int kt = rel / tn, nt = rel - (rel / tn) * tn;
    const float* src = jobs.s[j] + (size_t)l * K * N;
    unsigned short* d = dst + doff + (size_t)l * K * N;
    __shared__ float tl[32][33];
    const int c = threadIdx.x & 31, rg = threadIdx.x >> 5;
#pragma unroll
    for (int rr = 0; rr < 4; rr++)
        tl[rg * 4 + rr][c] = src[(size_t)(kt * 32 + rg * 4 + rr) * N + nt * 32 + c];
    __syncthreads();
#pragma unroll
    for (int rr = 0; rr < 4; rr++)
        d[(size_t)(nt * 32 + rg * 4 + rr) * K + kt * 32 + c] = f2bf(tl[c][rg * 4 + rr]);
}

// ---------------------------------------------------------------- init h ----
__global__ __launch_bounds__(256) void init_h_k(const float* __restrict__ x,
                                                float* __restrict__ h)
{
    size_t idx = (size_t)blockIdx.x * 256 + threadIdx.x;   // kROWS*kDM
    int d  = idx & (kDM - 1);
    int t  = (idx >> 9) & (kN - 1);
    int bb = (int)(idx >> 19);
    int b = bb & 3, dir = bb >> 2;
    int ts = dir ? (kN - 1 - t) : t;
    h[idx] = x[((size_t)b * kN + ts) * kDM + d];
}

__global__ __launch_bounds__(256) void h2b_k(const float* __restrict__ h,
                                             unsigned short* __restrict__ o)
{
    size_t idx = (size_t)blockIdx.x * 256 + threadIdx.x;
    o[idx] = f2bf(h[idx]);
}

// ---------------------------------------------------------------- layernorm --
template<int DIM, int OBF>
__global__ __launch_bounds__(256) void ln_k(const float* __restrict__ x,
    const float* __restrict__ wf, const float* __restrict__ wb,
    const float* __restrict__ bf, const float* __restrict__ bbp,
    void* __restrict__ outv)
{
    const int row = blockIdx.x;
    const int tid = threadIdx.x;
    constexpr int PT = DIM / 256;
    const int dir = (row >= kMDIR) ? 1 : 0;
    const float* w = dir ? wb : wf;
    const float* b = dir ? bbp : bf;

    float v[PT];
    float s1 = 0.f, s2 = 0.f;
#pragma unroll
    for (int i = 0; i < PT; i++) {
        float t = x[(size_t)row * DIM + tid + i * 256];
        v[i] = t; s1 += t; s2 += t * t;
    }
    for (int o = 32; o > 0; o >>= 1) { s1 += __shfl_xor(s1, o, 64); s2 += __shfl_xor(s2, o, 64); }
    __shared__ float r1[4], r2[4];
    int wv = tid >> 6;
    if ((tid & 63) == 0) { r1[wv] = s1; r2[wv] = s2; }
    __syncthreads();
    s1 = r1[0] + r1[1] + r1[2] + r1[3];
    s2 = r2[0] + r2[1] + r2[2] + r2[3];
    float mu  = s1 / DIM;
    float var = s2 / DIM - mu * mu;
    float rr  = rsqrtf(var + 1e-5f);
#pragma unroll
    for (int i = 0; i < PT; i++) {
        int c = tid + i * 256;
        float o = (v[i] - mu) * rr * w[c] + b[c];
        if (OBF) ((unsigned short*)outv)[(size_t)row * DIM + c] = f2bf(o);
        else     ((float*)outv)[(size_t)row * DIM + c] = o;
    }
}

// ---------------------------------------------------------------- MFMA GEMM -
// C = A @ B (+bias)(+epilogue). A bf16 [M][lda] (ATR=1: At[K][lda]),
// B^T bf16 [N][K] (pre-transposed weights).
// KB = K staged per barrier pair (32 or 64). MODE_DBL: cols>=32 also written
// as f32 to dblF [row][32] (B/C streams for the blocked scan).
template<int BM, int BN, int EPI, int ATR, int MODE, int OBF, int KB>
__global__ __launch_bounds__(256) void gemm_mfma(
    const unsigned short* __restrict__ A, int lda, int K,
    const unsigned short* __restrict__ Btf, const unsigned short* __restrict__ Btb,
    const float* __restrict__ biasf, const float* __restrict__ biasb,
    void* __restrict__ Cv, int ldc, unsigned short* __restrict__ Ct)
{
    constexpr int SK  = 40;              // padded LDS row stride (bf16 elems)
    constexpr int KT  = KB / 32;         // 32-wide sub-tiles per stage
    constexpr int CPR = KB / 8;          // 8-elem chunks per row
    constexpr int WM  = BM / 2, WN = BN / 2;
    constexpr int MT  = WM / 16, NT = WN / 16;
    constexpr int ASL = (BM * KB) / (256 * 8);
    constexpr int BSL = (BN * KB) / (256 * 8);
    constexpr int MB4 = BM / 4;
    constexpr int ATR_TH = (BM / 4) * (KB / 4);
    constexpr int ATR_R  = (ATR_TH + 255) / 256;

    __shared__ unsigned short As[KT * BM * SK];
    __shared__ unsigned short Bs[KT * BN * SK];

    const int tid  = threadIdx.x;
    const int n0   = blockIdx.x * BN;
    const int row0 = blockIdx.y * BM;
    const int dir  = (row0 >= kMDIR) ? 1 : 0;
    const unsigned short* __restrict__ Bt = dir ? Btb : Btf;
    const float* bias = dir ? biasb : biasf;

    const int lane = tid & 63;
    const int wave = tid >> 6;
    const int wr = wave >> 1, wc = wave & 1;
    const int ml = lane & 15, q = lane >> 4;

    f32x4 acc[MT][NT];
#pragma unroll
    for (int i = 0; i < MT; i++)
#pragma unroll
        for (int j = 0; j < NT; j++)
#pragma unroll
            for (int r = 0; r < 4; r++) acc[i][j][r] = 0.f;

    for (int kt = 0; kt < K; kt += KB) {
        // ---- global loads ----
        bf16x8 a_ld[ASL ? ASL : 1];
        bf16x4 at_ld[ATR_R][4];
        if (!ATR) {
#pragma unroll
            for (int r = 0; r < ASL; r++) {
                int i = tid + r * 256;
                int m = i / CPR, c8 = (i % CPR) * 8;
                a_ld[r] = *(const bf16x8*)(A + (size_t)(row0 + m) * lda + kt + c8);
            }
        } else {
#pragma unroll
            for (int r = 0; r < ATR_R; r++) {
                int idx = tid + r * 256;
                if (idx < ATR_TH) {
                    int mb = idx % MB4, ka = idx / MB4;
#pragma unroll
                    for (int j = 0; j < 4; j++)
                        at_ld[r][j] = *(const bf16x4*)(A + (size_t)(kt + ka * 4 + j) * lda + row0 + mb * 4);
                }
            }
        }
        bf16x8 b_ld[BSL ? BSL : 1];
#pragma unroll
        for (int r = 0; r < BSL; r++) {
            int i = tid + r * 256;
            int n = i / CPR, c8 = (i % CPR) * 8;
            b_ld[r] = *(const bf16x8*)(Bt + (size_t)(n0 + n) * K + kt + c8);
        }
        __syncthreads();     // previous iteration's LDS reads complete
        // ---- LDS writes ----
        if (!ATR) {
#pragma unroll
            for (int r = 0; r < ASL; r++) {
                int i = tid + r * 256;
                int m = i / CPR, c8 = (i % CPR) * 8;
                *(bf16x8*)&As[((c8 >> 5) * BM + m) * SK + (c8 & 31)] = a_ld[r];
            }
        } else {
#pragma unroll
            for (int r = 0; r < ATR_R; r++) {
                int idx = tid + r * 256;
                if (idx < ATR_TH) {
                    int mb = idx % MB4, ka = idx / MB4;
                    union { bf16x4 v; unsigned short u[4]; } rw4[4];
#pragma unroll
                    for (int j = 0; j < 4; j++) rw4[j].v = at_ld[r][j];
                    int col = ka * 4;
#pragma unroll
                    for (int mp = 0; mp < 4; mp++) {
                        union { unsigned short u[4]; bf16x4 v; } cl;
#pragma unroll
                        for (int j = 0; j < 4; j++) cl.u[j] = rw4[j].u[mp];
                        *(bf16x4*)&As[((col >> 5) * BM + mb * 4 + mp) * SK + (col & 31)] = cl.v;
                    }
                }
            }
        }
#pragma unroll
        for (int r = 0; r < BSL; r++) {
            int i = tid + r * 256;
            int n = i / CPR, c8 = (i % CPR) * 8;
            *(bf16x8*)&Bs[((c8 >> 5) * BN + n) * SK + (c8 & 31)] = b_ld[r];
        }
        __syncthreads();
        // ---- fragments + MFMA (KT sub-steps of K=32) ----
#pragma unroll
        for (int kk = 0; kk < KT; kk++) {
            bf16x8 af[MT], bfr[NT];
#pragma unroll
            for (int i = 0; i < MT; i++)
                af[i] = *(bf16x8*)&As[(kk * BM + wr * WM + i * 16 + ml) * SK + q * 8];
#pragma unroll
            for (int j = 0; j < NT; j++)
                bfr[j] = *(bf16x8*)&Bs[(kk * BN + wc * WN + j * 16 + ml) * SK + q * 8];
#pragma unroll
            for (int i = 0; i < MT; i++)
#pragma unroll
                for (int j = 0; j < NT; j++)
                    acc[i][j] = __builtin_amdgcn_mfma_f32_16x16x32_bf16(af[i], bfr[j], acc[i][j], 0, 0, 0);
        }
    }

    // ---- epilogue ----
    float* Cf = (float*)Cv;
    unsigned short* Cb = (unsigned short*)Cv;
#pragma unroll
    for (int j = 0; j < NT; j++) {
        int col = n0 + wc * WN + j * 16 + ml;
        float bv = 0.f;
        if (EPI == EPI_SOFTPLUS || EPI == EPI_GELU || EPI == EPI_RESID_BIAS || EPI == EPI_TANH)
            bv = bias[col];
#pragma unroll
        for (int i = 0; i < MT; i++) {
            int rw = row0 + wr * WM + i * 16 + q * 4;
            float v4[4];
#pragma unroll
            for (int r = 0; r < 4; r++) {
                float v = acc[i][j][r] + bv;
                if (EPI == EPI_SOFTPLUS) v = (v > 20.f) ? v : __logf(1.f + __expf(v));
                if (EPI == EPI_GELU)     v = 0.5f * v * (1.f + erff(v * 0.70710678118654752f));
                if (EPI == EPI_TANH)     v = tanhf(v);
                v4[r] = v;
            }
            if (MODE == MODE_OTR) {
                *(bf16x4*)&Ct[(size_t)col * kROWS + rw] = pack4(v4);
            } else if (MODE == MODE_GATE && n0 >= kDI) {
#pragma unroll
                for (int r = 0; r < 4; r++) v4[r] = v4[r] / (1.f + __expf(-v4[r]));
                *(bf16x4*)&Ct[(size_t)(col - kDI) * kROWS + rw] = pack4(v4);
            } else {
#pragma unroll
                for (int r = 0; r < 4; r++) {
                    size_t o = (size_t)(rw + r) * ldc + col;
                    if (EPI == EPI_RESID || EPI == EPI_RESID_BIAS) Cf[o] += v4[r];
                    else if (OBF) Cb[o] = f2bf(v4[r]);
                    else Cf[o] = v4[r];
                }
                if (MODE == MODE_DBL && col >= 32) {
                    float* F = (float*)Ct;          // dblF f32 [row][32]
#pragma unroll
                    for (int r = 0; r < 4; r++)
                        F[(size_t)(rw + r) * 32 + (col - 32)] = v4[r];
                }
            }
        }
    }
}

// ---------------------------------------------------------------- conv ------
// xb bf16 [row][kDI] (x-half) -> xhT bf16 [d][row] = silu(causal conv + cb).
__global__ __launch_bounds__(256) void conv_t_k(const unsigned short* __restrict__ xb,
    const float* __restrict__ cwf, const float* __restrict__ cwb,
    const float* __restrict__ cbf, const float* __restrict__ cbb,
    unsigned short* __restrict__ xhT)
{
    __shared__ float tl[67][33];
    const int t0 = blockIdx.x * 64, d0 = blockIdx.y * 32, bb = blockIdx.z;
    const int dir = bb >> 2;
    const float* cw = dir ? cwb : cwf;
    const float* cb = dir ? cbb : cbf;
    const int dl = threadIdx.x & 31, rl = threadIdx.x >> 5;
    const size_t base = (size_t)bb * kN * kDI + d0 + dl;
#pragma unroll
    for (int p = 0; p < 9; p++) {
        int r = p * 8 + rl;
        if (r < 67) {
            int ts = t0 + r - 3;
            tl[r][dl] = (ts >= 0) ? b2f(xb[base + (size_t)ts * kDI]) : 0.f;
        }
    }
    __syncthreads();
    const int gd = d0 + dl;
    float c0 = cw[gd*4+0], c1 = cw[gd*4+1], c2 = cw[gd*4+2], c3 = cw[gd*4+3];
    float bv = cb[gd];
    float o[8];
#pragma unroll
    for (int jj = 0; jj < 8; jj++) {
        int tt = rl + 8 * jj;
        float acc = bv + c0*tl[tt][dl] + c1*tl[tt+1][dl] + c2*tl[tt+2][dl] + c3*tl[tt+3][dl];
        o[jj] = acc / (1.f + __expf(-acc));
    }
    __syncthreads();
#pragma unroll
    for (int jj = 0; jj < 8; jj++) tl[rl + 8 * jj][dl] = o[jj];
    __syncthreads();
    const int tb = threadIdx.x & 63, dg = threadIdx.x >> 6;
#pragma unroll
    for (int dd = 0; dd < 8; dd++) {
        int d2 = dg * 8 + dd;
        xhT[(size_t)(d0 + d2) * kROWS + (size_t)bb * kN + t0 + tb] = f2bf(tl[tb][d2]);
    }
}

// ---------------------------------------------------------------- scan ------
// r13: s-in-registers blocked (chunked) scan.
// Three rounds of counters showed the lane-parallel-s layout costs 32-46
// VALU inst per (t,s) element (16 s-lanes redundantly process d-shared
// values + DPP sums + unpack/select overhead) for a 5-op core. This layout
// puts all 16 s-states of a chain in one thread (h[16] in VGPRs): core per
// t = 16x(mul,exp2,mul-fma) + 16 in-thread fmas for the C-dot = ~6 inst per
// (t,s). Occupancy comes from chunking t: G=32 groups/chain (r9's s-folded
// failure was 512 waves; this gives 8*32*4=1024 blocks = 4096 waves).
//   pass A (PASS=0): per-group local scan from h=0; store P_s=exp2(a2_s*sum
//     dt) and local L_s=h into PL[bb][g][d][0..15 | 16..31].
//   pass B (bfix_k): per (chain,s): 32 sequential boundary fmas; rewrites
//     the L slot with h_in (full-prefix state at group start).
//   pass C (PASS=1): recompute from h_in, full y output. ~2x arithmetic
//     total but ~7x fewer instructions per element -> net ~3.5x.
// B/C come from dblF f32 [row][32] (written by the xpw GEMM epilogue):
// wave-uniform address -> broadcast loads, L1/K$-resident (1 MB).
constexpr int kG  = 32;           // groups per chain
constexpr int kTg = kN / kG;      // 32 timesteps per group

template<int PASS>
__global__ __launch_bounds__(256) void bscan_k(
    const unsigned short* __restrict__ dtT, const unsigned short* __restrict__ xhT,
    const unsigned short* __restrict__ gateT, const float* __restrict__ dblF,
    unsigned short* __restrict__ yT, float* __restrict__ PL,
    const float* __restrict__ alogf, const float* __restrict__ alogb,
    const float* __restrict__ ddf,   const float* __restrict__ ddb)
{
    const int d  = blockIdx.x * 256 + threadIdx.x;   // 0..1023
    const int g  = blockIdx.y;                       // 0..31
    const int bb = blockIdx.z;                       // 0..7
    const int dir = bb >> 2;
    const float* alog = dir ? alogb : alogf;
    const float* ddp  = dir ? ddb  : ddf;

    float a2[16];
#pragma unroll
    for (int s = 0; s < 16; s += 4) {
        float4 al = *(const float4*)&alog[d * kDS + s];
        a2[s+0] = -__expf(al.x) * 1.44269504f;
        a2[s+1] = -__expf(al.y) * 1.44269504f;
        a2[s+2] = -__expf(al.z) * 1.44269504f;
        a2[s+3] = -__expf(al.w) * 1.44269504f;
    }

    const size_t plbase = ((size_t)(bb * kG + g) * kDI + d) * 32;
    float h[16];
    if (PASS == 0) {
#pragma unroll
        for (int s = 0; s < 16; s++) h[s] = 0.f;
    } else {
#pragma unroll
        for (int s = 0; s < 16; s += 4) {
            float4 t = *(const float4*)&PL[plbase + 16 + s];
            h[s] = t.x; h[s+1] = t.y; h[s+2] = t.z; h[s+3] = t.w;
        }
    }

    const size_t rowbase = (size_t)bb * kN + g * kTg;
    const unsigned short* p_dt = dtT   + (size_t)d * kROWS + rowbase;
    const unsigned short* p_xv = xhT   + (size_t)d * kROWS + rowbase;
    const unsigned short* p_gv = gateT + (size_t)d * kROWS + rowbase;
    const float* p_bc = dblF + rowbase * 32;
    unsigned short* p_y = yT + (size_t)d * kROWS + rowbase;
    const float ddv = (PASS == 1) ? ddp[d] : 0.f;
    float sdt = 0.f;

    for (int t8 = 0; t8 < kTg; t8 += 8) {
        uint4 dt8 = *(const uint4*)(p_dt + t8);
        uint4 xv8 = *(const uint4*)(p_xv + t8);
        uint4 gv8 = make_uint4(0, 0, 0, 0);
        if (PASS == 1) gv8 = *(const uint4*)(p_gv + t8);
        uint4 yw = make_uint4(0, 0, 0, 0);
#pragma unroll
        for (int tt = 0; tt < 8; tt++) {
            unsigned int du = u4c(dt8, tt >> 1);
            unsigned int xu = u4c(xv8, tt >> 1);
            float dtv = (tt & 1) ? bfhi(du) : bflo(du);
            float xvv = (tt & 1) ? bfhi(xu) : bflo(xu);
            float dtx = dtv * xvv;
            const float* bc = p_bc + (size_t)(t8 + tt) * 32;
            float Bv[16];
            *(float4*)&Bv[0]  = *(const float4*)(bc + 0);
            *(float4*)&Bv[4]  = *(const float4*)(bc + 4);
            *(float4*)&Bv[8]  = *(const float4*)(bc + 8);
            *(float4*)&Bv[12] = *(const float4*)(bc + 12);
            if (PASS == 0) {
                sdt += dtv;
#pragma unroll
                for (int s = 0; s < 16; s++)
                    h[s] = __builtin_amdgcn_exp2f(dtv * a2[s]) * h[s] + dtx * Bv[s];
            } else {
                float Cv[16];
                *(float4*)&Cv[0]  = *(const float4*)(bc + 16);
                *(float4*)&Cv[4]  = *(const float4*)(bc + 20);
                *(float4*)&Cv[8]  = *(const float4*)(bc + 24);
                *(float4*)&Cv[12] = *(const float4*)(bc + 28);
                float p = 0.f;
#pragma unroll
                for (int s = 0; s < 16; s++) {
                    h[s] = __builtin_amdgcn_exp2f(dtv * a2[s]) * h[s] + dtx * Bv[s];
                    p += h[s] * Cv[s];
                }
                unsigned int gu = u4c(gv8, tt >> 1);
                float gvv = (tt & 1) ? bfhi(gu) : bflo(gu);
                float yv = (p + ddv * xvv) * gvv;
                unsigned int yb = (unsigned int)f2bf(yv);
                if (tt == 0) yw.x  = yb;        else if (tt == 1) yw.x |= yb << 16;
                else if (tt == 2) yw.y  = yb;   else if (tt == 3) yw.y |= yb << 16;
                else if (tt == 4) yw.z  = yb;   else if (tt == 5) yw.z |= yb << 16;
                else if (tt == 6) yw.w  = yb;   else              yw.w |= yb << 16;
            }
        }
        if (PASS == 1) *(uint4*)(p_y + t8) = yw;
    }

    if (PASS == 0) {
#pragma unroll
        for (int s = 0; s < 16; s += 4) {
            float4 P4;
            P4.x = __builtin_amdgcn_exp2f(a2[s+0] * sdt);
            P4.y = __builtin_amdgcn_exp2f(a2[s+1] * sdt);
            P4.z = __builtin_amdgcn_exp2f(a2[s+2] * sdt);
            P4.w = __builtin_amdgcn_exp2f(a2[s+3] * sdt);
            *(float4*)&PL[plbase + s] = P4;
            *(float4*)&PL[plbase + 16 + s] = make_float4(h[s], h[s+1], h[s+2], h[s+3]);
        }
    }
}

// boundary fix: h_in[chain][g] = scan of (P,L) over groups; rewrites L slot.
__global__ __launch_bounds__(256) void bfix_k(float* __restrict__ PL)
{
    const int idx = blockIdx.x * 256 + threadIdx.x;  // kB2*kDI*kDS = 131072
    const int s  = idx & 15;
    const int cb = idx >> 4;                         // chain: bb*kDI + d
    const int d  = cb & (kDI - 1), bb = cb >> 10;
    float h = 0.f;
    for (int g = 0; g < kG; g++) {
        size_t base = ((size_t)(bb * kG + g) * kDI + d) * 32;
        float P = PL[base + s];
        float L = PL[base + 16 + s];
        PL[base + 16 + s] = h;       // h_in for pass C
        h = P * h + L;
    }
}

// ---------------------------------------------------------------- attention -
__global__ __launch_bounds__(64) void att_score_k(const unsigned short* __restrict__ tmp,
    const float* __restrict__ aw2, const float* __restrict__ ab2,
    float* __restrict__ score)
{
    int row = blockIdx.x, lane = threadIdx.x;
    float acc = 0.f;
#pragma unroll
    for (int j = 0; j < 4; j++)
        acc += b2f(tmp[(size_t)row * 256 + lane + j * 64]) * aw2[lane + j * 64];
    for (int o = 32; o > 0; o >>= 1) acc += __shfl_xor(acc, o, 64);
    if (lane == 0) score[row] = acc + ab2[0];
}

__global__ __launch_bounds__(256) void softmax_k(const float* __restrict__ score,
                                                 float* __restrict__ w)
{
    int bb = blockIdx.x, tid = threadIdx.x;
    float v[4]; float m = -1e30f;
#pragma unroll
    for (int i = 0; i < 4; i++) { v[i] = score[bb * kN + tid + i * 256]; m = fmaxf(m, v[i]); }
    for (int o = 32; o > 0; o >>= 1) m = fmaxf(m, __shfl_xor(m, o, 64));
    __shared__ float r1[4], r2[4];
    int wv = tid >> 6;
    if ((tid & 63) == 0) r1[wv] = m;
    __syncthreads();
    m = fmaxf(fmaxf(r1[0], r1[1]), fmaxf(r1[2], r1[3]));
    float s = 0.f;
#pragma unroll
    for (int i = 0; i < 4; i++) { v[i] = __expf(v[i] - m); s += v[i]; }
    for (int o = 32; o > 0; o >>= 1) s += __shfl_xor(s, o, 64);
    if ((tid & 63) == 0) r2[wv] = s;
    __syncthreads();
    s = r2[0] + r2[1] + r2[2] + r2[3];
    float inv = 1.f / s;
#pragma unroll
    for (int i = 0; i < 4; i++) w[bb * kN + tid + i * 256] = v[i] * inv;
}

__global__ __launch_bounds__(512) void pool_k(const float* __restrict__ w,
    const float* __restrict__ h, float* zcat)
{
    int bb = blockIdx.x, chunk = blockIdx.y;   // 8 x 32
    int d = threadIdx.x;
    float acc = 0.f;
    int n0 = chunk * 32;
    for (int n = n0; n < n0 + 32; n++)
        acc += w[bb * kN + n] * h[((size_t)bb * kN + n) * kDM + d];
    int b = bb & 3, dir = bb >> 2;
    atomicAdd(&zcat[b * (2 * kDM) + dir * kDM + d], acc);
}

__global__ __launch_bounds__(256) void att_out_k(const float* __restrict__ w,
                                                 float* __restrict__ out)
{
    int idx = blockIdx.x * 256 + threadIdx.x;  // kB*kN
    int b = idx >> 10, n = idx & 1023;
    out[idx] = 0.5f * (w[b * kN + n] + w[(b + 4) * kN + (kN - 1 - n)]);
}

// ---------------------------------------------------------------- launch ----
extern "C" void kernel_launch(void* const* d_in, const int* in_sizes, int n_in,
                              void* d_out, int out_size, void* d_ws, size_t ws_size,
                              hipStream_t stream)
{
    const float* x = (const float*)d_in[0];
    const float* fp[17]; const float* bp[17];
    for (int i = 0; i < 17; i++) { fp[i] = (const float*)d_in[1 + i]; bp[i] = (const float*)d_in[18 + i]; }
    const float* aw1 = (const float*)d_in[35];
    const float* ab1 = (const float*)d_in[36];
    const float* aw2 = (const float*)d_in[37];
    const float* ab2 = (const float*)d_in[38];
    const float* nw  = (const float*)d_in[39];
    const float* nb  = (const float*)d_in[40];
    float* out = (float*)d_out;

    float* h = (float*)d_ws;                                   // 8192*512 f32
    unsigned short* ub    = (unsigned short*)(h + (size_t)kROWS * kDM);  // 8192*512
    unsigned short* xbuf  = ub    + (size_t)kROWS * kDM;        // 8192*1024 (x-half / yT / ffn1 lo)
    unsigned short* tbuf  = xbuf  + (size_t)kROWS * kDI;        // 8192*1024 (dtT / ffn1 hi / hb)
    unsigned short* xhT   = tbuf  + (size_t)kROWS * kDI;        // 1024*8192
    unsigned short* gateT = xhT   + (size_t)kROWS * kDI;        // 1024*8192
    unsigned short* dbl   = gateT + (size_t)kROWS * kDI;        // 8192*64 bf16
    float* dblF  = (float*)(dbl + (size_t)kROWS * 64);          // 8192*32 f32 (B/C)
    float* score = dblF + (size_t)kROWS * 32;                   // 8192
    float* smw   = score + kROWS;                               // 8192
    float* zcat  = smw   + kROWS;                               // 4096
    unsigned short* wts  = (unsigned short*)(zcat + kB * 2 * kDM);
    float* PL = (float*)(wts + O_WTOT);                         // 8*32*1024*32 f32 = 32MB

    // ---- weight prep: fp32 [L][K][N] -> bf16 [L][N][K] (one launch) ----
    WJobs jobs;
    jobs.s[0] = fp[2];  jobs.s[1] = bp[2];
    jobs.s[2] = fp[5];  jobs.s[3] = bp[5];
    jobs.s[4] = fp[6];  jobs.s[5] = bp[6];
    jobs.s[6] = fp[10]; jobs.s[7] = bp[10];
    jobs.s[8] = fp[13]; jobs.s[9] = bp[13];
    jobs.s[10] = fp[15]; jobs.s[11] = bp[15];
    jobs.s[12] = aw1;
    int wblocks = 0;
    {
        const int wK[13] = {512,512,1024,1024,32,32,1024,1024,512,512,2048,2048,512};
        const int wN[13] = {2048,2048,64,64,1024,1024,512,512,2048,2048,512,512,256};
        const int wL[13] = {2,2,2,2,2,2,2,2,2,2,2,2,1};
        for (int j = 0; j < 13; j++) wblocks += wL[j] * (wK[j]/32) * (wN[j]/32);
    }
    wprep_k<<<wblocks, 256, 0, stream>>>(jobs, wts);

    init_h_k<<<kROWS * kDM / 256, 256, 0, stream>>>(x, h);

    for (int l = 0; l < kL; l++) {
        const float *f_n1w = fp[0]  + l * kDM,            *b_n1w = bp[0]  + l * kDM;
        const float *f_n1b = fp[1]  + l * kDM,            *b_n1b = bp[1]  + l * kDM;
        const float *f_cw  = fp[3]  + l * kDI * kDC,      *b_cw  = bp[3]  + l * kDI * kDC;
        const float *f_cb  = fp[4]  + l * kDI,            *b_cb  = bp[4]  + l * kDI;
        const float *f_dtb = fp[7]  + l * kDI,            *b_dtb = bp[7]  + l * kDI;
        const float *f_alog= fp[8]  + l * kDI * kDS,      *b_alog= bp[8]  + l * kDI * kDS;
        const float *f_dd  = fp[9]  + l * kDI,            *b_dd  = bp[9]  + l * kDI;
        const float *f_n2w = fp[11] + l * kDM,            *b_n2w = bp[11] + l * kDM;
        const float *f_n2b = fp[12] + l * kDM,            *b_n2b = bp[12] + l * kDM;
        const float *f_b1  = fp[14] + l * 4 * kDM,        *b_b1  = bp[14] + l * 4 * kDM;
        const float *f_b2  = fp[16] + l * kDM,            *b_b2  = bp[16] + l * kDM;

        const unsigned short *wInwF = wts + O_INW_F + (size_t)l * 2048 * 512;
        const unsigned short *wInwB = wts + O_INW_B + (size_t)l * 2048 * 512;
        const unsigned short *wXpwF = wts + O_XPW_F + (size_t)l * 64 * 1024;
        const unsigned short *wXpwB = wts + O_XPW_B + (size_t)l * 64 * 1024;
        const unsigned short *wDtwF = wts + O_DTW_F + (size_t)l * 1024 * 32;
        const unsigned short *wDtwB = wts + O_DTW_B + (size_t)l * 1024 * 32;
        const unsigned short *wOwF  = wts + O_OW_F  + (size_t)l * 512 * 1024;
        const unsigned short *wOwB  = wts + O_OW_B  + (size_t)l * 512 * 1024;
        const unsigned short *wW1F  = wts + O_W1_F  + (size_t)l * 2048 * 512;
        const unsigned short *wW1B  = wts + O_W1_B  + (size_t)l * 2048 * 512;
        const unsigned short *wW2F  = wts + O_W2_F  + (size_t)l * 512 * 2048;
        const unsigned short *wW2B  = wts + O_W2_B  + (size_t)l * 512 * 2048;

        // u = LN1(h) -> bf16
        ln_k<kDM,1><<<kROWS, 256, 0, stream>>>(h, f_n1w, b_n1w, f_n1b, b_n1b, ub);
        // x-half -> xbuf bf16; z-half -> gateT = silu(z) bf16 transposed
        gemm_mfma<128,128,EPI_NONE,0,MODE_GATE,1,64><<<dim3(16, 64), 256, 0, stream>>>(
            ub, kDM, kDM, wInwF, wInwB, nullptr, nullptr, xbuf, kDI, gateT);
        // xhT[d][row] = silu(conv(xbuf) + cb)
        conv_t_k<<<dim3(kN/64, kDI/32, kB2), 256, 0, stream>>>(
            xbuf, f_cw, b_cw, f_cb, b_cb, xhT);
        // dbl = xh @ xpw (A = xhT ATR); cols>=32 also -> dblF f32 [row][32]
        gemm_mfma<32,64,EPI_NONE,1,MODE_DBL,1,64><<<dim3(1, 256), 256, 0, stream>>>(
            xhT, kROWS, kDI, wXpwF, wXpwB, nullptr, nullptr, dbl, 64, (unsigned short*)dblF);
        // dtT[d][row] = softplus(dbl[:, :32] @ dtw + dtb) (transposed only)
        gemm_mfma<128,128,EPI_SOFTPLUS,0,MODE_OTR,1,32><<<dim3(8, 64), 256, 0, stream>>>(
            dbl, 64, kDTR, wDtwF, wDtwB, f_dtb, b_dtb, nullptr, 0, tbuf);
        // blocked scan: local pass -> boundary fix -> full pass (yT into xbuf)
        bscan_k<0><<<dim3(kDI/256, kG, kB2), 256, 0, stream>>>(
            tbuf, xhT, gateT, dblF, xbuf, PL, f_alog, b_alog, f_dd, b_dd);
        bfix_k<<<kB2 * kDI * kDS / 256, 256, 0, stream>>>(PL);
        bscan_k<1><<<dim3(kDI/256, kG, kB2), 256, 0, stream>>>(
            tbuf, xhT, gateT, dblF, xbuf, PL, f_alog, b_alog, f_dd, b_dd);
        // h += y @ ow  (A = yT ATR; 128x64 tile -> 512 blocks for occupancy)
        gemm_mfma<128,64,EPI_RESID,1,MODE_N,0,64><<<dim3(8, 64), 256, 0, stream>>>(
            xbuf, kROWS, kDI, wOwF, wOwB, nullptr, nullptr, h, kDM, nullptr);
        // u = LN2(h) -> bf16
        ln_k<kDM,1><<<kROWS, 256, 0, stream>>>(h, f_n2w, b_n2w, f_n2b, b_n2b, ub);
        // ffn1: gelu(u @ w1 + b1) -> xbuf..tbuf slab bf16 (8192 x 2048)
        gemm_mfma<128,128,EPI_GELU,0,MODE_N,1,64><<<dim3(16, 64), 256, 0, stream>>>(
            ub, kDM, kDM, wW1F, wW1B, f_b1, b_b1, xbuf, 4*kDM, nullptr);
        // h += ffn1 @ w2 + b2  (128x64 tile -> 512 blocks)
        gemm_mfma<128,64,EPI_RESID_BIAS,0,MODE_N,0,64><<<dim3(8, 64), 256, 0, stream>>>(
            xbuf, 4*kDM, 4*kDM, wW2F, wW2B, f_b2, b_b2, h, kDM, nullptr);
    }

    // attention: hb = bf16(h); u = tanh(hb @ aw1 + ab1) bf16
    h2b_k<<<kROWS * kDM / 256, 256, 0, stream>>>(h, tbuf);
    // 64x128 tile -> 256 blocks
    gemm_mfma<64,128,EPI_TANH,0,MODE_N,1,64><<<dim3(2, 128), 256, 0, stream>>>(
        tbuf, kDM, kDM, wts + O_AW1, wts + O_AW1, ab1, ab1, ub, 256, nullptr);
    att_score_k<<<kROWS, 64, 0, stream>>>(ub, aw2, ab2, score);
    softmax_k<<<kB2, 256, 0, stream>>>(score, smw);
    hipMemsetAsync(zcat, 0, kB * 2 * kDM * sizeof(float), stream);
    pool_k<<<dim3(kB2, 32), 512, 0, stream>>>(smw, h, zcat);
    // out[0:4096] = LN(concat(zf, zb))
    ln_k<2*kDM,0><<<kB, 256, 0, stream>>>(zcat, nw, nw, nb, nb, out);
    // out[4096:8192] = 0.5*(af + flip(ab))
    att_out_k<<<kB * kN / 256, 256, 0, stream>>>(smw, out + kB * 2 * kDM);
}

// Round 5
// 751.635 us; speedup vs baseline: 1.2460x; 1.2460x over previous
//
#include <hip/hip_runtime.h>
#include <math.h>

constexpr int kDM   = 512;
constexpr int kDI   = 1024;
constexpr int kDS   = 16;
constexpr int kDC   = 4;
constexpr int kDTR  = 32;
constexpr int kL    = 2;
constexpr int kB    = 4;
constexpr int kN    = 1024;
constexpr int kB2   = 8;              // combined batch: rows 0-3 fwd, 4-7 bwd
constexpr int kROWS = kB2 * kN;       // 8192
constexpr int kMDIR = kB * kN;        // 4096 rows per direction

enum { EPI_NONE=0, EPI_SOFTPLUS=1, EPI_RESID=2, EPI_GELU=3, EPI_RESID_BIAS=4, EPI_TANH=5 };
enum { MODE_N=0, MODE_OTR=1, MODE_DBL=2, MODE_GATE=3 };

typedef __attribute__((ext_vector_type(8))) short bf16x8;
typedef __attribute__((ext_vector_type(4))) short bf16x4;
typedef __attribute__((ext_vector_type(4))) float f32x4;

__device__ __forceinline__ unsigned short f2bf(float f) {
    unsigned int u = __float_as_uint(f);
    return (unsigned short)((u + 0x7FFFu + ((u >> 16) & 1u)) >> 16);
}
__device__ __forceinline__ float b2f(unsigned short u) {
    return __uint_as_float((unsigned int)u << 16);
}
__device__ __forceinline__ bf16x4 pack4(const float* v) {
    union { unsigned short u[4]; bf16x4 t; } p;
#pragma unroll
    for (int j = 0; j < 4; j++) p.u[j] = f2bf(v[j]);
    return p.t;
}

// ------------------------------------------------------- weight prep --------
struct WJobs { const float* s[13]; };
// job order: f_inw b_inw f_xpw b_xpw f_dtw b_dtw f_ow b_ow f_w1 b_w1 f_w2 b_w2 aw1
constexpr size_t O_INW_F = 0;
constexpr size_t O_INW_B = O_INW_F + 2u*512*2048;
constexpr size_t O_XPW_F = O_INW_B + 2u*512*2048;
constexpr size_t O_XPW_B = O_XPW_F + 2u*1024*64;
constexpr size_t O_DTW_F = O_XPW_B + 2u*1024*64;
constexpr size_t O_DTW_B = O_DTW_F + 2u*32*1024;
constexpr size_t O_OW_F  = O_DTW_B + 2u*32*1024;
constexpr size_t O_OW_B  = O_OW_F  + 2u*1024*512;
constexpr size_t O_W1_F  = O_OW_B  + 2u*1024*512;
constexpr size_t O_W1_B  = O_W1_F  + 2u*512*2048;
constexpr size_t O_W2_F  = O_W1_B  + 2u*512*2048;
constexpr size_t O_W2_B  = O_W2_F  + 2u*2048*512;
constexpr size_t O_AW1   = O_W2_B  + 2u*2048*512;
constexpr size_t O_WTOT  = O_AW1   + 1u*512*256;

__global__ __launch_bounds__(256) void wprep_k(WJobs jobs, unsigned short* __restrict__ dst)
{
    const int wK[13] = {512,512,1024,1024,32,32,1024,1024,512,512,2048,2048,512};
    const int wN[13] = {2048,2048,64,64,1024,1024,512,512,2048,2048,512,512,256};
    const int wL[13] = {2,2,2,2,2,2,2,2,2,2,2,2,1};
    int blk = blockIdx.x;
    int j = 0; int base = 0; size_t doff = 0;
    for (; j < 13; j++) {
        int nb = wL[j] * (wK[j] / 32) * (wN[j] / 32);
        if (blk < base + nb) break;
        base += nb;
        doff += (size_t)wL[j] * wK[j] * wN[j];
    }
    int rel = blk - base;
    int K = wK[j], N = wN[j];
    int tk = K / 32, tn = N / 32;
    int l = rel / (tk * tn); rel -= l * tk * tn;
    int kt = rel / tn, nt = rel - (rel / tn) * tn;
    const float* src = jobs.s[j] + (size_t)l * K * N;
    unsigned short* d = dst + doff + (size_t)l * K * N;
    __shared__ float tl[32][33];
    const int c = threadIdx.x & 31, rg = threadIdx.x >> 5;
#pragma unroll
    for (int rr = 0; rr < 4; rr++)
        tl[rg * 4 + rr][c] = src[(size_t)(kt * 32 + rg * 4 + rr) * N + nt * 32 + c];
    __syncthreads();
#pragma unroll
    for (int rr = 0; rr < 4; rr++)
        d[(size_t)(nt * 32 + rg * 4 + rr) * K + kt * 32 + c] = f2bf(tl[c][rg * 4 + rr]);
}

// ---------------------------------------------------------------- init h ----
__global__ __launch_bounds__(256) void init_h_k(const float* __restrict__ x,
                                                float* __restrict__ h)
{
    size_t idx = (size_t)blockIdx.x * 256 + threadIdx.x;   // kROWS*kDM
    int d  = idx & (kDM - 1);
    int t  = (idx >> 9) & (kN - 1);
    int bb = (int)(idx >> 19);
    int b = bb & 3, dir = bb >> 2;
    int ts = dir ? (kN - 1 - t) : t;
    h[idx] = x[((size_t)b * kN + ts) * kDM + d];
}

__global__ __launch_bounds__(256) void h2b_k(const float* __restrict__ h,
                                             unsigned short* __restrict__ o)
{
    size_t idx = (size_t)blockIdx.x * 256 + threadIdx.x;
    o[idx] = f2bf(h[idx]);
}

// ---------------------------------------------------------------- layernorm --
template<int DIM, int OBF>
__global__ __launch_bounds__(256) void ln_k(const float* __restrict__ x,
    const float* __restrict__ wf, const float* __restrict__ wb,
    const float* __restrict__ bf, const float* __restrict__ bbp,
    void* __restrict__ outv)
{
    const int row = blockIdx.x;
    const int tid = threadIdx.x;
    constexpr int PT = DIM / 256;
    const int dir = (row >= kMDIR) ? 1 : 0;
    const float* w = dir ? wb : wf;
    const float* b = dir ? bbp : bf;

    float v[PT];
    float s1 = 0.f, s2 = 0.f;
#pragma unroll
    for (int i = 0; i < PT; i++) {
        float t = x[(size_t)row * DIM + tid + i * 256];
        v[i] = t; s1 += t; s2 += t * t;
    }
    for (int o = 32; o > 0; o >>= 1) { s1 += __shfl_xor(s1, o, 64); s2 += __shfl_xor(s2, o, 64); }
    __shared__ float r1[4], r2[4];
    int wv = tid >> 6;
    if ((tid & 63) == 0) { r1[wv] = s1; r2[wv] = s2; }
    __syncthreads();
    s1 = r1[0] + r1[1] + r1[2] + r1[3];
    s2 = r2[0] + r2[1] + r2[2] + r2[3];
    float mu  = s1 / DIM;
    float var = s2 / DIM - mu * mu;
    float rr  = rsqrtf(var + 1e-5f);
#pragma unroll
    for (int i = 0; i < PT; i++) {
        int c = tid + i * 256;
        float o = (v[i] - mu) * rr * w[c] + b[c];
        if (OBF) ((unsigned short*)outv)[(size_t)row * DIM + c] = f2bf(o);
        else     ((float*)outv)[(size_t)row * DIM + c] = o;
    }
}

// ---------------------------------------------------------------- MFMA GEMM -
// C = A @ B (+bias)(+epilogue). A bf16 [M][lda], B^T bf16 [N][K].
// All outputs ROW-MAJOR now (r14): MODE_GATE silu(z) -> Ct[row][kDI];
// MODE_DBL cols>=32 also f32 -> dblF[row][32]. Row-major epilogue stores are
// 32-B-contiguous per 16 lanes (the old col-major transposed stores were
// 8 B per 16-KB stride -> write amplification).
template<int BM, int BN, int EPI, int ATR, int MODE, int OBF, int KB>
__global__ __launch_bounds__(256) void gemm_mfma(
    const unsigned short* __restrict__ A, int lda, int K,
    const unsigned short* __restrict__ Btf, const unsigned short* __restrict__ Btb,
    const float* __restrict__ biasf, const float* __restrict__ biasb,
    void* __restrict__ Cv, int ldc, unsigned short* __restrict__ Ct)
{
    constexpr int SK  = 40;              // padded LDS row stride (bf16 elems)
    constexpr int KT  = KB / 32;         // 32-wide sub-tiles per stage
    constexpr int CPR = KB / 8;          // 8-elem chunks per row
    constexpr int WM  = BM / 2, WN = BN / 2;
    constexpr int MT  = WM / 16, NT = WN / 16;
    constexpr int ASL = (BM * KB) / (256 * 8);
    constexpr int BSL = (BN * KB) / (256 * 8);
    constexpr int MB4 = BM / 4;
    constexpr int ATR_TH = (BM / 4) * (KB / 4);
    constexpr int ATR_R  = (ATR_TH + 255) / 256;

    __shared__ unsigned short As[KT * BM * SK];
    __shared__ unsigned short Bs[KT * BN * SK];

    const int tid  = threadIdx.x;
    const int n0   = blockIdx.x * BN;
    const int row0 = blockIdx.y * BM;
    const int dir  = (row0 >= kMDIR) ? 1 : 0;
    const unsigned short* __restrict__ Bt = dir ? Btb : Btf;
    const float* bias = dir ? biasb : biasf;

    const int lane = tid & 63;
    const int wave = tid >> 6;
    const int wr = wave >> 1, wc = wave & 1;
    const int ml = lane & 15, q = lane >> 4;

    f32x4 acc[MT][NT];
#pragma unroll
    for (int i = 0; i < MT; i++)
#pragma unroll
        for (int j = 0; j < NT; j++)
#pragma unroll
            for (int r = 0; r < 4; r++) acc[i][j][r] = 0.f;

    for (int kt = 0; kt < K; kt += KB) {
        // ---- global loads ----
        bf16x8 a_ld[ASL ? ASL : 1];
        bf16x4 at_ld[ATR_R][4];
        if (!ATR) {
#pragma unroll
            for (int r = 0; r < ASL; r++) {
                int i = tid + r * 256;
                int m = i / CPR, c8 = (i % CPR) * 8;
                a_ld[r] = *(const bf16x8*)(A + (size_t)(row0 + m) * lda + kt + c8);
            }
        } else {
#pragma unroll
            for (int r = 0; r < ATR_R; r++) {
                int idx = tid + r * 256;
                if (idx < ATR_TH) {
                    int mb = idx % MB4, ka = idx / MB4;
#pragma unroll
                    for (int j = 0; j < 4; j++)
                        at_ld[r][j] = *(const bf16x4*)(A + (size_t)(kt + ka * 4 + j) * lda + row0 + mb * 4);
                }
            }
        }
        bf16x8 b_ld[BSL ? BSL : 1];
#pragma unroll
        for (int r = 0; r < BSL; r++) {
            int i = tid + r * 256;
            int n = i / CPR, c8 = (i % CPR) * 8;
            b_ld[r] = *(const bf16x8*)(Bt + (size_t)(n0 + n) * K + kt + c8);
        }
        __syncthreads();     // previous iteration's LDS reads complete
        // ---- LDS writes ----
        if (!ATR) {
#pragma unroll
            for (int r = 0; r < ASL; r++) {
                int i = tid + r * 256;
                int m = i / CPR, c8 = (i % CPR) * 8;
                *(bf16x8*)&As[((c8 >> 5) * BM + m) * SK + (c8 & 31)] = a_ld[r];
            }
        } else {
#pragma unroll
            for (int r = 0; r < ATR_R; r++) {
                int idx = tid + r * 256;
                if (idx < ATR_TH) {
                    int mb = idx % MB4, ka = idx / MB4;
                    union { bf16x4 v; unsigned short u[4]; } rw4[4];
#pragma unroll
                    for (int j = 0; j < 4; j++) rw4[j].v = at_ld[r][j];
                    int col = ka * 4;
#pragma unroll
                    for (int mp = 0; mp < 4; mp++) {
                        union { unsigned short u[4]; bf16x4 v; } cl;
#pragma unroll
                        for (int j = 0; j < 4; j++) cl.u[j] = rw4[j].u[mp];
                        *(bf16x4*)&As[((col >> 5) * BM + mb * 4 + mp) * SK + (col & 31)] = cl.v;
                    }
                }
            }
        }
#pragma unroll
        for (int r = 0; r < BSL; r++) {
            int i = tid + r * 256;
            int n = i / CPR, c8 = (i % CPR) * 8;
            *(bf16x8*)&Bs[((c8 >> 5) * BN + n) * SK + (c8 & 31)] = b_ld[r];
        }
        __syncthreads();
        // ---- fragments + MFMA (KT sub-steps of K=32) ----
#pragma unroll
        for (int kk = 0; kk < KT; kk++) {
            bf16x8 af[MT], bfr[NT];
#pragma unroll
            for (int i = 0; i < MT; i++)
                af[i] = *(bf16x8*)&As[(kk * BM + wr * WM + i * 16 + ml) * SK + q * 8];
#pragma unroll
            for (int j = 0; j < NT; j++)
                bfr[j] = *(bf16x8*)&Bs[(kk * BN + wc * WN + j * 16 + ml) * SK + q * 8];
#pragma unroll
            for (int i = 0; i < MT; i++)
#pragma unroll
                for (int j = 0; j < NT; j++)
                    acc[i][j] = __builtin_amdgcn_mfma_f32_16x16x32_bf16(af[i], bfr[j], acc[i][j], 0, 0, 0);
        }
    }

    // ---- epilogue ----
    float* Cf = (float*)Cv;
    unsigned short* Cb = (unsigned short*)Cv;
#pragma unroll
    for (int j = 0; j < NT; j++) {
        int col = n0 + wc * WN + j * 16 + ml;
        float bv = 0.f;
        if (EPI == EPI_SOFTPLUS || EPI == EPI_GELU || EPI == EPI_RESID_BIAS || EPI == EPI_TANH)
            bv = bias[col];
#pragma unroll
        for (int i = 0; i < MT; i++) {
            int rw = row0 + wr * WM + i * 16 + q * 4;
            float v4[4];
#pragma unroll
            for (int r = 0; r < 4; r++) {
                float v = acc[i][j][r] + bv;
                if (EPI == EPI_SOFTPLUS) v = (v > 20.f) ? v : __logf(1.f + __expf(v));
                if (EPI == EPI_GELU)     v = 0.5f * v * (1.f + erff(v * 0.70710678118654752f));
                if (EPI == EPI_TANH)     v = tanhf(v);
                v4[r] = v;
            }
            if (MODE == MODE_GATE && n0 >= kDI) {
                // silu(z) -> gate row-major [row][kDI]
#pragma unroll
                for (int r = 0; r < 4; r++) {
                    float sv = v4[r] / (1.f + __expf(-v4[r]));
                    Ct[(size_t)(rw + r) * kDI + (col - kDI)] = f2bf(sv);
                }
            } else {
#pragma unroll
                for (int r = 0; r < 4; r++) {
                    size_t o = (size_t)(rw + r) * ldc + col;
                    if (EPI == EPI_RESID || EPI == EPI_RESID_BIAS) Cf[o] += v4[r];
                    else if (OBF) Cb[o] = f2bf(v4[r]);
                    else Cf[o] = v4[r];
                }
                if (MODE == MODE_DBL && col >= 32) {
                    float* F = (float*)Ct;          // dblF f32 [row][32]
#pragma unroll
                    for (int r = 0; r < 4; r++)
                        F[(size_t)(rw + r) * 32 + (col - 32)] = v4[r];
                }
            }
        }
    }
}

// ---------------------------------------------------------------- conv ------
// xb bf16 [row][kDI] (x-half) -> xh bf16 [row][kDI] = silu(causal conv + cb).
// r14: row-major output (no transpose stage -- scan + xpw GEMM read row-major).
__global__ __launch_bounds__(256) void conv_k(const unsigned short* __restrict__ xb,
    const float* __restrict__ cwf, const float* __restrict__ cwb,
    const float* __restrict__ cbf, const float* __restrict__ cbb,
    unsigned short* __restrict__ xh)
{
    __shared__ float tl[67][33];
    const int t0 = blockIdx.x * 64, d0 = blockIdx.y * 32, bb = blockIdx.z;
    const int dir = bb >> 2;
    const float* cw = dir ? cwb : cwf;
    const float* cb = dir ? cbb : cbf;
    const int dl = threadIdx.x & 31, rl = threadIdx.x >> 5;
    const size_t base = (size_t)bb * kN * kDI + d0 + dl;
#pragma unroll
    for (int p = 0; p < 9; p++) {
        int r = p * 8 + rl;
        if (r < 67) {
            int ts = t0 + r - 3;
            tl[r][dl] = (ts >= 0) ? b2f(xb[base + (size_t)ts * kDI]) : 0.f;
        }
    }
    __syncthreads();
    const int gd = d0 + dl;
    float c0 = cw[gd*4+0], c1 = cw[gd*4+1], c2 = cw[gd*4+2], c3 = cw[gd*4+3];
    float bv = cb[gd];
#pragma unroll
    for (int jj = 0; jj < 8; jj++) {
        int tt = rl + 8 * jj;
        float acc = bv + c0*tl[tt][dl] + c1*tl[tt+1][dl] + c2*tl[tt+2][dl] + c3*tl[tt+3][dl];
        float o = acc / (1.f + __expf(-acc));
        xh[(size_t)(bb * kN + t0 + tt) * kDI + gd] = f2bf(o);
    }
}

// ---------------------------------------------------------------- scan ------
// r14: coalesced blocked scan (r13 algorithm, row-major layout).
// r13 counters: VALU win confirmed (25% busy) but 200 MB FETCH vs 67 MB
// unique -- the [d][row] layout gave 64-B-per-thread strided reads (half-
// used, L1-thrashed lines) . r14 keeps the h[16]-in-registers 3-pass
// decomposition (arithmetic identical, r13-validated) and flips every
// stream to [row][d]: consecutive lanes -> consecutive addresses (fully
// consumed lines); B/C rows of dblF are block-uniform loads (L1-resident
// 8 KB/group); PL re-laid as [bb][g][slot][d] so PL I/O is coalesced too.
constexpr int kG  = 32;           // groups per chain
constexpr int kTg = kN / kG;      // 32 timesteps per group

template<int PASS>
__global__ __launch_bounds__(256) void bscan_k(
    const unsigned short* __restrict__ dt,   // [row][kDI]
    const unsigned short* __restrict__ xh,   // [row][kDI]
    const unsigned short* __restrict__ gate, // [row][kDI]
    const float* __restrict__ dblF,          // [row][32] (B | C)
    unsigned short* __restrict__ y,          // [row][kDI]
    float* __restrict__ PL,                  // [bb][g][32 slots][kDI]
    const float* __restrict__ alogf, const float* __restrict__ alogb,
    const float* __restrict__ ddf,   const float* __restrict__ ddb)
{
    const int d  = blockIdx.x * 256 + threadIdx.x;   // 0..1023
    const int g  = blockIdx.y;                       // 0..31
    const int bb = blockIdx.z;                       // 0..7
    const int dir = bb >> 2;
    const float* alog = dir ? alogb : alogf;
    const float* ddp  = dir ? ddb  : ddf;

    float a2[16];
#pragma unroll
    for (int s = 0; s < 16; s += 4) {
        float4 al = *(const float4*)&alog[d * kDS + s];
        a2[s+0] = -__expf(al.x) * 1.44269504f;
        a2[s+1] = -__expf(al.y) * 1.44269504f;
        a2[s+2] = -__expf(al.z) * 1.44269504f;
        a2[s+3] = -__expf(al.w) * 1.44269504f;
    }

    const size_t plb = (size_t)(bb * kG + g) * 32 * kDI + d;   // slot stride kDI
    float h[16];
    if (PASS == 0) {
#pragma unroll
        for (int s = 0; s < 16; s++) h[s] = 0.f;
    } else {
#pragma unroll
        for (int s = 0; s < 16; s++) h[s] = PL[plb + (size_t)(16 + s) * kDI];
    }

    const int row0 = bb * kN + g * kTg;
    const unsigned short* pd = dt   + (size_t)row0 * kDI + d;
    const unsigned short* px = xh   + (size_t)row0 * kDI + d;
    const unsigned short* pg = gate + (size_t)row0 * kDI + d;
    const float* pbc = dblF + (size_t)row0 * 32;
    unsigned short* py = y + (size_t)row0 * kDI + d;
    const float ddv = ddp[d];
    float sdt = 0.f;

#pragma unroll 4
    for (int t = 0; t < kTg; t++) {
        float dtv = b2f(pd[(size_t)t * kDI]);
        float xvv = b2f(px[(size_t)t * kDI]);
        float dtx = dtv * xvv;
        const float* bc = pbc + t * 32;
        if (PASS == 0) {
            sdt += dtv;
#pragma unroll
            for (int s4 = 0; s4 < 4; s4++) {
                float4 Bq = *(const float4*)(bc + s4 * 4);
                h[s4*4+0] = __builtin_amdgcn_exp2f(dtv * a2[s4*4+0]) * h[s4*4+0] + dtx * Bq.x;
                h[s4*4+1] = __builtin_amdgcn_exp2f(dtv * a2[s4*4+1]) * h[s4*4+1] + dtx * Bq.y;
                h[s4*4+2] = __builtin_amdgcn_exp2f(dtv * a2[s4*4+2]) * h[s4*4+2] + dtx * Bq.z;
                h[s4*4+3] = __builtin_amdgcn_exp2f(dtv * a2[s4*4+3]) * h[s4*4+3] + dtx * Bq.w;
            }
        } else {
            float p = 0.f;
#pragma unroll
            for (int s4 = 0; s4 < 4; s4++) {
                float4 Bq = *(const float4*)(bc + s4 * 4);
                float4 Cq = *(const float4*)(bc + 16 + s4 * 4);
                h[s4*4+0] = __builtin_amdgcn_exp2f(dtv * a2[s4*4+0]) * h[s4*4+0] + dtx * Bq.x;
                p += h[s4*4+0] * Cq.x;
                h[s4*4+1] = __builtin_amdgcn_exp2f(dtv * a2[s4*4+1]) * h[s4*4+1] + dtx * Bq.y;
                p += h[s4*4+1] * Cq.y;
                h[s4*4+2] = __builtin_amdgcn_exp2f(dtv * a2[s4*4+2]) * h[s4*4+2] + dtx * Bq.z;
                p += h[s4*4+2] * Cq.z;
                h[s4*4+3] = __builtin_amdgcn_exp2f(dtv * a2[s4*4+3]) * h[s4*4+3] + dtx * Bq.w;
                p += h[s4*4+3] * Cq.w;
            }
            float gvv = b2f(pg[(size_t)t * kDI]);
            py[(size_t)t * kDI] = f2bf((p + ddv * xvv) * gvv);
        }
    }

    if (PASS == 0) {
#pragma unroll
        for (int s = 0; s < 16; s++) {
            PL[plb + (size_t)s * kDI]        = __builtin_amdgcn_exp2f(a2[s] * sdt);
            PL[plb + (size_t)(16 + s) * kDI] = h[s];
        }
    }
}

// boundary fix: h_in[chain][g] = scan of (P,L) over groups; rewrites L slot.
__global__ __launch_bounds__(256) void bfix_k(float* __restrict__ PL)
{
    const int idx = blockIdx.x * 256 + threadIdx.x;  // 16 s x 8 bb x 1024 d
    const int d  = idx & (kDI - 1);
    const int bb = (idx >> 10) & 7;
    const int s  = idx >> 13;
    float h = 0.f;
    for (int g = 0; g < kG; g++) {
        size_t base = (size_t)(bb * kG + g) * 32 * kDI + d;
        float P = PL[base + (size_t)s * kDI];
        float L = PL[base + (size_t)(16 + s) * kDI];
        PL[base + (size_t)(16 + s) * kDI] = h;   // h_in for pass C
        h = P * h + L;
    }
}

// ---------------------------------------------------------------- attention -
__global__ __launch_bounds__(64) void att_score_k(const unsigned short* __restrict__ tmp,
    const float* __restrict__ aw2, const float* __restrict__ ab2,
    float* __restrict__ score)
{
    int row = blockIdx.x, lane = threadIdx.x;
    float acc = 0.f;
#pragma unroll
    for (int j = 0; j < 4; j++)
        acc += b2f(tmp[(size_t)row * 256 + lane + j * 64]) * aw2[lane + j * 64];
    for (int o = 32; o > 0; o >>= 1) acc += __shfl_xor(acc, o, 64);
    if (lane == 0) score[row] = acc + ab2[0];
}

__global__ __launch_bounds__(256) void softmax_k(const float* __restrict__ score,
                                                 float* __restrict__ w)
{
    int bb = blockIdx.x, tid = threadIdx.x;
    float v[4]; float m = -1e30f;
#pragma unroll
    for (int i = 0; i < 4; i++) { v[i] = score[bb * kN + tid + i * 256]; m = fmaxf(m, v[i]); }
    for (int o = 32; o > 0; o >>= 1) m = fmaxf(m, __shfl_xor(m, o, 64));
    __shared__ float r1[4], r2[4];
    int wv = tid >> 6;
    if ((tid & 63) == 0) r1[wv] = m;
    __syncthreads();
    m = fmaxf(fmaxf(r1[0], r1[1]), fmaxf(r1[2], r1[3]));
    float s = 0.f;
#pragma unroll
    for (int i = 0; i < 4; i++) { v[i] = __expf(v[i] - m); s += v[i]; }
    for (int o = 32; o > 0; o >>= 1) s += __shfl_xor(s, o, 64);
    if ((tid & 63) == 0) r2[wv] = s;
    __syncthreads();
    s = r2[0] + r2[1] + r2[2] + r2[3];
    float inv = 1.f / s;
#pragma unroll
    for (int i = 0; i < 4; i++) w[bb * kN + tid + i * 256] = v[i] * inv;
}

__global__ __launch_bounds__(512) void pool_k(const float* __restrict__ w,
    const float* __restrict__ h, float* zcat)
{
    int bb = blockIdx.x, chunk = blockIdx.y;   // 8 x 32
    int d = threadIdx.x;
    float acc = 0.f;
    int n0 = chunk * 32;
    for (int n = n0; n < n0 + 32; n++)
        acc += w[bb * kN + n] * h[((size_t)bb * kN + n) * kDM + d];
    int b = bb & 3, dir = bb >> 2;
    atomicAdd(&zcat[b * (2 * kDM) + dir * kDM + d], acc);
}

__global__ __launch_bounds__(256) void att_out_k(const float* __restrict__ w,
                                                 float* __restrict__ out)
{
    int idx = blockIdx.x * 256 + threadIdx.x;  // kB*kN
    int b = idx >> 10, n = idx & 1023;
    out[idx] = 0.5f * (w[b * kN + n] + w[(b + 4) * kN + (kN - 1 - n)]);
}

// ---------------------------------------------------------------- launch ----
extern "C" void kernel_launch(void* const* d_in, const int* in_sizes, int n_in,
                              void* d_out, int out_size, void* d_ws, size_t ws_size,
                              hipStream_t stream)
{
    const float* x = (const float*)d_in[0];
    const float* fp[17]; const float* bp[17];
    for (int i = 0; i < 17; i++) { fp[i] = (const float*)d_in[1 + i]; bp[i] = (const float*)d_in[18 + i]; }
    const float* aw1 = (const float*)d_in[35];
    const float* ab1 = (const float*)d_in[36];
    const float* aw2 = (const float*)d_in[37];
    const float* ab2 = (const float*)d_in[38];
    const float* nw  = (const float*)d_in[39];
    const float* nb  = (const float*)d_in[40];
    float* out = (float*)d_out;

    float* h = (float*)d_ws;                                   // 8192*512 f32
    unsigned short* ub    = (unsigned short*)(h + (size_t)kROWS * kDM);  // 8192*512
    unsigned short* xbuf  = ub    + (size_t)kROWS * kDM;        // 8192*1024 (x-half / y / ffn1 lo)
    unsigned short* tbuf  = xbuf  + (size_t)kROWS * kDI;        // 8192*1024 (dt / ffn1 hi / hb)
    unsigned short* xhb   = tbuf  + (size_t)kROWS * kDI;        // 8192*1024 (xh row-major)
    unsigned short* gateb = xhb   + (size_t)kROWS * kDI;        // 8192*1024 (gate row-major)
    unsigned short* dbl   = gateb + (size_t)kROWS * kDI;        // 8192*64 bf16
    float* dblF  = (float*)(dbl + (size_t)kROWS * 64);          // 8192*32 f32 (B/C)
    float* score = dblF + (size_t)kROWS * 32;                   // 8192
    float* smw   = score + kROWS;                               // 8192
    float* zcat  = smw   + kROWS;                               // 4096
    unsigned short* wts  = (unsigned short*)(zcat + kB * 2 * kDM);
    float* PL = (float*)(wts + O_WTOT);                         // 8*32*32*1024 f32 = 32MB

    // ---- weight prep: fp32 [L][K][N] -> bf16 [L][N][K] (one launch) ----
    WJobs jobs;
    jobs.s[0] = fp[2];  jobs.s[1] = bp[2];
    jobs.s[2] = fp[5];  jobs.s[3] = bp[5];
    jobs.s[4] = fp[6];  jobs.s[5] = bp[6];
    jobs.s[6] = fp[10]; jobs.s[7] = bp[10];
    jobs.s[8] = fp[13]; jobs.s[9] = bp[13];
    jobs.s[10] = fp[15]; jobs.s[11] = bp[15];
    jobs.s[12] = aw1;
    int wblocks = 0;
    {
        const int wK[13] = {512,512,1024,1024,32,32,1024,1024,512,512,2048,2048,512};
        const int wN[13] = {2048,2048,64,64,1024,1024,512,512,2048,2048,512,512,256};
        const int wL[13] = {2,2,2,2,2,2,2,2,2,2,2,2,1};
        for (int j = 0; j < 13; j++) wblocks += wL[j] * (wK[j]/32) * (wN[j]/32);
    }
    wprep_k<<<wblocks, 256, 0, stream>>>(jobs, wts);

    init_h_k<<<kROWS * kDM / 256, 256, 0, stream>>>(x, h);

    for (int l = 0; l < kL; l++) {
        const float *f_n1w = fp[0]  + l * kDM,            *b_n1w = bp[0]  + l * kDM;
        const float *f_n1b = fp[1]  + l * kDM,            *b_n1b = bp[1]  + l * kDM;
        const float *f_cw  = fp[3]  + l * kDI * kDC,      *b_cw  = bp[3]  + l * kDI * kDC;
        const float *f_cb  = fp[4]  + l * kDI,            *b_cb  = bp[4]  + l * kDI;
        const float *f_dtb = fp[7]  + l * kDI,            *b_dtb = bp[7]  + l * kDI;
        const float *f_alog= fp[8]  + l * kDI * kDS,      *b_alog= bp[8]  + l * kDI * kDS;
        const float *f_dd  = fp[9]  + l * kDI,            *b_dd  = bp[9]  + l * kDI;
        const float *f_n2w = fp[11] + l * kDM,            *b_n2w = bp[11] + l * kDM;
        const float *f_n2b = fp[12] + l * kDM,            *b_n2b = bp[12] + l * kDM;
        const float *f_b1  = fp[14] + l * 4 * kDM,        *b_b1  = bp[14] + l * 4 * kDM;
        const float *f_b2  = fp[16] + l * kDM,            *b_b2  = bp[16] + l * kDM;

        const unsigned short *wInwF = wts + O_INW_F + (size_t)l * 2048 * 512;
        const unsigned short *wInwB = wts + O_INW_B + (size_t)l * 2048 * 512;
        const unsigned short *wXpwF = wts + O_XPW_F + (size_t)l * 64 * 1024;
        const unsigned short *wXpwB = wts + O_XPW_B + (size_t)l * 64 * 1024;
        const unsigned short *wDtwF = wts + O_DTW_F + (size_t)l * 1024 * 32;
        const unsigned short *wDtwB = wts + O_DTW_B + (size_t)l * 1024 * 32;
        const unsigned short *wOwF  = wts + O_OW_F  + (size_t)l * 512 * 1024;
        const unsigned short *wOwB  = wts + O_OW_B  + (size_t)l * 512 * 1024;
        const unsigned short *wW1F  = wts + O_W1_F  + (size_t)l * 2048 * 512;
        const unsigned short *wW1B  = wts + O_W1_B  + (size_t)l * 2048 * 512;
        const unsigned short *wW2F  = wts + O_W2_F  + (size_t)l * 512 * 2048;
        const unsigned short *wW2B  = wts + O_W2_B  + (size_t)l * 512 * 2048;

        // u = LN1(h) -> bf16
        ln_k<kDM,1><<<kROWS, 256, 0, stream>>>(h, f_n1w, b_n1w, f_n1b, b_n1b, ub);
        // x-half -> xbuf bf16 [row][kDI]; z-half -> gateb = silu(z) row-major
        gemm_mfma<128,128,EPI_NONE,0,MODE_GATE,1,64><<<dim3(16, 64), 256, 0, stream>>>(
            ub, kDM, kDM, wInwF, wInwB, nullptr, nullptr, xbuf, kDI, gateb);
        // xh[row][kDI] = silu(conv(xbuf) + cb)  (row-major, no transpose)
        conv_k<<<dim3(kN/64, kDI/32, kB2), 256, 0, stream>>>(
            xbuf, f_cw, b_cw, f_cb, b_cb, xhb);
        // dbl = xh @ xpw (A row-major); cols>=32 also -> dblF f32 [row][32]
        gemm_mfma<32,64,EPI_NONE,0,MODE_DBL,1,64><<<dim3(1, 256), 256, 0, stream>>>(
            xhb, kDI, kDI, wXpwF, wXpwB, nullptr, nullptr, dbl, 64, (unsigned short*)dblF);
        // dt[row][kDI] = softplus(dbl[:, :32] @ dtw + dtb)  (row-major)
        gemm_mfma<128,128,EPI_SOFTPLUS,0,MODE_N,1,32><<<dim3(8, 64), 256, 0, stream>>>(
            dbl, 64, kDTR, wDtwF, wDtwB, f_dtb, b_dtb, tbuf, kDI, nullptr);
        // blocked scan: local pass -> boundary fix -> full pass (y into xbuf)
        bscan_k<0><<<dim3(kDI/256, kG, kB2), 256, 0, stream>>>(
            tbuf, xhb, gateb, dblF, xbuf, PL, f_alog, b_alog, f_dd, b_dd);
        bfix_k<<<kB2 * kDI * kDS / 256, 256, 0, stream>>>(PL);
        bscan_k<1><<<dim3(kDI/256, kG, kB2), 256, 0, stream>>>(
            tbuf, xhb, gateb, dblF, xbuf, PL, f_alog, b_alog, f_dd, b_dd);
        // h += y @ ow  (A = y row-major)
        gemm_mfma<128,64,EPI_RESID,0,MODE_N,0,64><<<dim3(8, 64), 256, 0, stream>>>(
            xbuf, kDI, kDI, wOwF, wOwB, nullptr, nullptr, h, kDM, nullptr);
        // u = LN2(h) -> bf16
        ln_k<kDM,1><<<kROWS, 256, 0, stream>>>(h, f_n2w, b_n2w, f_n2b, b_n2b, ub);
        // ffn1: gelu(u @ w1 + b1) -> xbuf..tbuf slab bf16 (8192 x 2048)
        gemm_mfma<128,128,EPI_GELU,0,MODE_N,1,64><<<dim3(16, 64), 256, 0, stream>>>(
            ub, kDM, kDM, wW1F, wW1B, f_b1, b_b1, xbuf, 4*kDM, nullptr);
        // h += ffn1 @ w2 + b2  (128x64 tile -> 512 blocks)
        gemm_mfma<128,64,EPI_RESID_BIAS,0,MODE_N,0,64><<<dim3(8, 64), 256, 0, stream>>>(
            xbuf, 4*kDM, 4*kDM, wW2F, wW2B, f_b2, b_b2, h, kDM, nullptr);
    }

    // attention: hb = bf16(h); u = tanh(hb @ aw1 + ab1) bf16
    h2b_k<<<kROWS * kDM / 256, 256, 0, stream>>>(h, tbuf);
    // 64x128 tile -> 256 blocks
    gemm_mfma<64,128,EPI_TANH,0,MODE_N,1,64><<<dim3(2, 128), 256, 0, stream>>>(
        tbuf, kDM, kDM, wts + O_AW1, wts + O_AW1, ab1, ab1, ub, 256, nullptr);
    att_score_k<<<kROWS, 64, 0, stream>>>(ub, aw2, ab2, score);
    softmax_k<<<kB2, 256, 0, stream>>>(score, smw);
    hipMemsetAsync(zcat, 0, kB * 2 * kDM * sizeof(float), stream);
    pool_k<<<dim3(kB2, 32), 512, 0, stream>>>(smw, h, zcat);
    // out[0:4096] = LN(concat(zf, zb))
    ln_k<2*kDM,0><<<kB, 256, 0, stream>>>(zcat, nw, nw, nb, nb, out);
    // out[4096:8192] = 0.5*(af + flip(ab))
    att_out_k<<<kB * kN / 256, 256, 0, stream>>>(smw, out + kB * 2 * kDM);
}

// Round 6
// 727.785 us; speedup vs baseline: 1.2868x; 1.0328x over previous
//
#include <hip/hip_runtime.h>
#include <math.h>

constexpr int kDM   = 512;
constexpr int kDI   = 1024;
constexpr int kDS   = 16;
constexpr int kDC   = 4;
constexpr int kDTR  = 32;
constexpr int kL    = 2;
constexpr int kB    = 4;
constexpr int kN    = 1024;
constexpr int kB2   = 8;              // combined batch: rows 0-3 fwd, 4-7 bwd
constexpr int kROWS = kB2 * kN;       // 8192
constexpr int kMDIR = kB * kN;        // 4096 rows per direction

enum { EPI_NONE=0, EPI_SOFTPLUS=1, EPI_RESID=2, EPI_GELU=3, EPI_RESID_BIAS=4, EPI_TANH=5 };
enum { MODE_N=0, MODE_OTR=1, MODE_DBL=2, MODE_GATE=3 };

typedef __attribute__((ext_vector_type(8))) short bf16x8;
typedef __attribute__((ext_vector_type(4))) short bf16x4;
typedef __attribute__((ext_vector_type(4))) float f32x4;

__device__ __forceinline__ unsigned short f2bf(float f) {
    unsigned int u = __float_as_uint(f);
    return (unsigned short)((u + 0x7FFFu + ((u >> 16) & 1u)) >> 16);
}
__device__ __forceinline__ float b2f(unsigned short u) {
    return __uint_as_float((unsigned int)u << 16);
}
__device__ __forceinline__ bf16x4 pack4(const float* v) {
    union { unsigned short u[4]; bf16x4 t; } p;
#pragma unroll
    for (int j = 0; j < 4; j++) p.u[j] = f2bf(v[j]);
    return p.t;
}

// ------------------------------------------------------- weight prep --------
struct WJobs { const float* s[13]; };
// job order: f_inw b_inw f_xpw b_xpw f_dtw b_dtw f_ow b_ow f_w1 b_w1 f_w2 b_w2 aw1
constexpr size_t O_INW_F = 0;
constexpr size_t O_INW_B = O_INW_F + 2u*512*2048;
constexpr size_t O_XPW_F = O_INW_B + 2u*512*2048;
constexpr size_t O_XPW_B = O_XPW_F + 2u*1024*64;
constexpr size_t O_DTW_F = O_XPW_B + 2u*1024*64;
constexpr size_t O_DTW_B = O_DTW_F + 2u*32*1024;
constexpr size_t O_OW_F  = O_DTW_B + 2u*32*1024;
constexpr size_t O_OW_B  = O_OW_F  + 2u*1024*512;
constexpr size_t O_W1_F  = O_OW_B  + 2u*1024*512;
constexpr size_t O_W1_B  = O_W1_F  + 2u*512*2048;
constexpr size_t O_W2_F  = O_W1_B  + 2u*512*2048;
constexpr size_t O_W2_B  = O_W2_F  + 2u*2048*512;
constexpr size_t O_AW1   = O_W2_B  + 2u*2048*512;
constexpr size_t O_WTOT  = O_AW1   + 1u*512*256;

__global__ __launch_bounds__(256) void wprep_k(WJobs jobs, unsigned short* __restrict__ dst)
{
    const int wK[13] = {512,512,1024,1024,32,32,1024,1024,512,512,2048,2048,512};
    const int wN[13] = {2048,2048,64,64,1024,1024,512,512,2048,2048,512,512,256};
    const int wL[13] = {2,2,2,2,2,2,2,2,2,2,2,2,1};
    int blk = blockIdx.x;
    int j = 0; int base = 0; size_t doff = 0;
    for (; j < 13; j++) {
        int nb = wL[j] * (wK[j] / 32) * (wN[j] / 32);
        if (blk < base + nb) break;
        base += nb;
        doff += (size_t)wL[j] * wK[j] * wN[j];
    }
    int rel = blk - base;
    int K = wK[j], N = wN[j];
    int tk = K / 32, tn = N / 32;
    int l = rel / (tk * tn); rel -= l * tk * tn;
    int kt = rel / tn, nt = rel - (rel / tn) * tn;
    const float* src = jobs.s[j] + (size_t)l * K * N;
    unsigned short* d = dst + doff + (size_t)l * K * N;
    __shared__ float tl[32][33];
    const int c = threadIdx.x & 31, rg = threadIdx.x >> 5;
#pragma unroll
    for (int rr = 0; rr < 4; rr++)
        tl[rg * 4 + rr][c] = src[(size_t)(kt * 32 + rg * 4 + rr) * N + nt * 32 + c];
    __syncthreads();
#pragma unroll
    for (int rr = 0; rr < 4; rr++)
        d[(size_t)(nt * 32 + rg * 4 + rr) * K + kt * 32 + c] = f2bf(tl[c][rg * 4 + rr]);
}

// ---------------------------------------------------------------- init h ----
__global__ __launch_bounds__(256) void init_h_k(const float* __restrict__ x,
                                                float* __restrict__ h)
{
    size_t idx = (size_t)blockIdx.x * 256 + threadIdx.x;   // kROWS*kDM
    int d  = idx & (kDM - 1);
    int t  = (idx >> 9) & (kN - 1);
    int bb = (int)(idx >> 19);
    int b = bb & 3, dir = bb >> 2;
    int ts = dir ? (kN - 1 - t) : t;
    h[idx] = x[((size_t)b * kN + ts) * kDM + d];
}

__global__ __launch_bounds__(256) void h2b_k(const float* __restrict__ h,
                                             unsigned short* __restrict__ o)
{
    size_t idx = (size_t)blockIdx.x * 256 + threadIdx.x;
    o[idx] = f2bf(h[idx]);
}

// ---------------------------------------------------------------- layernorm --
template<int DIM, int OBF>
__global__ __launch_bounds__(256) void ln_k(const float* __restrict__ x,
    const float* __restrict__ wf, const float* __restrict__ wb,
    const float* __restrict__ bf, const float* __restrict__ bbp,
    void* __restrict__ outv)
{
    const int row = blockIdx.x;
    const int tid = threadIdx.x;
    constexpr int PT = DIM / 256;
    const int dir = (row >= kMDIR) ? 1 : 0;
    const float* w = dir ? wb : wf;
    const float* b = dir ? bbp : bf;

    float v[PT];
    float s1 = 0.f, s2 = 0.f;
#pragma unroll
    for (int i = 0; i < PT; i++) {
        float t = x[(size_t)row * DIM + tid + i * 256];
        v[i] = t; s1 += t; s2 += t * t;
    }
    for (int o = 32; o > 0; o >>= 1) { s1 += __shfl_xor(s1, o, 64); s2 += __shfl_xor(s2, o, 64); }
    __shared__ float r1[4], r2[4];
    int wv = tid >> 6;
    if ((tid & 63) == 0) { r1[wv] = s1; r2[wv] = s2; }
    __syncthreads();
    s1 = r1[0] + r1[1] + r1[2] + r1[3];
    s2 = r2[0] + r2[1] + r2[2] + r2[3];
    float mu  = s1 / DIM;
    float var = s2 / DIM - mu * mu;
    float rr  = rsqrtf(var + 1e-5f);
#pragma unroll
    for (int i = 0; i < PT; i++) {
        int c = tid + i * 256;
        float o = (v[i] - mu) * rr * w[c] + b[c];
        if (OBF) ((unsigned short*)outv)[(size_t)row * DIM + c] = f2bf(o);
        else     ((float*)outv)[(size_t)row * DIM + c] = o;
    }
}

// ---------------------------------------------------------------- MFMA GEMM -
// C = A @ B (+bias)(+epilogue). A bf16 [M][lda], B^T bf16 [N][K].
// r15: bijective XCD-aware block swizzle. R5 counters showed the big GEMMs
// HBM-bound at 141 MB FETCH vs ~10 MB unique A: the 8-16 blocks sharing an
// A row-panel are consecutive linear IDs -> round-robined across 8 XCD L2s
// -> each panel fetched ~8x. swz = (lin%8)*(nwg/8) + lin/8 gives XCD k a
// contiguous run of row panels so panel-sharing blocks hit one L2. All
// grids here have nwg % 8 == 0 (bijectivity).
template<int BM, int BN, int EPI, int ATR, int MODE, int OBF, int KB>
__global__ __launch_bounds__(256) void gemm_mfma(
    const unsigned short* __restrict__ A, int lda, int K,
    const unsigned short* __restrict__ Btf, const unsigned short* __restrict__ Btb,
    const float* __restrict__ biasf, const float* __restrict__ biasb,
    void* __restrict__ Cv, int ldc, unsigned short* __restrict__ Ct)
{
    constexpr int SK  = 40;              // padded LDS row stride (bf16 elems)
    constexpr int KT  = KB / 32;         // 32-wide sub-tiles per stage
    constexpr int CPR = KB / 8;          // 8-elem chunks per row
    constexpr int WM  = BM / 2, WN = BN / 2;
    constexpr int MT  = WM / 16, NT = WN / 16;
    constexpr int ASL = (BM * KB) / (256 * 8);
    constexpr int BSL = (BN * KB) / (256 * 8);
    constexpr int MB4 = BM / 4;
    constexpr int ATR_TH = (BM / 4) * (KB / 4);
    constexpr int ATR_R  = (ATR_TH + 255) / 256;

    __shared__ unsigned short As[KT * BM * SK];
    __shared__ unsigned short Bs[KT * BN * SK];

    const int tid  = threadIdx.x;
    // ---- XCD swizzle (T1, bijective: nwg % 8 == 0 for every launch here) --
    const int gx   = gridDim.x;
    const int nwg  = gx * gridDim.y;
    const int lin  = blockIdx.x + blockIdx.y * gx;
    const int swz  = (lin & 7) * (nwg >> 3) + (lin >> 3);
    const int by   = swz / gx;
    const int bx   = swz - by * gx;
    const int n0   = bx * BN;
    const int row0 = by * BM;
    const int dir  = (row0 >= kMDIR) ? 1 : 0;
    const unsigned short* __restrict__ Bt = dir ? Btb : Btf;
    const float* bias = dir ? biasb : biasf;

    const int lane = tid & 63;
    const int wave = tid >> 6;
    const int wr = wave >> 1, wc = wave & 1;
    const int ml = lane & 15, q = lane >> 4;

    f32x4 acc[MT][NT];
#pragma unroll
    for (int i = 0; i < MT; i++)
#pragma unroll
        for (int j = 0; j < NT; j++)
#pragma unroll
            for (int r = 0; r < 4; r++) acc[i][j][r] = 0.f;

    for (int kt = 0; kt < K; kt += KB) {
        // ---- global loads ----
        bf16x8 a_ld[ASL ? ASL : 1];
        bf16x4 at_ld[ATR_R][4];
        if (!ATR) {
#pragma unroll
            for (int r = 0; r < ASL; r++) {
                int i = tid + r * 256;
                int m = i / CPR, c8 = (i % CPR) * 8;
                a_ld[r] = *(const bf16x8*)(A + (size_t)(row0 + m) * lda + kt + c8);
            }
        } else {
#pragma unroll
            for (int r = 0; r < ATR_R; r++) {
                int idx = tid + r * 256;
                if (idx < ATR_TH) {
                    int mb = idx % MB4, ka = idx / MB4;
#pragma unroll
                    for (int j = 0; j < 4; j++)
                        at_ld[r][j] = *(const bf16x4*)(A + (size_t)(kt + ka * 4 + j) * lda + row0 + mb * 4);
                }
            }
        }
        bf16x8 b_ld[BSL ? BSL : 1];
#pragma unroll
        for (int r = 0; r < BSL; r++) {
            int i = tid + r * 256;
            int n = i / CPR, c8 = (i % CPR) * 8;
            b_ld[r] = *(const bf16x8*)(Bt + (size_t)(n0 + n) * K + kt + c8);
        }
        __syncthreads();     // previous iteration's LDS reads complete
        // ---- LDS writes ----
        if (!ATR) {
#pragma unroll
            for (int r = 0; r < ASL; r++) {
                int i = tid + r * 256;
                int m = i / CPR, c8 = (i % CPR) * 8;
                *(bf16x8*)&As[((c8 >> 5) * BM + m) * SK + (c8 & 31)] = a_ld[r];
            }
        } else {
#pragma unroll
            for (int r = 0; r < ATR_R; r++) {
                int idx = tid + r * 256;
                if (idx < ATR_TH) {
                    int mb = idx % MB4, ka = idx / MB4;
                    union { bf16x4 v; unsigned short u[4]; } rw4[4];
#pragma unroll
                    for (int j = 0; j < 4; j++) rw4[j].v = at_ld[r][j];
                    int col = ka * 4;
#pragma unroll
                    for (int mp = 0; mp < 4; mp++) {
                        union { unsigned short u[4]; bf16x4 v; } cl;
#pragma unroll
                        for (int j = 0; j < 4; j++) cl.u[j] = rw4[j].u[mp];
                        *(bf16x4*)&As[((col >> 5) * BM + mb * 4 + mp) * SK + (col & 31)] = cl.v;
                    }
                }
            }
        }
#pragma unroll
        for (int r = 0; r < BSL; r++) {
            int i = tid + r * 256;
            int n = i / CPR, c8 = (i % CPR) * 8;
            *(bf16x8*)&Bs[((c8 >> 5) * BN + n) * SK + (c8 & 31)] = b_ld[r];
        }
        __syncthreads();
        // ---- fragments + MFMA (KT sub-steps of K=32) ----
#pragma unroll
        for (int kk = 0; kk < KT; kk++) {
            bf16x8 af[MT], bfr[NT];
#pragma unroll
            for (int i = 0; i < MT; i++)
                af[i] = *(bf16x8*)&As[(kk * BM + wr * WM + i * 16 + ml) * SK + q * 8];
#pragma unroll
            for (int j = 0; j < NT; j++)
                bfr[j] = *(bf16x8*)&Bs[(kk * BN + wc * WN + j * 16 + ml) * SK + q * 8];
#pragma unroll
            for (int i = 0; i < MT; i++)
#pragma unroll
                for (int j = 0; j < NT; j++)
                    acc[i][j] = __builtin_amdgcn_mfma_f32_16x16x32_bf16(af[i], bfr[j], acc[i][j], 0, 0, 0);
        }
    }

    // ---- epilogue ----
    float* Cf = (float*)Cv;
    unsigned short* Cb = (unsigned short*)Cv;
#pragma unroll
    for (int j = 0; j < NT; j++) {
        int col = n0 + wc * WN + j * 16 + ml;
        float bv = 0.f;
        if (EPI == EPI_SOFTPLUS || EPI == EPI_GELU || EPI == EPI_RESID_BIAS || EPI == EPI_TANH)
            bv = bias[col];
#pragma unroll
        for (int i = 0; i < MT; i++) {
            int rw = row0 + wr * WM + i * 16 + q * 4;
            float v4[4];
#pragma unroll
            for (int r = 0; r < 4; r++) {
                float v = acc[i][j][r] + bv;
                if (EPI == EPI_SOFTPLUS) v = (v > 20.f) ? v : __logf(1.f + __expf(v));
                if (EPI == EPI_GELU)     v = 0.5f * v * (1.f + erff(v * 0.70710678118654752f));
                if (EPI == EPI_TANH)     v = tanhf(v);
                v4[r] = v;
            }
            if (MODE == MODE_GATE && n0 >= kDI) {
                // silu(z) -> gate row-major [row][kDI]
#pragma unroll
                for (int r = 0; r < 4; r++) {
                    float sv = v4[r] / (1.f + __expf(-v4[r]));
                    Ct[(size_t)(rw + r) * kDI + (col - kDI)] = f2bf(sv);
                }
            } else {
#pragma unroll
                for (int r = 0; r < 4; r++) {
                    size_t o = (size_t)(rw + r) * ldc + col;
                    if (EPI == EPI_RESID || EPI == EPI_RESID_BIAS) Cf[o] += v4[r];
                    else if (OBF) Cb[o] = f2bf(v4[r]);
                    else Cf[o] = v4[r];
                }
                if (MODE == MODE_DBL && col >= 32) {
                    float* F = (float*)Ct;          // dblF f32 [row][32]
#pragma unroll
                    for (int r = 0; r < 4; r++)
                        F[(size_t)(rw + r) * 32 + (col - 32)] = v4[r];
                }
            }
        }
    }
}

// ---------------------------------------------------------------- conv ------
// xb bf16 [row][kDI] (x-half) -> xh bf16 [row][kDI] = silu(causal conv + cb).
__global__ __launch_bounds__(256) void conv_k(const unsigned short* __restrict__ xb,
    const float* __restrict__ cwf, const float* __restrict__ cwb,
    const float* __restrict__ cbf, const float* __restrict__ cbb,
    unsigned short* __restrict__ xh)
{
    __shared__ float tl[67][33];
    const int t0 = blockIdx.x * 64, d0 = blockIdx.y * 32, bb = blockIdx.z;
    const int dir = bb >> 2;
    const float* cw = dir ? cwb : cwf;
    const float* cb = dir ? cbb : cbf;
    const int dl = threadIdx.x & 31, rl = threadIdx.x >> 5;
    const size_t base = (size_t)bb * kN * kDI + d0 + dl;
#pragma unroll
    for (int p = 0; p < 9; p++) {
        int r = p * 8 + rl;
        if (r < 67) {
            int ts = t0 + r - 3;
            tl[r][dl] = (ts >= 0) ? b2f(xb[base + (size_t)ts * kDI]) : 0.f;
        }
    }
    __syncthreads();
    const int gd = d0 + dl;
    float c0 = cw[gd*4+0], c1 = cw[gd*4+1], c2 = cw[gd*4+2], c3 = cw[gd*4+3];
    float bv = cb[gd];
#pragma unroll
    for (int jj = 0; jj < 8; jj++) {
        int tt = rl + 8 * jj;
        float acc = bv + c0*tl[tt][dl] + c1*tl[tt+1][dl] + c2*tl[tt+2][dl] + c3*tl[tt+3][dl];
        float o = acc / (1.f + __expf(-acc));
        xh[(size_t)(bb * kN + t0 + tt) * kDI + gd] = f2bf(o);
    }
}

// ---------------------------------------------------------------- scan ------
// r14 coalesced blocked scan (validated): h[16]-in-registers 3-pass
// decomposition, all streams [row][d] row-major.
constexpr int kG  = 32;           // groups per chain
constexpr int kTg = kN / kG;      // 32 timesteps per group

template<int PASS>
__global__ __launch_bounds__(256) void bscan_k(
    const unsigned short* __restrict__ dt,   // [row][kDI]
    const unsigned short* __restrict__ xh,   // [row][kDI]
    const unsigned short* __restrict__ gate, // [row][kDI]
    const float* __restrict__ dblF,          // [row][32] (B | C)
    unsigned short* __restrict__ y,          // [row][kDI]
    float* __restrict__ PL,                  // [bb][g][32 slots][kDI]
    const float* __restrict__ alogf, const float* __restrict__ alogb,
    const float* __restrict__ ddf,   const float* __restrict__ ddb)
{
    const int d  = blockIdx.x * 256 + threadIdx.x;   // 0..1023
    const int g  = blockIdx.y;                       // 0..31
    const int bb = blockIdx.z;                       // 0..7
    const int dir = bb >> 2;
    const float* alog = dir ? alogb : alogf;
    const float* ddp  = dir ? ddb  : ddf;

    float a2[16];
#pragma unroll
    for (int s = 0; s < 16; s += 4) {
        float4 al = *(const float4*)&alog[d * kDS + s];
        a2[s+0] = -__expf(al.x) * 1.44269504f;
        a2[s+1] = -__expf(al.y) * 1.44269504f;
        a2[s+2] = -__expf(al.z) * 1.44269504f;
        a2[s+3] = -__expf(al.w) * 1.44269504f;
    }

    const size_t plb = (size_t)(bb * kG + g) * 32 * kDI + d;   // slot stride kDI
    float h[16];
    if (PASS == 0) {
#pragma unroll
        for (int s = 0; s < 16; s++) h[s] = 0.f;
    } else {
#pragma unroll
        for (int s = 0; s < 16; s++) h[s] = PL[plb + (size_t)(16 + s) * kDI];
    }

    const int row0 = bb * kN + g * kTg;
    const unsigned short* pd = dt   + (size_t)row0 * kDI + d;
    const unsigned short* px = xh   + (size_t)row0 * kDI + d;
    const unsigned short* pg = gate + (size_t)row0 * kDI + d;
    const float* pbc = dblF + (size_t)row0 * 32;
    unsigned short* py = y + (size_t)row0 * kDI + d;
    const float ddv = ddp[d];
    float sdt = 0.f;

#pragma unroll 4
    for (int t = 0; t < kTg; t++) {
        float dtv = b2f(pd[(size_t)t * kDI]);
        float xvv = b2f(px[(size_t)t * kDI]);
        float dtx = dtv * xvv;
        const float* bc = pbc + t * 32;
        if (PASS == 0) {
            sdt += dtv;
#pragma unroll
            for (int s4 = 0; s4 < 4; s4++) {
                float4 Bq = *(const float4*)(bc + s4 * 4);
                h[s4*4+0] = __builtin_amdgcn_exp2f(dtv * a2[s4*4+0]) * h[s4*4+0] + dtx * Bq.x;
                h[s4*4+1] = __builtin_amdgcn_exp2f(dtv * a2[s4*4+1]) * h[s4*4+1] + dtx * Bq.y;
                h[s4*4+2] = __builtin_amdgcn_exp2f(dtv * a2[s4*4+2]) * h[s4*4+2] + dtx * Bq.z;
                h[s4*4+3] = __builtin_amdgcn_exp2f(dtv * a2[s4*4+3]) * h[s4*4+3] + dtx * Bq.w;
            }
        } else {
            float p = 0.f;
#pragma unroll
            for (int s4 = 0; s4 < 4; s4++) {
                float4 Bq = *(const float4*)(bc + s4 * 4);
                float4 Cq = *(const float4*)(bc + 16 + s4 * 4);
                h[s4*4+0] = __builtin_amdgcn_exp2f(dtv * a2[s4*4+0]) * h[s4*4+0] + dtx * Bq.x;
                p += h[s4*4+0] * Cq.x;
                h[s4*4+1] = __builtin_amdgcn_exp2f(dtv * a2[s4*4+1]) * h[s4*4+1] + dtx * Bq.y;
                p += h[s4*4+1] * Cq.y;
                h[s4*4+2] = __builtin_amdgcn_exp2f(dtv * a2[s4*4+2]) * h[s4*4+2] + dtx * Bq.z;
                p += h[s4*4+2] * Cq.z;
                h[s4*4+3] = __builtin_amdgcn_exp2f(dtv * a2[s4*4+3]) * h[s4*4+3] + dtx * Bq.w;
                p += h[s4*4+3] * Cq.w;
            }
            float gvv = b2f(pg[(size_t)t * kDI]);
            py[(size_t)t * kDI] = f2bf((p + ddv * xvv) * gvv);
        }
    }

    if (PASS == 0) {
#pragma unroll
        for (int s = 0; s < 16; s++) {
            PL[plb + (size_t)s * kDI]        = __builtin_amdgcn_exp2f(a2[s] * sdt);
            PL[plb + (size_t)(16 + s) * kDI] = h[s];
        }
    }
}

// boundary fix: h_in[chain][g] = scan of (P,L) over groups; rewrites L slot.
__global__ __launch_bounds__(256) void bfix_k(float* __restrict__ PL)
{
    const int idx = blockIdx.x * 256 + threadIdx.x;  // 16 s x 8 bb x 1024 d
    const int d  = idx & (kDI - 1);
    const int bb = (idx >> 10) & 7;
    const int s  = idx >> 13;
    float h = 0.f;
    for (int g = 0; g < kG; g++) {
        size_t base = (size_t)(bb * kG + g) * 32 * kDI + d;
        float P = PL[base + (size_t)s * kDI];
        float L = PL[base + (size_t)(16 + s) * kDI];
        PL[base + (size_t)(16 + s) * kDI] = h;   // h_in for pass C
        h = P * h + L;
    }
}

// ---------------------------------------------------------------- attention -
__global__ __launch_bounds__(64) void att_score_k(const unsigned short* __restrict__ tmp,
    const float* __restrict__ aw2, const float* __restrict__ ab2,
    float* __restrict__ score)
{
    int row = blockIdx.x, lane = threadIdx.x;
    float acc = 0.f;
#pragma unroll
    for (int j = 0; j < 4; j++)
        acc += b2f(tmp[(size_t)row * 256 + lane + j * 64]) * aw2[lane + j * 64];
    for (int o = 32; o > 0; o >>= 1) acc += __shfl_xor(acc, o, 64);
    if (lane == 0) score[row] = acc + ab2[0];
}

__global__ __launch_bounds__(256) void softmax_k(const float* __restrict__ score,
                                                 float* __restrict__ w)
{
    int bb = blockIdx.x, tid = threadIdx.x;
    float v[4]; float m = -1e30f;
#pragma unroll
    for (int i = 0; i < 4; i++) { v[i] = score[bb * kN + tid + i * 256]; m = fmaxf(m, v[i]); }
    for (int o = 32; o > 0; o >>= 1) m = fmaxf(m, __shfl_xor(m, o, 64));
    __shared__ float r1[4], r2[4];
    int wv = tid >> 6;
    if ((tid & 63) == 0) r1[wv] = m;
    __syncthreads();
    m = fmaxf(fmaxf(r1[0], r1[1]), fmaxf(r1[2], r1[3]));
    float s = 0.f;
#pragma unroll
    for (int i = 0; i < 4; i++) { v[i] = __expf(v[i] - m); s += v[i]; }
    for (int o = 32; o > 0; o >>= 1) s += __shfl_xor(s, o, 64);
    if ((tid & 63) == 0) r2[wv] = s;
    __syncthreads();
    s = r2[0] + r2[1] + r2[2] + r2[3];
    float inv = 1.f / s;
#pragma unroll
    for (int i = 0; i < 4; i++) w[bb * kN + tid + i * 256] = v[i] * inv;
}

__global__ __launch_bounds__(512) void pool_k(const float* __restrict__ w,
    const float* __restrict__ h, float* zcat)
{
    int bb = blockIdx.x, chunk = blockIdx.y;   // 8 x 32
    int d = threadIdx.x;
    float acc = 0.f;
    int n0 = chunk * 32;
    for (int n = n0; n < n0 + 32; n++)
        acc += w[bb * kN + n] * h[((size_t)bb * kN + n) * kDM + d];
    int b = bb & 3, dir = bb >> 2;
    atomicAdd(&zcat[b * (2 * kDM) + dir * kDM + d], acc);
}

__global__ __launch_bounds__(256) void att_out_k(const float* __restrict__ w,
                                                 float* __restrict__ out)
{
    int idx = blockIdx.x * 256 + threadIdx.x;  // kB*kN
    int b = idx >> 10, n = idx & 1023;
    out[idx] = 0.5f * (w[b * kN + n] + w[(b + 4) * kN + (kN - 1 - n)]);
}

// ---------------------------------------------------------------- launch ----
extern "C" void kernel_launch(void* const* d_in, const int* in_sizes, int n_in,
                              void* d_out, int out_size, void* d_ws, size_t ws_size,
                              hipStream_t stream)
{
    const float* x = (const float*)d_in[0];
    const float* fp[17]; const float* bp[17];
    for (int i = 0; i < 17; i++) { fp[i] = (const float*)d_in[1 + i]; bp[i] = (const float*)d_in[18 + i]; }
    const float* aw1 = (const float*)d_in[35];
    const float* ab1 = (const float*)d_in[36];
    const float* aw2 = (const float*)d_in[37];
    const float* ab2 = (const float*)d_in[38];
    const float* nw  = (const float*)d_in[39];
    const float* nb  = (const float*)d_in[40];
    float* out = (float*)d_out;

    float* h = (float*)d_ws;                                   // 8192*512 f32
    unsigned short* ub    = (unsigned short*)(h + (size_t)kROWS * kDM);  // 8192*512
    unsigned short* xbuf  = ub    + (size_t)kROWS * kDM;        // 8192*1024 (x-half / y / ffn1 lo)
    unsigned short* tbuf  = xbuf  + (size_t)kROWS * kDI;        // 8192*1024 (dt / ffn1 hi / hb)
    unsigned short* xhb   = tbuf  + (size_t)kROWS * kDI;        // 8192*1024 (xh row-major)
    unsigned short* gateb = xhb   + (size_t)kROWS * kDI;        // 8192*1024 (gate row-major)
    unsigned short* dbl   = gateb + (size_t)kROWS * kDI;        // 8192*64 bf16
    float* dblF  = (float*)(dbl + (size_t)kROWS * 64);          // 8192*32 f32 (B/C)
    float* score = dblF + (size_t)kROWS * 32;                   // 8192
    float* smw   = score + kROWS;                               // 8192
    float* zcat  = smw   + kROWS;                               // 4096
    unsigned short* wts  = (unsigned short*)(zcat + kB * 2 * kDM);
    float* PL = (float*)(wts + O_WTOT);                         // 8*32*32*1024 f32 = 32MB

    // ---- weight prep: fp32 [L][K][N] -> bf16 [L][N][K] (one launch) ----
    WJobs jobs;
    jobs.s[0] = fp[2];  jobs.s[1] = bp[2];
    jobs.s[2] = fp[5];  jobs.s[3] = bp[5];
    jobs.s[4] = fp[6];  jobs.s[5] = bp[6];
    jobs.s[6] = fp[10]; jobs.s[7] = bp[10];
    jobs.s[8] = fp[13]; jobs.s[9] = bp[13];
    jobs.s[10] = fp[15]; jobs.s[11] = bp[15];
    jobs.s[12] = aw1;
    int wblocks = 0;
    {
        const int wK[13] = {512,512,1024,1024,32,32,1024,1024,512,512,2048,2048,512};
        const int wN[13] = {2048,2048,64,64,1024,1024,512,512,2048,2048,512,512,256};
        const int wL[13] = {2,2,2,2,2,2,2,2,2,2,2,2,1};
        for (int j = 0; j < 13; j++) wblocks += wL[j] * (wK[j]/32) * (wN[j]/32);
    }
    wprep_k<<<wblocks, 256, 0, stream>>>(jobs, wts);

    init_h_k<<<kROWS * kDM / 256, 256, 0, stream>>>(x, h);

    for (int l = 0; l < kL; l++) {
        const float *f_n1w = fp[0]  + l * kDM,            *b_n1w = bp[0]  + l * kDM;
        const float *f_n1b = fp[1]  + l * kDM,            *b_n1b = bp[1]  + l * kDM;
        const float *f_cw  = fp[3]  + l * kDI * kDC,      *b_cw  = bp[3]  + l * kDI * kDC;
        const float *f_cb  = fp[4]  + l * kDI,            *b_cb  = bp[4]  + l * kDI;
        const float *f_dtb = fp[7]  + l * kDI,            *b_dtb = bp[7]  + l * kDI;
        const float *f_alog= fp[8]  + l * kDI * kDS,      *b_alog= bp[8]  + l * kDI * kDS;
        const float *f_dd  = fp[9]  + l * kDI,            *b_dd  = bp[9]  + l * kDI;
        const float *f_n2w = fp[11] + l * kDM,            *b_n2w = bp[11] + l * kDM;
        const float *f_n2b = fp[12] + l * kDM,            *b_n2b = bp[12] + l * kDM;
        const float *f_b1  = fp[14] + l * 4 * kDM,        *b_b1  = bp[14] + l * 4 * kDM;
        const float *f_b2  = fp[16] + l * kDM,            *b_b2  = bp[16] + l * kDM;

        const unsigned short *wInwF = wts + O_INW_F + (size_t)l * 2048 * 512;
        const unsigned short *wInwB = wts + O_INW_B + (size_t)l * 2048 * 512;
        const unsigned short *wXpwF = wts + O_XPW_F + (size_t)l * 64 * 1024;
        const unsigned short *wXpwB = wts + O_XPW_B + (size_t)l * 64 * 1024;
        const unsigned short *wDtwF = wts + O_DTW_F + (size_t)l * 1024 * 32;
        const unsigned short *wDtwB = wts + O_DTW_B + (size_t)l * 1024 * 32;
        const unsigned short *wOwF  = wts + O_OW_F  + (size_t)l * 512 * 1024;
        const unsigned short *wOwB  = wts + O_OW_B  + (size_t)l * 512 * 1024;
        const unsigned short *wW1F  = wts + O_W1_F  + (size_t)l * 2048 * 512;
        const unsigned short *wW1B  = wts + O_W1_B  + (size_t)l * 2048 * 512;
        const unsigned short *wW2F  = wts + O_W2_F  + (size_t)l * 512 * 2048;
        const unsigned short *wW2B  = wts + O_W2_B  + (size_t)l * 512 * 2048;

        // u = LN1(h) -> bf16
        ln_k<kDM,1><<<kROWS, 256, 0, stream>>>(h, f_n1w, b_n1w, f_n1b, b_n1b, ub);
        // x-half -> xbuf bf16 [row][kDI]; z-half -> gateb = silu(z) row-major
        gemm_mfma<128,128,EPI_NONE,0,MODE_GATE,1,64><<<dim3(16, 64), 256, 0, stream>>>(
            ub, kDM, kDM, wInwF, wInwB, nullptr, nullptr, xbuf, kDI, gateb);
        // xh[row][kDI] = silu(conv(xbuf) + cb)  (row-major, no transpose)
        conv_k<<<dim3(kN/64, kDI/32, kB2), 256, 0, stream>>>(
            xbuf, f_cw, b_cw, f_cb, b_cb, xhb);
        // dbl = xh @ xpw (A row-major); cols>=32 also -> dblF f32 [row][32]
        gemm_mfma<32,64,EPI_NONE,0,MODE_DBL,1,64><<<dim3(1, 256), 256, 0, stream>>>(
            xhb, kDI, kDI, wXpwF, wXpwB, nullptr, nullptr, dbl, 64, (unsigned short*)dblF);
        // dt[row][kDI] = softplus(dbl[:, :32] @ dtw + dtb)  (row-major)
        gemm_mfma<128,128,EPI_SOFTPLUS,0,MODE_N,1,32><<<dim3(8, 64), 256, 0, stream>>>(
            dbl, 64, kDTR, wDtwF, wDtwB, f_dtb, b_dtb, tbuf, kDI, nullptr);
        // blocked scan: local pass -> boundary fix -> full pass (y into xbuf)
        bscan_k<0><<<dim3(kDI/256, kG, kB2), 256, 0, stream>>>(
            tbuf, xhb, gateb, dblF, xbuf, PL, f_alog, b_alog, f_dd, b_dd);
        bfix_k<<<kB2 * kDI * kDS / 256, 256, 0, stream>>>(PL);
        bscan_k<1><<<dim3(kDI/256, kG, kB2), 256, 0, stream>>>(
            tbuf, xhb, gateb, dblF, xbuf, PL, f_alog, b_alog, f_dd, b_dd);
        // h += y @ ow  (A = y row-major)
        gemm_mfma<128,64,EPI_RESID,0,MODE_N,0,64><<<dim3(8, 64), 256, 0, stream>>>(
            xbuf, kDI, kDI, wOwF, wOwB, nullptr, nullptr, h, kDM, nullptr);
        // u = LN2(h) -> bf16
        ln_k<kDM,1><<<kROWS, 256, 0, stream>>>(h, f_n2w, b_n2w, f_n2b, b_n2b, ub);
        // ffn1: gelu(u @ w1 + b1) -> xbuf..tbuf slab bf16 (8192 x 2048)
        gemm_mfma<128,128,EPI_GELU,0,MODE_N,1,64><<<dim3(16, 64), 256, 0, stream>>>(
            ub, kDM, kDM, wW1F, wW1B, f_b1, b_b1, xbuf, 4*kDM, nullptr);
        // h += ffn1 @ w2 + b2  (128x64 tile -> 512 blocks)
        gemm_mfma<128,64,EPI_RESID_BIAS,0,MODE_N,0,64><<<dim3(8, 64), 256, 0, stream>>>(
            xbuf, 4*kDM, 4*kDM, wW2F, wW2B, f_b2, b_b2, h, kDM, nullptr);
    }

    // attention: hb = bf16(h); u = tanh(hb @ aw1 + ab1) bf16
    h2b_k<<<kROWS * kDM / 256, 256, 0, stream>>>(h, tbuf);
    // 64x128 tile -> 256 blocks
    gemm_mfma<64,128,EPI_TANH,0,MODE_N,1,64><<<dim3(2, 128), 256, 0, stream>>>(
        tbuf, kDM, kDM, wts + O_AW1, wts + O_AW1, ab1, ab1, ub, 256, nullptr);
    att_score_k<<<kROWS, 64, 0, stream>>>(ub, aw2, ab2, score);
    softmax_k<<<kB2, 256, 0, stream>>>(score, smw);
    hipMemsetAsync(zcat, 0, kB * 2 * kDM * sizeof(float), stream);
    pool_k<<<dim3(kB2, 32), 512, 0, stream>>>(smw, h, zcat);
    // out[0:4096] = LN(concat(zf, zb))
    ln_k<2*kDM,0><<<kB, 256, 0, stream>>>(zcat, nw, nw, nb, nb, out);
    // out[4096:8192] = 0.5*(af + flip(ab))
    att_out_k<<<kB * kN / 256, 256, 0, stream>>>(smw, out + kB * 2 * kDM);
}

// Round 7
// 711.553 us; speedup vs baseline: 1.3162x; 1.0228x over previous
//
#include <hip/hip_runtime.h>
#include <math.h>

constexpr int kDM   = 512;
constexpr int kDI   = 1024;
constexpr int kDS   = 16;
constexpr int kDC   = 4;
constexpr int kDTR  = 32;
constexpr int kL    = 2;
constexpr int kB    = 4;
constexpr int kN    = 1024;
constexpr int kB2   = 8;              // combined batch: rows 0-3 fwd, 4-7 bwd
constexpr int kROWS = kB2 * kN;       // 8192
constexpr int kMDIR = kB * kN;        // 4096 rows per direction

enum { EPI_NONE=0, EPI_SOFTPLUS=1, EPI_RESID=2, EPI_GELU=3, EPI_RESID_BIAS=4, EPI_TANH=5 };
enum { MODE_N=0, MODE_OTR=1, MODE_DBL=2, MODE_GATE=3 };

typedef __attribute__((ext_vector_type(8))) short bf16x8;
typedef __attribute__((ext_vector_type(4))) short bf16x4;
typedef __attribute__((ext_vector_type(4))) float f32x4;

__device__ __forceinline__ unsigned short f2bf(float f) {
    unsigned int u = __float_as_uint(f);
    return (unsigned short)((u + 0x7FFFu + ((u >> 16) & 1u)) >> 16);
}
__device__ __forceinline__ float b2f(unsigned short u) {
    return __uint_as_float((unsigned int)u << 16);
}

// global -> LDS 16-B DMA (one instruction, no VGPR round-trip)
#define GLD_LDS16(gsrc, ldst) \
    __builtin_amdgcn_global_load_lds((const __attribute__((address_space(1))) void*)(gsrc), \
                                     (__attribute__((address_space(3))) void*)(ldst), 16, 0, 0)

// ------------------------------------------------------- weight prep --------
struct WJobs { const float* s[13]; };
// job order: f_inw b_inw f_xpw b_xpw f_dtw b_dtw f_ow b_ow f_w1 b_w1 f_w2 b_w2 aw1
constexpr size_t O_INW_F = 0;
constexpr size_t O_INW_B = O_INW_F + 2u*512*2048;
constexpr size_t O_XPW_F = O_INW_B + 2u*512*2048;
constexpr size_t O_XPW_B = O_XPW_F + 2u*1024*64;
constexpr size_t O_DTW_F = O_XPW_B + 2u*1024*64;
constexpr size_t O_DTW_B = O_DTW_F + 2u*32*1024;
constexpr size_t O_OW_F  = O_DTW_B + 2u*32*1024;
constexpr size_t O_OW_B  = O_OW_F  + 2u*1024*512;
constexpr size_t O_W1_F  = O_OW_B  + 2u*1024*512;
constexpr size_t O_W1_B  = O_W1_F  + 2u*512*2048;
constexpr size_t O_W2_F  = O_W1_B  + 2u*512*2048;
constexpr size_t O_W2_B  = O_W2_F  + 2u*2048*512;
constexpr size_t O_AW1   = O_W2_B  + 2u*2048*512;
constexpr size_t O_WTOT  = O_AW1   + 1u*512*256;

__global__ __launch_bounds__(256) void wprep_k(WJobs jobs, unsigned short* __restrict__ dst)
{
    const int wK[13] = {512,512,1024,1024,32,32,1024,1024,512,512,2048,2048,512};
    const int wN[13] = {2048,2048,64,64,1024,1024,512,512,2048,2048,512,512,256};
    const int wL[13] = {2,2,2,2,2,2,2,2,2,2,2,2,1};
    int blk = blockIdx.x;
    int j = 0; int base = 0; size_t doff = 0;
    for (; j < 13; j++) {
        int nb = wL[j] * (wK[j] / 32) * (wN[j] / 32);
        if (blk < base + nb) break;
        base += nb;
        doff += (size_t)wL[j] * wK[j] * wN[j];
    }
    int rel = blk - base;
    int K = wK[j], N = wN[j];
    int tk = K / 32, tn = N / 32;
    int l = rel / (tk * tn); rel -= l * tk * tn;
    int kt = rel / tn, nt = rel - (rel / tn) * tn;
    const float* src = jobs.s[j] + (size_t)l * K * N;
    unsigned short* d = dst + doff + (size_t)l * K * N;
    __shared__ float tl[32][33];
    const int c = threadIdx.x & 31, rg = threadIdx.x >> 5;
#pragma unroll
    for (int rr = 0; rr < 4; rr++)
        tl[rg * 4 + rr][c] = src[(size_t)(kt * 32 + rg * 4 + rr) * N + nt * 32 + c];
    __syncthreads();
#pragma unroll
    for (int rr = 0; rr < 4; rr++)
        d[(size_t)(nt * 32 + rg * 4 + rr) * K + kt * 32 + c] = f2bf(tl[c][rg * 4 + rr]);
}

// ---------------------------------------------------------------- init h ----
__global__ __launch_bounds__(256) void init_h_k(const float* __restrict__ x,
                                                float* __restrict__ h)
{
    size_t idx = (size_t)blockIdx.x * 256 + threadIdx.x;   // kROWS*kDM
    int d  = idx & (kDM - 1);
    int t  = (idx >> 9) & (kN - 1);
    int bb = (int)(idx >> 19);
    int b = bb & 3, dir = bb >> 2;
    int ts = dir ? (kN - 1 - t) : t;
    h[idx] = x[((size_t)b * kN + ts) * kDM + d];
}

__global__ __launch_bounds__(256) void h2b_k(const float* __restrict__ h,
                                             unsigned short* __restrict__ o)
{
    size_t idx = (size_t)blockIdx.x * 256 + threadIdx.x;
    o[idx] = f2bf(h[idx]);
}

// ---------------------------------------------------------------- layernorm --
template<int DIM, int OBF>
__global__ __launch_bounds__(256) void ln_k(const float* __restrict__ x,
    const float* __restrict__ wf, const float* __restrict__ wb,
    const float* __restrict__ bf, const float* __restrict__ bbp,
    void* __restrict__ outv)
{
    const int row = blockIdx.x;
    const int tid = threadIdx.x;
    constexpr int PT = DIM / 256;
    const int dir = (row >= kMDIR) ? 1 : 0;
    const float* w = dir ? wb : wf;
    const float* b = dir ? bbp : bf;

    float v[PT];
    float s1 = 0.f, s2 = 0.f;
#pragma unroll
    for (int i = 0; i < PT; i++) {
        float t = x[(size_t)row * DIM + tid + i * 256];
        v[i] = t; s1 += t; s2 += t * t;
    }
    for (int o = 32; o > 0; o >>= 1) { s1 += __shfl_xor(s1, o, 64); s2 += __shfl_xor(s2, o, 64); }
    __shared__ float r1[4], r2[4];
    int wv = tid >> 6;
    if ((tid & 63) == 0) { r1[wv] = s1; r2[wv] = s2; }
    __syncthreads();
    s1 = r1[0] + r1[1] + r1[2] + r1[3];
    s2 = r2[0] + r2[1] + r2[2] + r2[3];
    float mu  = s1 / DIM;
    float var = s2 / DIM - mu * mu;
    float rr  = rsqrtf(var + 1e-5f);
#pragma unroll
    for (int i = 0; i < PT; i++) {
        int c = tid + i * 256;
        float o = (v[i] - mu) * rr * w[c] + b[c];
        if (OBF) ((unsigned short*)outv)[(size_t)row * DIM + c] = f2bf(o);
        else     ((float*)outv)[(size_t)row * DIM + c] = o;
    }
}

// ---------------------------------------------------------------- MFMA GEMM -
// C = A @ B (+bias)(+epilogue). A bf16 [M][lda], B^T bf16 [N][K].
// r16 (KB==64 path): m97-structure staging -- global_load_lds width-16 DMA
// into LINEAR LDS (32 KB, no pad) with the G4 XOR swizzle byte^=((row&7)<<4)
// realized by pre-swizzling the per-lane GLOBAL source address (m173: linear
// DMA dest + inverse-swz source + swz on ds_read). Per-lane source offsets
// are K-invariant -> in-loop staging = 8 pointer adds + 8 DMA issues (was
// ~200 VALU of reg-staging addr calc + LDS writes at SK=40). R6 counters:
// 45.5us, MfmaUtil 13.6%, VALUBusy 36.5%, 4.2M LDS conflicts = the reg-
// staging tax; m151 measured this exact switch 646->874 TF at 128^2.
// KB==32 (dtw only) keeps the old reg-staging path.
template<int BM, int BN, int EPI, int ATR, int MODE, int OBF, int KB>
__global__ __launch_bounds__(256) void gemm_mfma(
    const unsigned short* __restrict__ A, int lda, int K,
    const unsigned short* __restrict__ Btf, const unsigned short* __restrict__ Btb,
    const float* __restrict__ biasf, const float* __restrict__ biasb,
    void* __restrict__ Cv, int ldc, unsigned short* __restrict__ Ct)
{
    constexpr int SK  = 40;              // padded LDS row stride (old path)
    constexpr int KT  = KB / 32;         // 32-wide sub-tiles per stage
    constexpr int CPR = KB / 8;          // 8-elem chunks per row (old path)
    constexpr int WM  = BM / 2, WN = BN / 2;
    constexpr int MT  = WM / 16, NT = WN / 16;
    constexpr int ASL = (BM * KB) / (256 * 8);
    constexpr int BSL = (BN * KB) / (256 * 8);
    constexpr int ASZ = (KB == 64) ? BM * 64 : KT * BM * SK;
    constexpr int BSZ = (KB == 64) ? BN * 64 : KT * BN * SK;

    __shared__ __align__(16) unsigned short As[ASZ];
    __shared__ __align__(16) unsigned short Bs[BSZ];

    const int tid  = threadIdx.x;
    // ---- XCD swizzle (T1, bijective: nwg % 8 == 0 for every launch here) --
    const int gx   = gridDim.x;
    const int nwg  = gx * gridDim.y;
    const int lin  = blockIdx.x + blockIdx.y * gx;
    const int swz  = (lin & 7) * (nwg >> 3) + (lin >> 3);
    const int by   = swz / gx;
    const int bx   = swz - by * gx;
    const int n0   = bx * BN;
    const int row0 = by * BM;
    const int dir  = (row0 >= kMDIR) ? 1 : 0;
    const unsigned short* __restrict__ Bt = dir ? Btb : Btf;
    const float* bias = dir ? biasb : biasf;

    const int lane = tid & 63;
    const int wave = tid >> 6;
    const int wr = wave >> 1, wc = wave & 1;
    const int ml = lane & 15, q = lane >> 4;

    f32x4 acc[MT][NT];
#pragma unroll
    for (int i = 0; i < MT; i++)
#pragma unroll
        for (int j = 0; j < NT; j++)
#pragma unroll
            for (int r = 0; r < 4; r++) acc[i][j][r] = 0.f;

    if constexpr (KB == 64) {
        // ---- m97-structure K-loop: DMA staging + swizzled linear LDS ----
        constexpr int ACW = BM / 32;     // 1-KB chunks per wave (A)
        constexpr int BCW = BN / 32;     // 1-KB chunks per wave (B)
        const int lrow = lane >> 3;                       // 0..7 row in chunk
        const int lcol = ((lane & 7) ^ (lrow & 7)) << 4;  // pre-swizzled col byte
        const char* aS[ACW ? ACW : 1];
        const char* bS[BCW ? BCW : 1];
#pragma unroll
        for (int ch = 0; ch < ACW; ch++) {
            const int chunk = wave * ACW + ch;
            aS[ch] = (const char*)A + (size_t)(row0 + chunk * 8 + lrow) * lda * 2 + lcol;
        }
#pragma unroll
        for (int ch = 0; ch < BCW; ch++) {
            const int chunk = wave * BCW + ch;
            bS[ch] = (const char*)Bt + (size_t)(n0 + chunk * 8 + lrow) * K * 2 + lcol;
        }
        const int axor = (ml & 7) << 3;  // read-side swizzle (ushort units)

        for (int kt = 0; kt < K; kt += 64) {
#pragma unroll
            for (int ch = 0; ch < ACW; ch++) {
                GLD_LDS16(aS[ch], &As[(wave * ACW + ch) * 512]);
                aS[ch] += 128;
            }
#pragma unroll
            for (int ch = 0; ch < BCW; ch++) {
                GLD_LDS16(bS[ch], &Bs[(wave * BCW + ch) * 512]);
                bS[ch] += 128;
            }
            __syncthreads();             // drains vmcnt(0): DMA data visible
#pragma unroll
            for (int kk = 0; kk < 2; kk++) {
                bf16x8 af[MT], bfr[NT];
#pragma unroll
                for (int i = 0; i < MT; i++)
                    af[i] = *(bf16x8*)&As[(wr * WM + i * 16 + ml) * 64 + ((kk * 32 + q * 8) ^ axor)];
#pragma unroll
                for (int j = 0; j < NT; j++)
                    bfr[j] = *(bf16x8*)&Bs[(wc * WN + j * 16 + ml) * 64 + ((kk * 32 + q * 8) ^ axor)];
#pragma unroll
                for (int i = 0; i < MT; i++)
#pragma unroll
                    for (int j = 0; j < NT; j++)
                        acc[i][j] = __builtin_amdgcn_mfma_f32_16x16x32_bf16(af[i], bfr[j], acc[i][j], 0, 0, 0);
            }
            __syncthreads();             // all reads done before next DMA
        }
    } else {
        // ---- old reg-staging path (KB==32: dtw GEMM only) ----
        for (int kt = 0; kt < K; kt += KB) {
            bf16x8 a_ld[ASL ? ASL : 1];
#pragma unroll
            for (int r = 0; r < ASL; r++) {
                int i = tid + r * 256;
                int m = i / CPR, c8 = (i % CPR) * 8;
                a_ld[r] = *(const bf16x8*)(A + (size_t)(row0 + m) * lda + kt + c8);
            }
            bf16x8 b_ld[BSL ? BSL : 1];
#pragma unroll
            for (int r = 0; r < BSL; r++) {
                int i = tid + r * 256;
                int n = i / CPR, c8 = (i % CPR) * 8;
                b_ld[r] = *(const bf16x8*)(Bt + (size_t)(n0 + n) * K + kt + c8);
            }
            __syncthreads();
#pragma unroll
            for (int r = 0; r < ASL; r++) {
                int i = tid + r * 256;
                int m = i / CPR, c8 = (i % CPR) * 8;
                *(bf16x8*)&As[((c8 >> 5) * BM + m) * SK + (c8 & 31)] = a_ld[r];
            }
#pragma unroll
            for (int r = 0; r < BSL; r++) {
                int i = tid + r * 256;
                int n = i / CPR, c8 = (i % CPR) * 8;
                *(bf16x8*)&Bs[((c8 >> 5) * BN + n) * SK + (c8 & 31)] = b_ld[r];
            }
            __syncthreads();
#pragma unroll
            for (int kk = 0; kk < KT; kk++) {
                bf16x8 af[MT], bfr[NT];
#pragma unroll
                for (int i = 0; i < MT; i++)
                    af[i] = *(bf16x8*)&As[(kk * BM + wr * WM + i * 16 + ml) * SK + q * 8];
#pragma unroll
                for (int j = 0; j < NT; j++)
                    bfr[j] = *(bf16x8*)&Bs[(kk * BN + wc * WN + j * 16 + ml) * SK + q * 8];
#pragma unroll
                for (int i = 0; i < MT; i++)
#pragma unroll
                    for (int j = 0; j < NT; j++)
                        acc[i][j] = __builtin_amdgcn_mfma_f32_16x16x32_bf16(af[i], bfr[j], acc[i][j], 0, 0, 0);
            }
            __syncthreads();
        }
    }

    // ---- epilogue ----
    float* Cf = (float*)Cv;
    unsigned short* Cb = (unsigned short*)Cv;
#pragma unroll
    for (int j = 0; j < NT; j++) {
        int col = n0 + wc * WN + j * 16 + ml;
        float bv = 0.f;
        if (EPI == EPI_SOFTPLUS || EPI == EPI_GELU || EPI == EPI_RESID_BIAS || EPI == EPI_TANH)
            bv = bias[col];
#pragma unroll
        for (int i = 0; i < MT; i++) {
            int rw = row0 + wr * WM + i * 16 + q * 4;
            float v4[4];
#pragma unroll
            for (int r = 0; r < 4; r++) {
                float v = acc[i][j][r] + bv;
                if (EPI == EPI_SOFTPLUS) v = (v > 20.f) ? v : __logf(1.f + __expf(v));
                if (EPI == EPI_GELU)     v = 0.5f * v * (1.f + erff(v * 0.70710678118654752f));
                if (EPI == EPI_TANH)     v = tanhf(v);
                v4[r] = v;
            }
            if (MODE == MODE_GATE && n0 >= kDI) {
                // silu(z) -> gate row-major [row][kDI]
#pragma unroll
                for (int r = 0; r < 4; r++) {
                    float sv = v4[r] / (1.f + __expf(-v4[r]));
                    Ct[(size_t)(rw + r) * kDI + (col - kDI)] = f2bf(sv);
                }
            } else {
#pragma unroll
                for (int r = 0; r < 4; r++) {
                    size_t o = (size_t)(rw + r) * ldc + col;
                    if (EPI == EPI_RESID || EPI == EPI_RESID_BIAS) Cf[o] += v4[r];
                    else if (OBF) Cb[o] = f2bf(v4[r]);
                    else Cf[o] = v4[r];
                }
                if (MODE == MODE_DBL && col >= 32) {
                    float* F = (float*)Ct;          // dblF f32 [row][32]
#pragma unroll
                    for (int r = 0; r < 4; r++)
                        F[(size_t)(rw + r) * 32 + (col - 32)] = v4[r];
                }
            }
        }
    }
}

// ---------------------------------------------------------------- conv ------
// xb bf16 [row][kDI] (x-half) -> xh bf16 [row][kDI] = silu(causal conv + cb).
__global__ __launch_bounds__(256) void conv_k(const unsigned short* __restrict__ xb,
    const float* __restrict__ cwf, const float* __restrict__ cwb,
    const float* __restrict__ cbf, const float* __restrict__ cbb,
    unsigned short* __restrict__ xh)
{
    __shared__ float tl[67][33];
    const int t0 = blockIdx.x * 64, d0 = blockIdx.y * 32, bb = blockIdx.z;
    const int dir = bb >> 2;
    const float* cw = dir ? cwb : cwf;
    const float* cb = dir ? cbb : cbf;
    const int dl = threadIdx.x & 31, rl = threadIdx.x >> 5;
    const size_t base = (size_t)bb * kN * kDI + d0 + dl;
#pragma unroll
    for (int p = 0; p < 9; p++) {
        int r = p * 8 + rl;
        if (r < 67) {
            int ts = t0 + r - 3;
            tl[r][dl] = (ts >= 0) ? b2f(xb[base + (size_t)ts * kDI]) : 0.f;
        }
    }
    __syncthreads();
    const int gd = d0 + dl;
    float c0 = cw[gd*4+0], c1 = cw[gd*4+1], c2 = cw[gd*4+2], c3 = cw[gd*4+3];
    float bv = cb[gd];
#pragma unroll
    for (int jj = 0; jj < 8; jj++) {
        int tt = rl + 8 * jj;
        float acc = bv + c0*tl[tt][dl] + c1*tl[tt+1][dl] + c2*tl[tt+2][dl] + c3*tl[tt+3][dl];
        float o = acc / (1.f + __expf(-acc));
        xh[(size_t)(bb * kN + t0 + tt) * kDI + gd] = f2bf(o);
    }
}

// ---------------------------------------------------------------- scan ------
// r14 coalesced blocked scan (validated): h[16]-in-registers 3-pass
// decomposition, all streams [row][d] row-major.
constexpr int kG  = 32;           // groups per chain
constexpr int kTg = kN / kG;      // 32 timesteps per group

template<int PASS>
__global__ __launch_bounds__(256) void bscan_k(
    const unsigned short* __restrict__ dt,   // [row][kDI]
    const unsigned short* __restrict__ xh,   // [row][kDI]
    const unsigned short* __restrict__ gate, // [row][kDI]
    const float* __restrict__ dblF,          // [row][32] (B | C)
    unsigned short* __restrict__ y,          // [row][kDI]
    float* __restrict__ PL,                  // [bb][g][32 slots][kDI]
    const float* __restrict__ alogf, const float* __restrict__ alogb,
    const float* __restrict__ ddf,   const float* __restrict__ ddb)
{
    const int d  = blockIdx.x * 256 + threadIdx.x;   // 0..1023
    const int g  = blockIdx.y;                       // 0..31
    const int bb = blockIdx.z;                       // 0..7
    const int dir = bb >> 2;
    const float* alog = dir ? alogb : alogf;
    const float* ddp  = dir ? ddb  : ddf;

    float a2[16];
#pragma unroll
    for (int s = 0; s < 16; s += 4) {
        float4 al = *(const float4*)&alog[d * kDS + s];
        a2[s+0] = -__expf(al.x) * 1.44269504f;
        a2[s+1] = -__expf(al.y) * 1.44269504f;
        a2[s+2] = -__expf(al.z) * 1.44269504f;
        a2[s+3] = -__expf(al.w) * 1.44269504f;
    }

    const size_t plb = (size_t)(bb * kG + g) * 32 * kDI + d;   // slot stride kDI
    float h[16];
    if (PASS == 0) {
#pragma unroll
        for (int s = 0; s < 16; s++) h[s] = 0.f;
    } else {
#pragma unroll
        for (int s = 0; s < 16; s++) h[s] = PL[plb + (size_t)(16 + s) * kDI];
    }

    const int row0 = bb * kN + g * kTg;
    const unsigned short* pd = dt   + (size_t)row0 * kDI + d;
    const unsigned short* px = xh   + (size_t)row0 * kDI + d;
    const unsigned short* pg = gate + (size_t)row0 * kDI + d;
    const float* pbc = dblF + (size_t)row0 * 32;
    unsigned short* py = y + (size_t)row0 * kDI + d;
    const float ddv = ddp[d];
    float sdt = 0.f;

#pragma unroll 4
    for (int t = 0; t < kTg; t++) {
        float dtv = b2f(pd[(size_t)t * kDI]);
        float xvv = b2f(px[(size_t)t * kDI]);
        float dtx = dtv * xvv;
        const float* bc = pbc + t * 32;
        if (PASS == 0) {
            sdt += dtv;
#pragma unroll
            for (int s4 = 0; s4 < 4; s4++) {
                float4 Bq = *(const float4*)(bc + s4 * 4);
                h[s4*4+0] = __builtin_amdgcn_exp2f(dtv * a2[s4*4+0]) * h[s4*4+0] + dtx * Bq.x;
                h[s4*4+1] = __builtin_amdgcn_exp2f(dtv * a2[s4*4+1]) * h[s4*4+1] + dtx * Bq.y;
                h[s4*4+2] = __builtin_amdgcn_exp2f(dtv * a2[s4*4+2]) * h[s4*4+2] + dtx * Bq.z;
                h[s4*4+3] = __builtin_amdgcn_exp2f(dtv * a2[s4*4+3]) * h[s4*4+3] + dtx * Bq.w;
            }
        } else {
            float p = 0.f;
#pragma unroll
            for (int s4 = 0; s4 < 4; s4++) {
                float4 Bq = *(const float4*)(bc + s4 * 4);
                float4 Cq = *(const float4*)(bc + 16 + s4 * 4);
                h[s4*4+0] = __builtin_amdgcn_exp2f(dtv * a2[s4*4+0]) * h[s4*4+0] + dtx * Bq.x;
                p += h[s4*4+0] * Cq.x;
                h[s4*4+1] = __builtin_amdgcn_exp2f(dtv * a2[s4*4+1]) * h[s4*4+1] + dtx * Bq.y;
                p += h[s4*4+1] * Cq.y;
                h[s4*4+2] = __builtin_amdgcn_exp2f(dtv * a2[s4*4+2]) * h[s4*4+2] + dtx * Bq.z;
                p += h[s4*4+2] * Cq.z;
                h[s4*4+3] = __builtin_amdgcn_exp2f(dtv * a2[s4*4+3]) * h[s4*4+3] + dtx * Bq.w;
                p += h[s4*4+3] * Cq.w;
            }
            float gvv = b2f(pg[(size_t)t * kDI]);
            py[(size_t)t * kDI] = f2bf((p + ddv * xvv) * gvv);
        }
    }

    if (PASS == 0) {
#pragma unroll
        for (int s = 0; s < 16; s++) {
            PL[plb + (size_t)s * kDI]        = __builtin_amdgcn_exp2f(a2[s] * sdt);
            PL[plb + (size_t)(16 + s) * kDI] = h[s];
        }
    }
}

// boundary fix: h_in[chain][g] = scan of (P,L) over groups; rewrites L slot.
__global__ __launch_bounds__(256) void bfix_k(float* __restrict__ PL)
{
    const int idx = blockIdx.x * 256 + threadIdx.x;  // 16 s x 8 bb x 1024 d
    const int d  = idx & (kDI - 1);
    const int bb = (idx >> 10) & 7;
    const int s  = idx >> 13;
    float h = 0.f;
    for (int g = 0; g < kG; g++) {
        size_t base = (size_t)(bb * kG + g) * 32 * kDI + d;
        float P = PL[base + (size_t)s * kDI];
        float L = PL[base + (size_t)(16 + s) * kDI];
        PL[base + (size_t)(16 + s) * kDI] = h;   // h_in for pass C
        h = P * h + L;
    }
}

// ---------------------------------------------------------------- attention -
__global__ __launch_bounds__(64) void att_score_k(const unsigned short* __restrict__ tmp,
    const float* __restrict__ aw2, const float* __restrict__ ab2,
    float* __restrict__ score)
{
    int row = blockIdx.x, lane = threadIdx.x;
    float acc = 0.f;
#pragma unroll
    for (int j = 0; j < 4; j++)
        acc += b2f(tmp[(size_t)row * 256 + lane + j * 64]) * aw2[lane + j * 64];
    for (int o = 32; o > 0; o >>= 1) acc += __shfl_xor(acc, o, 64);
    if (lane == 0) score[row] = acc + ab2[0];
}

__global__ __launch_bounds__(256) void softmax_k(const float* __restrict__ score,
                                                 float* __restrict__ w)
{
    int bb = blockIdx.x, tid = threadIdx.x;
    float v[4]; float m = -1e30f;
#pragma unroll
    for (int i = 0; i < 4; i++) { v[i] = score[bb * kN + tid + i * 256]; m = fmaxf(m, v[i]); }
    for (int o = 32; o > 0; o >>= 1) m = fmaxf(m, __shfl_xor(m, o, 64));
    __shared__ float r1[4], r2[4];
    int wv = tid >> 6;
    if ((tid & 63) == 0) r1[wv] = m;
    __syncthreads();
    m = fmaxf(fmaxf(r1[0], r1[1]), fmaxf(r1[2], r1[3]));
    float s = 0.f;
#pragma unroll
    for (int i = 0; i < 4; i++) { v[i] = __expf(v[i] - m); s += v[i]; }
    for (int o = 32; o > 0; o >>= 1) s += __shfl_xor(s, o, 64);
    if ((tid & 63) == 0) r2[wv] = s;
    __syncthreads();
    s = r2[0] + r2[1] + r2[2] + r2[3];
    float inv = 1.f / s;
#pragma unroll
    for (int i = 0; i < 4; i++) w[bb * kN + tid + i * 256] = v[i] * inv;
}

__global__ __launch_bounds__(512) void pool_k(const float* __restrict__ w,
    const float* __restrict__ h, float* zcat)
{
    int bb = blockIdx.x, chunk = blockIdx.y;   // 8 x 32
    int d = threadIdx.x;
    float acc = 0.f;
    int n0 = chunk * 32;
    for (int n = n0; n < n0 + 32; n++)
        acc += w[bb * kN + n] * h[((size_t)bb * kN + n) * kDM + d];
    int b = bb & 3, dir = bb >> 2;
    atomicAdd(&zcat[b * (2 * kDM) + dir * kDM + d], acc);
}

__global__ __launch_bounds__(256) void att_out_k(const float* __restrict__ w,
                                                 float* __restrict__ out)
{
    int idx = blockIdx.x * 256 + threadIdx.x;  // kB*kN
    int b = idx >> 10, n = idx & 1023;
    out[idx] = 0.5f * (w[b * kN + n] + w[(b + 4) * kN + (kN - 1 - n)]);
}

// ---------------------------------------------------------------- launch ----
extern "C" void kernel_launch(void* const* d_in, const int* in_sizes, int n_in,
                              void* d_out, int out_size, void* d_ws, size_t ws_size,
                              hipStream_t stream)
{
    const float* x = (const float*)d_in[0];
    const float* fp[17]; const float* bp[17];
    for (int i = 0; i < 17; i++) { fp[i] = (const float*)d_in[1 + i]; bp[i] = (const float*)d_in[18 + i]; }
    const float* aw1 = (const float*)d_in[35];
    const float* ab1 = (const float*)d_in[36];
    const float* aw2 = (const float*)d_in[37];
    const float* ab2 = (const float*)d_in[38];
    const float* nw  = (const float*)d_in[39];
    const float* nb  = (const float*)d_in[40];
    float* out = (float*)d_out;

    float* h = (float*)d_ws;                                   // 8192*512 f32
    unsigned short* ub    = (unsigned short*)(h + (size_t)kROWS * kDM);  // 8192*512
    unsigned short* xbuf  = ub    + (size_t)kROWS * kDM;        // 8192*1024 (x-half / y / ffn1 lo)
    unsigned short* tbuf  = xbuf  + (size_t)kROWS * kDI;        // 8192*1024 (dt / ffn1 hi / hb)
    unsigned short* xhb   = tbuf  + (size_t)kROWS * kDI;        // 8192*1024 (xh row-major)
    unsigned short* gateb = xhb   + (size_t)kROWS * kDI;        // 8192*1024 (gate row-major)
    unsigned short* dbl   = gateb + (size_t)kROWS * kDI;        // 8192*64 bf16
    float* dblF  = (float*)(dbl + (size_t)kROWS * 64);          // 8192*32 f32 (B/C)
    float* score = dblF + (size_t)kROWS * 32;                   // 8192
    float* smw   = score + kROWS;                               // 8192
    float* zcat  = smw   + kROWS;                               // 4096
    unsigned short* wts  = (unsigned short*)(zcat + kB * 2 * kDM);
    float* PL = (float*)(wts + O_WTOT);                         // 8*32*32*1024 f32 = 32MB

    // ---- weight prep: fp32 [L][K][N] -> bf16 [L][N][K] (one launch) ----
    WJobs jobs;
    jobs.s[0] = fp[2];  jobs.s[1] = bp[2];
    jobs.s[2] = fp[5];  jobs.s[3] = bp[5];
    jobs.s[4] = fp[6];  jobs.s[5] = bp[6];
    jobs.s[6] = fp[10]; jobs.s[7] = bp[10];
    jobs.s[8] = fp[13]; jobs.s[9] = bp[13];
    jobs.s[10] = fp[15]; jobs.s[11] = bp[15];
    jobs.s[12] = aw1;
    int wblocks = 0;
    {
        const int wK[13] = {512,512,1024,1024,32,32,1024,1024,512,512,2048,2048,512};
        const int wN[13] = {2048,2048,64,64,1024,1024,512,512,2048,2048,512,512,256};
        const int wL[13] = {2,2,2,2,2,2,2,2,2,2,2,2,1};
        for (int j = 0; j < 13; j++) wblocks += wL[j] * (wK[j]/32) * (wN[j]/32);
    }
    wprep_k<<<wblocks, 256, 0, stream>>>(jobs, wts);

    init_h_k<<<kROWS * kDM / 256, 256, 0, stream>>>(x, h);

    for (int l = 0; l < kL; l++) {
        const float *f_n1w = fp[0]  + l * kDM,            *b_n1w = bp[0]  + l * kDM;
        const float *f_n1b = fp[1]  + l * kDM,            *b_n1b = bp[1]  + l * kDM;
        const float *f_cw  = fp[3]  + l * kDI * kDC,      *b_cw  = bp[3]  + l * kDI * kDC;
        const float *f_cb  = fp[4]  + l * kDI,            *b_cb  = bp[4]  + l * kDI;
        const float *f_dtb = fp[7]  + l * kDI,            *b_dtb = bp[7]  + l * kDI;
        const float *f_alog= fp[8]  + l * kDI * kDS,      *b_alog= bp[8]  + l * kDI * kDS;
        const float *f_dd  = fp[9]  + l * kDI,            *b_dd  = bp[9]  + l * kDI;
        const float *f_n2w = fp[11] + l * kDM,            *b_n2w = bp[11] + l * kDM;
        const float *f_n2b = fp[12] + l * kDM,            *b_n2b = bp[12] + l * kDM;
        const float *f_b1  = fp[14] + l * 4 * kDM,        *b_b1  = bp[14] + l * 4 * kDM;
        const float *f_b2  = fp[16] + l * kDM,            *b_b2  = bp[16] + l * kDM;

        const unsigned short *wInwF = wts + O_INW_F + (size_t)l * 2048 * 512;
        const unsigned short *wInwB = wts + O_INW_B + (size_t)l * 2048 * 512;
        const unsigned short *wXpwF = wts + O_XPW_F + (size_t)l * 64 * 1024;
        const unsigned short *wXpwB = wts + O_XPW_B + (size_t)l * 64 * 1024;
        const unsigned short *wDtwF = wts + O_DTW_F + (size_t)l * 1024 * 32;
        const unsigned short *wDtwB = wts + O_DTW_B + (size_t)l * 1024 * 32;
        const unsigned short *wOwF  = wts + O_OW_F  + (size_t)l * 512 * 1024;
        const unsigned short *wOwB  = wts + O_OW_B  + (size_t)l * 512 * 1024;
        const unsigned short *wW1F  = wts + O_W1_F  + (size_t)l * 2048 * 512;
        const unsigned short *wW1B  = wts + O_W1_B  + (size_t)l * 2048 * 512;
        const unsigned short *wW2F  = wts + O_W2_F  + (size_t)l * 512 * 2048;
        const unsigned short *wW2B  = wts + O_W2_B  + (size_t)l * 512 * 2048;

        // u = LN1(h) -> bf16
        ln_k<kDM,1><<<kROWS, 256, 0, stream>>>(h, f_n1w, b_n1w, f_n1b, b_n1b, ub);
        // x-half -> xbuf bf16 [row][kDI]; z-half -> gateb = silu(z) row-major
        gemm_mfma<128,128,EPI_NONE,0,MODE_GATE,1,64><<<dim3(16, 64), 256, 0, stream>>>(
            ub, kDM, kDM, wInwF, wInwB, nullptr, nullptr, xbuf, kDI, gateb);
        // xh[row][kDI] = silu(conv(xbuf) + cb)  (row-major, no transpose)
        conv_k<<<dim3(kN/64, kDI/32, kB2), 256, 0, stream>>>(
            xbuf, f_cw, b_cw, f_cb, b_cb, xhb);
        // dbl = xh @ xpw (A row-major); cols>=32 also -> dblF f32 [row][32]
        gemm_mfma<32,64,EPI_NONE,0,MODE_DBL,1,64><<<dim3(1, 256), 256, 0, stream>>>(
            xhb, kDI, kDI, wXpwF, wXpwB, nullptr, nullptr, dbl, 64, (unsigned short*)dblF);
        // dt[row][kDI] = softplus(dbl[:, :32] @ dtw + dtb)  (row-major)
        gemm_mfma<128,128,EPI_SOFTPLUS,0,MODE_N,1,32><<<dim3(8, 64), 256, 0, stream>>>(
            dbl, 64, kDTR, wDtwF, wDtwB, f_dtb, b_dtb, tbuf, kDI, nullptr);
        // blocked scan: local pass -> boundary fix -> full pass (y into xbuf)
        bscan_k<0><<<dim3(kDI/256, kG, kB2), 256, 0, stream>>>(
            tbuf, xhb, gateb, dblF, xbuf, PL, f_alog, b_alog, f_dd, b_dd);
        bfix_k<<<kB2 * kDI * kDS / 256, 256, 0, stream>>>(PL);
        bscan_k<1><<<dim3(kDI/256, kG, kB2), 256, 0, stream>>>(
            tbuf, xhb, gateb, dblF, xbuf, PL, f_alog, b_alog, f_dd, b_dd);
        // h += y @ ow  (A = y row-major)
        gemm_mfma<128,64,EPI_RESID,0,MODE_N,0,64><<<dim3(8, 64), 256, 0, stream>>>(
            xbuf, kDI, kDI, wOwF, wOwB, nullptr, nullptr, h, kDM, nullptr);
        // u = LN2(h) -> bf16
        ln_k<kDM,1><<<kROWS, 256, 0, stream>>>(h, f_n2w, b_n2w, f_n2b, b_n2b, ub);
        // ffn1: gelu(u @ w1 + b1) -> xbuf..tbuf slab bf16 (8192 x 2048)
        gemm_mfma<128,128,EPI_GELU,0,MODE_N,1,64><<<dim3(16, 64), 256, 0, stream>>>(
            ub, kDM, kDM, wW1F, wW1B, f_b1, b_b1, xbuf, 4*kDM, nullptr);
        // h += ffn1 @ w2 + b2  (128x64 tile -> 512 blocks)
        gemm_mfma<128,64,EPI_RESID_BIAS,0,MODE_N,0,64><<<dim3(8, 64), 256, 0, stream>>>(
            xbuf, 4*kDM, 4*kDM, wW2F, wW2B, f_b2, b_b2, h, kDM, nullptr);
    }

    // attention: hb = bf16(h); u = tanh(hb @ aw1 + ab1) bf16
    h2b_k<<<kROWS * kDM / 256, 256, 0, stream>>>(h, tbuf);
    // 64x128 tile -> 256 blocks
    gemm_mfma<64,128,EPI_TANH,0,MODE_N,1,64><<<dim3(2, 128), 256, 0, stream>>>(
        tbuf, kDM, kDM, wts + O_AW1, wts + O_AW1, ab1, ab1, ub, 256, nullptr);
    att_score_k<<<kROWS, 64, 0, stream>>>(ub, aw2, ab2, score);
    softmax_k<<<kB2, 256, 0, stream>>>(score, smw);
    hipMemsetAsync(zcat, 0, kB * 2 * kDM * sizeof(float), stream);
    pool_k<<<dim3(kB2, 32), 512, 0, stream>>>(smw, h, zcat);
    // out[0:4096] = LN(concat(zf, zb))
    ln_k<2*kDM,0><<<kB, 256, 0, stream>>>(zcat, nw, nw, nb, nb, out);
    // out[4096:8192] = 0.5*(af + flip(ab))
    att_out_k<<<kB * kN / 256, 256, 0, stream>>>(smw, out + kB * 2 * kDM);
}

// Round 8
// 685.644 us; speedup vs baseline: 1.3659x; 1.0378x over previous
//
#include <hip/hip_runtime.h>
#include <math.h>

constexpr int kDM   = 512;
constexpr int kDI   = 1024;
constexpr int kDS   = 16;
constexpr int kDC   = 4;
constexpr int kDTR  = 32;
constexpr int kL    = 2;
constexpr int kB    = 4;
constexpr int kN    = 1024;
constexpr int kB2   = 8;              // combined batch: rows 0-3 fwd, 4-7 bwd
constexpr int kROWS = kB2 * kN;       // 8192
constexpr int kMDIR = kB * kN;        // 4096 rows per direction

enum { EPI_NONE=0, EPI_SOFTPLUS=1, EPI_RESID=2, EPI_GELU=3, EPI_RESID_BIAS=4, EPI_TANH=5 };
enum { MODE_N=0, MODE_OTR=1, MODE_DBL=2, MODE_GATE=3 };

typedef __attribute__((ext_vector_type(8))) short bf16x8;
typedef __attribute__((ext_vector_type(4))) short bf16x4;
typedef __attribute__((ext_vector_type(4))) float f32x4;

__device__ __forceinline__ unsigned short f2bf(float f) {
    unsigned int u = __float_as_uint(f);
    return (unsigned short)((u + 0x7FFFu + ((u >> 16) & 1u)) >> 16);
}
__device__ __forceinline__ float b2f(unsigned short u) {
    return __uint_as_float((unsigned int)u << 16);
}

// Abramowitz-Stegun 7.1.26 erf: max err 1.5e-7 (+ ~1e-7 from v_rcp) --
// far below bf16 LSB (2^-8 rel), replaces branchy libm erff (~50 inst -> ~14).
__device__ __forceinline__ float erf_as(float x) {
    float ax = fabsf(x);
    float t  = __builtin_amdgcn_rcpf(1.f + 0.3275911f * ax);
    float p  = t * (0.254829592f + t * (-0.284496736f + t * (1.421413741f +
               t * (-1.453152027f + t * 1.061405429f))));
    float e  = __builtin_amdgcn_exp2f(ax * ax * -1.44269504f);
    float r  = 1.f - p * e;
    return __builtin_copysignf(r, x);
}

// global -> LDS 16-B DMA (one instruction, no VGPR round-trip)
#define GLD_LDS16(gsrc, ldst) \
    __builtin_amdgcn_global_load_lds((const __attribute__((address_space(1))) void*)(gsrc), \
                                     (__attribute__((address_space(3))) void*)(ldst), 16, 0, 0)

// ------------------------------------------------------- weight prep --------
struct WJobs { const float* s[13]; };
// job order: f_inw b_inw f_xpw b_xpw f_dtw b_dtw f_ow b_ow f_w1 b_w1 f_w2 b_w2 aw1
constexpr size_t O_INW_F = 0;
constexpr size_t O_INW_B = O_INW_F + 2u*512*2048;
constexpr size_t O_XPW_F = O_INW_B + 2u*512*2048;
constexpr size_t O_XPW_B = O_XPW_F + 2u*1024*64;
constexpr size_t O_DTW_F = O_XPW_B + 2u*1024*64;
constexpr size_t O_DTW_B = O_DTW_F + 2u*32*1024;
constexpr size_t O_OW_F  = O_DTW_B + 2u*32*1024;
constexpr size_t O_OW_B  = O_OW_F  + 2u*1024*512;
constexpr size_t O_W1_F  = O_OW_B  + 2u*1024*512;
constexpr size_t O_W1_B  = O_W1_F  + 2u*512*2048;
constexpr size_t O_W2_F  = O_W1_B  + 2u*512*2048;
constexpr size_t O_W2_B  = O_W2_F  + 2u*2048*512;
constexpr size_t O_AW1   = O_W2_B  + 2u*2048*512;
constexpr size_t O_WTOT  = O_AW1   + 1u*512*256;

__global__ __launch_bounds__(256) void wprep_k(WJobs jobs, unsigned short* __restrict__ dst)
{
    const int wK[13] = {512,512,1024,1024,32,32,1024,1024,512,512,2048,2048,512};
    const int wN[13] = {2048,2048,64,64,1024,1024,512,512,2048,2048,512,512,256};
    const int wL[13] = {2,2,2,2,2,2,2,2,2,2,2,2,1};
    int blk = blockIdx.x;
    int j = 0; int base = 0; size_t doff = 0;
    for (; j < 13; j++) {
        int nb = wL[j] * (wK[j] / 32) * (wN[j] / 32);
        if (blk < base + nb) break;
        base += nb;
        doff += (size_t)wL[j] * wK[j] * wN[j];
    }
    int rel = blk - base;
    int K = wK[j], N = wN[j];
    int tk = K / 32, tn = N / 32;
    int l = rel / (tk * tn); rel -= l * tk * tn;
    int kt = rel / tn, nt = rel - (rel / tn) * tn;
    const float* src = jobs.s[j] + (size_t)l * K * N;
    unsigned short* d = dst + doff + (size_t)l * K * N;
    __shared__ float tl[32][33];
    const int c = threadIdx.x & 31, rg = threadIdx.x >> 5;
#pragma unroll
    for (int rr = 0; rr < 4; rr++)
        tl[rg * 4 + rr][c] = src[(size_t)(kt * 32 + rg * 4 + rr) * N + nt * 32 + c];
    __syncthreads();
#pragma unroll
    for (int rr = 0; rr < 4; rr++)
        d[(size_t)(nt * 32 + rg * 4 + rr) * K + kt * 32 + c] = f2bf(tl[c][rg * 4 + rr]);
}

// ---------------------------------------------------------------- init h ----
__global__ __launch_bounds__(256) void init_h_k(const float* __restrict__ x,
                                                float* __restrict__ h)
{
    size_t idx = (size_t)blockIdx.x * 256 + threadIdx.x;   // kROWS*kDM
    int d  = idx & (kDM - 1);
    int t  = (idx >> 9) & (kN - 1);
    int bb = (int)(idx >> 19);
    int b = bb & 3, dir = bb >> 2;
    int ts = dir ? (kN - 1 - t) : t;
    h[idx] = x[((size_t)b * kN + ts) * kDM + d];
}

__global__ __launch_bounds__(256) void h2b_k(const float* __restrict__ h,
                                             unsigned short* __restrict__ o)
{
    size_t idx = (size_t)blockIdx.x * 256 + threadIdx.x;
    o[idx] = f2bf(h[idx]);
}

// ---------------------------------------------------------------- layernorm --
template<int DIM, int OBF>
__global__ __launch_bounds__(256) void ln_k(const float* __restrict__ x,
    const float* __restrict__ wf, const float* __restrict__ wb,
    const float* __restrict__ bf, const float* __restrict__ bbp,
    void* __restrict__ outv)
{
    const int row = blockIdx.x;
    const int tid = threadIdx.x;
    constexpr int PT = DIM / 256;
    const int dir = (row >= kMDIR) ? 1 : 0;
    const float* w = dir ? wb : wf;
    const float* b = dir ? bbp : bf;

    float v[PT];
    float s1 = 0.f, s2 = 0.f;
#pragma unroll
    for (int i = 0; i < PT; i++) {
        float t = x[(size_t)row * DIM + tid + i * 256];
        v[i] = t; s1 += t; s2 += t * t;
    }
    for (int o = 32; o > 0; o >>= 1) { s1 += __shfl_xor(s1, o, 64); s2 += __shfl_xor(s2, o, 64); }
    __shared__ float r1[4], r2[4];
    int wv = tid >> 6;
    if ((tid & 63) == 0) { r1[wv] = s1; r2[wv] = s2; }
    __syncthreads();
    s1 = r1[0] + r1[1] + r1[2] + r1[3];
    s2 = r2[0] + r2[1] + r2[2] + r2[3];
    float mu  = s1 / DIM;
    float var = s2 / DIM - mu * mu;
    float rr  = rsqrtf(var + 1e-5f);
#pragma unroll
    for (int i = 0; i < PT; i++) {
        int c = tid + i * 256;
        float o = (v[i] - mu) * rr * w[c] + b[c];
        if (OBF) ((unsigned short*)outv)[(size_t)row * DIM + c] = f2bf(o);
        else     ((float*)outv)[(size_t)row * DIM + c] = o;
    }
}

// ---------------------------------------------------------------- MFMA GEMM -
// C = A @ B (+bias)(+epilogue). A bf16 [M][lda], B^T bf16 [N][K].
// r17 (KB==64): 2-phase double-buffered DMA K-loop (T3-minimum). R7 counters:
// staging VALU fixed (conflicts 0) but dur barely moved -- the 2-barrier
// structure issues tile t+1 loads AFTER tile t MFMA, exposing ~300-400cyc
// per K-iter at ~1.5 blocks/CU. Now: stage(t+1) issued BEFORE compute(t),
// ONE barrier/iter (its implicit per-wave vmcnt(0) = stage complete,
// lgkmcnt(0) = reads complete before buffer reuse). LDS 2x32KB.
// Epilogue: GELU erf via erf_as (A&S 7.1.26) -- libm erff was ~3-4K VALU
// inst/wave = ~13us of the 44us w1 dispatch.
template<int BM, int BN, int EPI, int ATR, int MODE, int OBF, int KB>
__global__ __launch_bounds__(256) void gemm_mfma(
    const unsigned short* __restrict__ A, int lda, int K,
    const unsigned short* __restrict__ Btf, const unsigned short* __restrict__ Btb,
    const float* __restrict__ biasf, const float* __restrict__ biasb,
    void* __restrict__ Cv, int ldc, unsigned short* __restrict__ Ct)
{
    constexpr int SK  = 40;              // padded LDS row stride (old path)
    constexpr int KT  = KB / 32;         // 32-wide sub-tiles per stage
    constexpr int CPR = KB / 8;          // 8-elem chunks per row (old path)
    constexpr int WM  = BM / 2, WN = BN / 2;
    constexpr int MT  = WM / 16, NT = WN / 16;
    constexpr int ASL = (BM * KB) / (256 * 8);
    constexpr int BSL = (BN * KB) / (256 * 8);
    constexpr int ABUF = BM * 64;        // one K-tile of A (ushorts)
    constexpr int BBUF = BN * 64;
    constexpr int ASZ = (KB == 64) ? 2 * ABUF : KT * BM * SK;
    constexpr int BSZ = (KB == 64) ? 2 * BBUF : KT * BN * SK;

    __shared__ __align__(16) unsigned short As[ASZ];
    __shared__ __align__(16) unsigned short Bs[BSZ];

    const int tid  = threadIdx.x;
    // ---- XCD swizzle (T1, bijective: nwg % 8 == 0 for every launch here) --
    const int gx   = gridDim.x;
    const int nwg  = gx * gridDim.y;
    const int lin  = blockIdx.x + blockIdx.y * gx;
    const int swz  = (lin & 7) * (nwg >> 3) + (lin >> 3);
    const int by   = swz / gx;
    const int bx   = swz - by * gx;
    const int n0   = bx * BN;
    const int row0 = by * BM;
    const int dir  = (row0 >= kMDIR) ? 1 : 0;
    const unsigned short* __restrict__ Bt = dir ? Btb : Btf;
    const float* bias = dir ? biasb : biasf;

    const int lane = tid & 63;
    const int wave = tid >> 6;
    const int wr = wave >> 1, wc = wave & 1;
    const int ml = lane & 15, q = lane >> 4;

    f32x4 acc[MT][NT];
#pragma unroll
    for (int i = 0; i < MT; i++)
#pragma unroll
        for (int j = 0; j < NT; j++)
#pragma unroll
            for (int r = 0; r < 4; r++) acc[i][j][r] = 0.f;

    if constexpr (KB == 64) {
        // ---- 2-phase double-buffered DMA K-loop ----
        constexpr int ACW = BM / 32;     // 1-KB chunks per wave (A)
        constexpr int BCW = BN / 32;     // 1-KB chunks per wave (B)
        const int lrow = lane >> 3;                       // 0..7 row in chunk
        const int lcol = ((lane & 7) ^ (lrow & 7)) << 4;  // pre-swizzled col byte
        const char* aS[ACW ? ACW : 1];
        const char* bS[BCW ? BCW : 1];
#pragma unroll
        for (int ch = 0; ch < ACW; ch++) {
            const int chunk = wave * ACW + ch;
            aS[ch] = (const char*)A + (size_t)(row0 + chunk * 8 + lrow) * lda * 2 + lcol;
        }
#pragma unroll
        for (int ch = 0; ch < BCW; ch++) {
            const int chunk = wave * BCW + ch;
            bS[ch] = (const char*)Bt + (size_t)(n0 + chunk * 8 + lrow) * K * 2 + lcol;
        }
        const int axor = (ml & 7) << 3;  // read-side swizzle (ushort units)

        auto stage = [&](int buf) {
#pragma unroll
            for (int ch = 0; ch < ACW; ch++) {
                GLD_LDS16(aS[ch], &As[buf * ABUF + (wave * ACW + ch) * 512]);
                aS[ch] += 128;
            }
#pragma unroll
            for (int ch = 0; ch < BCW; ch++) {
                GLD_LDS16(bS[ch], &Bs[buf * BBUF + (wave * BCW + ch) * 512]);
                bS[ch] += 128;
            }
        };

        stage(0);
        __syncthreads();                 // buf0 staged (vmcnt(0) + barrier)
        const int NKT = K >> 6;
        int cur = 0;
        for (int t = 0; t < NKT; t++) {
            if (t + 1 < NKT) stage(cur ^ 1);   // prefetch BEFORE compute
#pragma unroll
            for (int kk = 0; kk < 2; kk++) {
                bf16x8 af[MT], bfr[NT];
#pragma unroll
                for (int i = 0; i < MT; i++)
                    af[i] = *(bf16x8*)&As[cur * ABUF + (wr * WM + i * 16 + ml) * 64 + ((kk * 32 + q * 8) ^ axor)];
#pragma unroll
                for (int j = 0; j < NT; j++)
                    bfr[j] = *(bf16x8*)&Bs[cur * BBUF + (wc * WN + j * 16 + ml) * 64 + ((kk * 32 + q * 8) ^ axor)];
#pragma unroll
                for (int i = 0; i < MT; i++)
#pragma unroll
                    for (int j = 0; j < NT; j++)
                        acc[i][j] = __builtin_amdgcn_mfma_f32_16x16x32_bf16(af[i], bfr[j], acc[i][j], 0, 0, 0);
            }
            __syncthreads();   // per-wave vmcnt(0): next buf staged; lgkm(0): cur reads done
            cur ^= 1;
        }
    } else {
        // ---- old reg-staging path (KB==32: dtw GEMM only) ----
        for (int kt = 0; kt < K; kt += KB) {
            bf16x8 a_ld[ASL ? ASL : 1];
#pragma unroll
            for (int r = 0; r < ASL; r++) {
                int i = tid + r * 256;
                int m = i / CPR, c8 = (i % CPR) * 8;
                a_ld[r] = *(const bf16x8*)(A + (size_t)(row0 + m) * lda + kt + c8);
            }
            bf16x8 b_ld[BSL ? BSL : 1];
#pragma unroll
            for (int r = 0; r < BSL; r++) {
                int i = tid + r * 256;
                int n = i / CPR, c8 = (i % CPR) * 8;
                b_ld[r] = *(const bf16x8*)(Bt + (size_t)(n0 + n) * K + kt + c8);
            }
            __syncthreads();
#pragma unroll
            for (int r = 0; r < ASL; r++) {
                int i = tid + r * 256;
                int m = i / CPR, c8 = (i % CPR) * 8;
                *(bf16x8*)&As[((c8 >> 5) * BM + m) * SK + (c8 & 31)] = a_ld[r];
            }
#pragma unroll
            for (int r = 0; r < BSL; r++) {
                int i = tid + r * 256;
                int n = i / CPR, c8 = (i % CPR) * 8;
                *(bf16x8*)&Bs[((c8 >> 5) * BN + n) * SK + (c8 & 31)] = b_ld[r];
            }
            __syncthreads();
#pragma unroll
            for (int kk = 0; kk < KT; kk++) {
                bf16x8 af[MT], bfr[NT];
#pragma unroll
                for (int i = 0; i < MT; i++)
                    af[i] = *(bf16x8*)&As[(kk * BM + wr * WM + i * 16 + ml) * SK + q * 8];
#pragma unroll
                for (int j = 0; j < NT; j++)
                    bfr[j] = *(bf16x8*)&Bs[(kk * BN + wc * WN + j * 16 + ml) * SK + q * 8];
#pragma unroll
                for (int i = 0; i < MT; i++)
#pragma unroll
                    for (int j = 0; j < NT; j++)
                        acc[i][j] = __builtin_amdgcn_mfma_f32_16x16x32_bf16(af[i], bfr[j], acc[i][j], 0, 0, 0);
            }
            __syncthreads();
        }
    }

    // ---- epilogue ----
    float* Cf = (float*)Cv;
    unsigned short* Cb = (unsigned short*)Cv;
#pragma unroll
    for (int j = 0; j < NT; j++) {
        int col = n0 + wc * WN + j * 16 + ml;
        float bv = 0.f;
        if (EPI == EPI_SOFTPLUS || EPI == EPI_GELU || EPI == EPI_RESID_BIAS || EPI == EPI_TANH)
            bv = bias[col];
#pragma unroll
        for (int i = 0; i < MT; i++) {
            int rw = row0 + wr * WM + i * 16 + q * 4;
            float v4[4];
#pragma unroll
            for (int r = 0; r < 4; r++) {
                float v = acc[i][j][r] + bv;
                if (EPI == EPI_SOFTPLUS) v = (v > 20.f) ? v : __logf(1.f + __expf(v));
                if (EPI == EPI_GELU)     v = 0.5f * v * (1.f + erf_as(v * 0.70710678118654752f));
                if (EPI == EPI_TANH)     v = tanhf(v);
                v4[r] = v;
            }
            if (MODE == MODE_GATE && n0 >= kDI) {
                // silu(z) -> gate row-major [row][kDI]
#pragma unroll
                for (int r = 0; r < 4; r++) {
                    float sv = v4[r] / (1.f + __expf(-v4[r]));
                    Ct[(size_t)(rw + r) * kDI + (col - kDI)] = f2bf(sv);
                }
            } else {
#pragma unroll
                for (int r = 0; r < 4; r++) {
                    size_t o = (size_t)(rw + r) * ldc + col;
                    if (EPI == EPI_RESID || EPI == EPI_RESID_BIAS) Cf[o] += v4[r];
                    else if (OBF) Cb[o] = f2bf(v4[r]);
                    else Cf[o] = v4[r];
                }
                if (MODE == MODE_DBL && col >= 32) {
                    float* F = (float*)Ct;          // dblF f32 [row][32]
#pragma unroll
                    for (int r = 0; r < 4; r++)
                        F[(size_t)(rw + r) * 32 + (col - 32)] = v4[r];
                }
            }
        }
    }
}

// ---------------------------------------------------------------- conv ------
// xb bf16 [row][kDI] (x-half) -> xh bf16 [row][kDI] = silu(causal conv + cb).
__global__ __launch_bounds__(256) void conv_k(const unsigned short* __restrict__ xb,
    const float* __restrict__ cwf, const float* __restrict__ cwb,
    const float* __restrict__ cbf, const float* __restrict__ cbb,
    unsigned short* __restrict__ xh)
{
    __shared__ float tl[67][33];
    const int t0 = blockIdx.x * 64, d0 = blockIdx.y * 32, bb = blockIdx.z;
    const int dir = bb >> 2;
    const float* cw = dir ? cwb : cwf;
    const float* cb = dir ? cbb : cbf;
    const int dl = threadIdx.x & 31, rl = threadIdx.x >> 5;
    const size_t base = (size_t)bb * kN * kDI + d0 + dl;
#pragma unroll
    for (int p = 0; p < 9; p++) {
        int r = p * 8 + rl;
        if (r < 67) {
            int ts = t0 + r - 3;
            tl[r][dl] = (ts >= 0) ? b2f(xb[base + (size_t)ts * kDI]) : 0.f;
        }
    }
    __syncthreads();
    const int gd = d0 + dl;
    float c0 = cw[gd*4+0], c1 = cw[gd*4+1], c2 = cw[gd*4+2], c3 = cw[gd*4+3];
    float bv = cb[gd];
#pragma unroll
    for (int jj = 0; jj < 8; jj++) {
        int tt = rl + 8 * jj;
        float acc = bv + c0*tl[tt][dl] + c1*tl[tt+1][dl] + c2*tl[tt+2][dl] + c3*tl[tt+3][dl];
        float o = acc / (1.f + __expf(-acc));
        xh[(size_t)(bb * kN + t0 + tt) * kDI + gd] = f2bf(o);
    }
}

// ---------------------------------------------------------------- scan ------
// r14 coalesced blocked scan (validated): h[16]-in-registers 3-pass
// decomposition, all streams [row][d] row-major.
constexpr int kG  = 32;           // groups per chain
constexpr int kTg = kN / kG;      // 32 timesteps per group

template<int PASS>
__global__ __launch_bounds__(256) void bscan_k(
    const unsigned short* __restrict__ dt,   // [row][kDI]
    const unsigned short* __restrict__ xh,   // [row][kDI]
    const unsigned short* __restrict__ gate, // [row][kDI]
    const float* __restrict__ dblF,          // [row][32] (B | C)
    unsigned short* __restrict__ y,          // [row][kDI]
    float* __restrict__ PL,                  // [bb][g][32 slots][kDI]
    const float* __restrict__ alogf, const float* __restrict__ alogb,
    const float* __restrict__ ddf,   const float* __restrict__ ddb)
{
    const int d  = blockIdx.x * 256 + threadIdx.x;   // 0..1023
    const int g  = blockIdx.y;                       // 0..31
    const int bb = blockIdx.z;                       // 0..7
    const int dir = bb >> 2;
    const float* alog = dir ? alogb : alogf;
    const float* ddp  = dir ? ddb  : ddf;

    float a2[16];
#pragma unroll
    for (int s = 0; s < 16; s += 4) {
        float4 al = *(const float4*)&alog[d * kDS + s];
        a2[s+0] = -__expf(al.x) * 1.44269504f;
        a2[s+1] = -__expf(al.y) * 1.44269504f;
        a2[s+2] = -__expf(al.z) * 1.44269504f;
        a2[s+3] = -__expf(al.w) * 1.44269504f;
    }

    const size_t plb = (size_t)(bb * kG + g) * 32 * kDI + d;   // slot stride kDI
    float h[16];
    if (PASS == 0) {
#pragma unroll
        for (int s = 0; s < 16; s++) h[s] = 0.f;
    } else {
#pragma unroll
        for (int s = 0; s < 16; s++) h[s] = PL[plb + (size_t)(16 + s) * kDI];
    }

    const int row0 = bb * kN + g * kTg;
    const unsigned short* pd = dt   + (size_t)row0 * kDI + d;
    const unsigned short* px = xh   + (size_t)row0 * kDI + d;
    const unsigned short* pg = gate + (size_t)row0 * kDI + d;
    const float* pbc = dblF + (size_t)row0 * 32;
    unsigned short* py = y + (size_t)row0 * kDI + d;
    const float ddv = ddp[d];
    float sdt = 0.f;

#pragma unroll 4
    for (int t = 0; t < kTg; t++) {
        float dtv = b2f(pd[(size_t)t * kDI]);
        float xvv = b2f(px[(size_t)t * kDI]);
        float dtx = dtv * xvv;
        const float* bc = pbc + t * 32;
        if (PASS == 0) {
            sdt += dtv;
#pragma unroll
            for (int s4 = 0; s4 < 4; s4++) {
                float4 Bq = *(const float4*)(bc + s4 * 4);
                h[s4*4+0] = __builtin_amdgcn_exp2f(dtv * a2[s4*4+0]) * h[s4*4+0] + dtx * Bq.x;
                h[s4*4+1] = __builtin_amdgcn_exp2f(dtv * a2[s4*4+1]) * h[s4*4+1] + dtx * Bq.y;
                h[s4*4+2] = __builtin_amdgcn_exp2f(dtv * a2[s4*4+2]) * h[s4*4+2] + dtx * Bq.z;
                h[s4*4+3] = __builtin_amdgcn_exp2f(dtv * a2[s4*4+3]) * h[s4*4+3] + dtx * Bq.w;
            }
        } else {
            float p = 0.f;
#pragma unroll
            for (int s4 = 0; s4 < 4; s4++) {
                float4 Bq = *(const float4*)(bc + s4 * 4);
                float4 Cq = *(const float4*)(bc + 16 + s4 * 4);
                h[s4*4+0] = __builtin_amdgcn_exp2f(dtv * a2[s4*4+0]) * h[s4*4+0] + dtx * Bq.x;
                p += h[s4*4+0] * Cq.x;
                h[s4*4+1] = __builtin_amdgcn_exp2f(dtv * a2[s4*4+1]) * h[s4*4+1] + dtx * Bq.y;
                p += h[s4*4+1] * Cq.y;
                h[s4*4+2] = __builtin_amdgcn_exp2f(dtv * a2[s4*4+2]) * h[s4*4+2] + dtx * Bq.z;
                p += h[s4*4+2] * Cq.z;
                h[s4*4+3] = __builtin_amdgcn_exp2f(dtv * a2[s4*4+3]) * h[s4*4+3] + dtx * Bq.w;
                p += h[s4*4+3] * Cq.w;
            }
            float gvv = b2f(pg[(size_t)t * kDI]);
            py[(size_t)t * kDI] = f2bf((p + ddv * xvv) * gvv);
        }
    }

    if (PASS == 0) {
#pragma unroll
        for (int s = 0; s < 16; s++) {
            PL[plb + (size_t)s * kDI]        = __builtin_amdgcn_exp2f(a2[s] * sdt);
            PL[plb + (size_t)(16 + s) * kDI] = h[s];
        }
    }
}

// boundary fix: h_in[chain][g] = scan of (P,L) over groups; rewrites L slot.
__global__ __launch_bounds__(256) void bfix_k(float* __restrict__ PL)
{
    const int idx = blockIdx.x * 256 + threadIdx.x;  // 16 s x 8 bb x 1024 d
    const int d  = idx & (kDI - 1);
    const int bb = (idx >> 10) & 7;
    const int s  = idx >> 13;
    float h = 0.f;
    for (int g = 0; g < kG; g++) {
        size_t base = (size_t)(bb * kG + g) * 32 * kDI + d;
        float P = PL[base + (size_t)s * kDI];
        float L = PL[base + (size_t)(16 + s) * kDI];
        PL[base + (size_t)(16 + s) * kDI] = h;   // h_in for pass C
        h = P * h + L;
    }
}

// ---------------------------------------------------------------- attention -
__global__ __launch_bounds__(64) void att_score_k(const unsigned short* __restrict__ tmp,
    const float* __restrict__ aw2, const float* __restrict__ ab2,
    float* __restrict__ score)
{
    int row = blockIdx.x, lane = threadIdx.x;
    float acc = 0.f;
#pragma unroll
    for (int j = 0; j < 4; j++)
        acc += b2f(tmp[(size_t)row * 256 + lane + j * 64]) * aw2[lane + j * 64];
    for (int o = 32; o > 0; o >>= 1) acc += __shfl_xor(acc, o, 64);
    if (lane == 0) score[row] = acc + ab2[0];
}

__global__ __launch_bounds__(256) void softmax_k(const float* __restrict__ score,
                                                 float* __restrict__ w)
{
    int bb = blockIdx.x, tid = threadIdx.x;
    float v[4]; float m = -1e30f;
#pragma unroll
    for (int i = 0; i < 4; i++) { v[i] = score[bb * kN + tid + i * 256]; m = fmaxf(m, v[i]); }
    for (int o = 32; o > 0; o >>= 1) m = fmaxf(m, __shfl_xor(m, o, 64));
    __shared__ float r1[4], r2[4];
    int wv = tid >> 6;
    if ((tid & 63) == 0) r1[wv] = m;
    __syncthreads();
    m = fmaxf(fmaxf(r1[0], r1[1]), fmaxf(r1[2], r1[3]));
    float s = 0.f;
#pragma unroll
    for (int i = 0; i < 4; i++) { v[i] = __expf(v[i] - m); s += v[i]; }
    for (int o = 32; o > 0; o >>= 1) s += __shfl_xor(s, o, 64);
    if ((tid & 63) == 0) r2[wv] = s;
    __syncthreads();
    s = r2[0] + r2[1] + r2[2] + r2[3];
    float inv = 1.f / s;
#pragma unroll
    for (int i = 0; i < 4; i++) w[bb * kN + tid + i * 256] = v[i] * inv;
}

__global__ __launch_bounds__(512) void pool_k(const float* __restrict__ w,
    const float* __restrict__ h, float* zcat)
{
    int bb = blockIdx.x, chunk = blockIdx.y;   // 8 x 32
    int d = threadIdx.x;
    float acc = 0.f;
    int n0 = chunk * 32;
    for (int n = n0; n < n0 + 32; n++)
        acc += w[bb * kN + n] * h[((size_t)bb * kN + n) * kDM + d];
    int b = bb & 3, dir = bb >> 2;
    atomicAdd(&zcat[b * (2 * kDM) + dir * kDM + d], acc);
}

__global__ __launch_bounds__(256) void att_out_k(const float* __restrict__ w,
                                                 float* __restrict__ out)
{
    int idx = blockIdx.x * 256 + threadIdx.x;  // kB*kN
    int b = idx >> 10, n = idx & 1023;
    out[idx] = 0.5f * (w[b * kN + n] + w[(b + 4) * kN + (kN - 1 - n)]);
}

// ---------------------------------------------------------------- launch ----
extern "C" void kernel_launch(void* const* d_in, const int* in_sizes, int n_in,
                              void* d_out, int out_size, void* d_ws, size_t ws_size,
                              hipStream_t stream)
{
    const float* x = (const float*)d_in[0];
    const float* fp[17]; const float* bp[17];
    for (int i = 0; i < 17; i++) { fp[i] = (const float*)d_in[1 + i]; bp[i] = (const float*)d_in[18 + i]; }
    const float* aw1 = (const float*)d_in[35];
    const float* ab1 = (const float*)d_in[36];
    const float* aw2 = (const float*)d_in[37];
    const float* ab2 = (const float*)d_in[38];
    const float* nw  = (const float*)d_in[39];
    const float* nb  = (const float*)d_in[40];
    float* out = (float*)d_out;

    float* h = (float*)d_ws;                                   // 8192*512 f32
    unsigned short* ub    = (unsigned short*)(h + (size_t)kROWS * kDM);  // 8192*512
    unsigned short* xbuf  = ub    + (size_t)kROWS * kDM;        // 8192*1024 (x-half / y / ffn1 lo)
    unsigned short* tbuf  = xbuf  + (size_t)kROWS * kDI;        // 8192*1024 (dt / ffn1 hi / hb)
    unsigned short* xhb   = tbuf  + (size_t)kROWS * kDI;        // 8192*1024 (xh row-major)
    unsigned short* gateb = xhb   + (size_t)kROWS * kDI;        // 8192*1024 (gate row-major)
    unsigned short* dbl   = gateb + (size_t)kROWS * kDI;        // 8192*64 bf16
    float* dblF  = (float*)(dbl + (size_t)kROWS * 64);          // 8192*32 f32 (B/C)
    float* score = dblF + (size_t)kROWS * 32;                   // 8192
    float* smw   = score + kROWS;                               // 8192
    float* zcat  = smw   + kROWS;                               // 4096
    unsigned short* wts  = (unsigned short*)(zcat + kB * 2 * kDM);
    float* PL = (float*)(wts + O_WTOT);                         // 8*32*32*1024 f32 = 32MB

    // ---- weight prep: fp32 [L][K][N] -> bf16 [L][N][K] (one launch) ----
    WJobs jobs;
    jobs.s[0] = fp[2];  jobs.s[1] = bp[2];
    jobs.s[2] = fp[5];  jobs.s[3] = bp[5];
    jobs.s[4] = fp[6];  jobs.s[5] = bp[6];
    jobs.s[6] = fp[10]; jobs.s[7] = bp[10];
    jobs.s[8] = fp[13]; jobs.s[9] = bp[13];
    jobs.s[10] = fp[15]; jobs.s[11] = bp[15];
    jobs.s[12] = aw1;
    int wblocks = 0;
    {
        const int wK[13] = {512,512,1024,1024,32,32,1024,1024,512,512,2048,2048,512};
        const int wN[13] = {2048,2048,64,64,1024,1024,512,512,2048,2048,512,512,256};
        const int wL[13] = {2,2,2,2,2,2,2,2,2,2,2,2,1};
        for (int j = 0; j < 13; j++) wblocks += wL[j] * (wK[j]/32) * (wN[j]/32);
    }
    wprep_k<<<wblocks, 256, 0, stream>>>(jobs, wts);

    init_h_k<<<kROWS * kDM / 256, 256, 0, stream>>>(x, h);

    for (int l = 0; l < kL; l++) {
        const float *f_n1w = fp[0]  + l * kDM,            *b_n1w = bp[0]  + l * kDM;
        const float *f_n1b = fp[1]  + l * kDM,            *b_n1b = bp[1]  + l * kDM;
        const float *f_cw  = fp[3]  + l * kDI * kDC,      *b_cw  = bp[3]  + l * kDI * kDC;
        const float *f_cb  = fp[4]  + l * kDI,            *b_cb  = bp[4]  + l * kDI;
        const float *f_dtb = fp[7]  + l * kDI,            *b_dtb = bp[7]  + l * kDI;
        const float *f_alog= fp[8]  + l * kDI * kDS,      *b_alog= bp[8]  + l * kDI * kDS;
        const float *f_dd  = fp[9]  + l * kDI,            *b_dd  = bp[9]  + l * kDI;
        const float *f_n2w = fp[11] + l * kDM,            *b_n2w = bp[11] + l * kDM;
        const float *f_n2b = fp[12] + l * kDM,            *b_n2b = bp[12] + l * kDM;
        const float *f_b1  = fp[14] + l * 4 * kDM,        *b_b1  = bp[14] + l * 4 * kDM;
        const float *f_b2  = fp[16] + l * kDM,            *b_b2  = bp[16] + l * kDM;

        const unsigned short *wInwF = wts + O_INW_F + (size_t)l * 2048 * 512;
        const unsigned short *wInwB = wts + O_INW_B + (size_t)l * 2048 * 512;
        const unsigned short *wXpwF = wts + O_XPW_F + (size_t)l * 64 * 1024;
        const unsigned short *wXpwB = wts + O_XPW_B + (size_t)l * 64 * 1024;
        const unsigned short *wDtwF = wts + O_DTW_F + (size_t)l * 1024 * 32;
        const unsigned short *wDtwB = wts + O_DTW_B + (size_t)l * 1024 * 32;
        const unsigned short *wOwF  = wts + O_OW_F  + (size_t)l * 512 * 1024;
        const unsigned short *wOwB  = wts + O_OW_B  + (size_t)l * 512 * 1024;
        const unsigned short *wW1F  = wts + O_W1_F  + (size_t)l * 2048 * 512;
        const unsigned short *wW1B  = wts + O_W1_B  + (size_t)l * 2048 * 512;
        const unsigned short *wW2F  = wts + O_W2_F  + (size_t)l * 512 * 2048;
        const unsigned short *wW2B  = wts + O_W2_B  + (size_t)l * 512 * 2048;

        // u = LN1(h) -> bf16
        ln_k<kDM,1><<<kROWS, 256, 0, stream>>>(h, f_n1w, b_n1w, f_n1b, b_n1b, ub);
        // x-half -> xbuf bf16 [row][kDI]; z-half -> gateb = silu(z) row-major
        gemm_mfma<128,128,EPI_NONE,0,MODE_GATE,1,64><<<dim3(16, 64), 256, 0, stream>>>(
            ub, kDM, kDM, wInwF, wInwB, nullptr, nullptr, xbuf, kDI, gateb);
        // xh[row][kDI] = silu(conv(xbuf) + cb)  (row-major, no transpose)
        conv_k<<<dim3(kN/64, kDI/32, kB2), 256, 0, stream>>>(
            xbuf, f_cw, b_cw, f_cb, b_cb, xhb);
        // dbl = xh @ xpw (A row-major); cols>=32 also -> dblF f32 [row][32]
        gemm_mfma<32,64,EPI_NONE,0,MODE_DBL,1,64><<<dim3(1, 256), 256, 0, stream>>>(
            xhb, kDI, kDI, wXpwF, wXpwB, nullptr, nullptr, dbl, 64, (unsigned short*)dblF);
        // dt[row][kDI] = softplus(dbl[:, :32] @ dtw + dtb)  (row-major)
        gemm_mfma<128,128,EPI_SOFTPLUS,0,MODE_N,1,32><<<dim3(8, 64), 256, 0, stream>>>(
            dbl, 64, kDTR, wDtwF, wDtwB, f_dtb, b_dtb, tbuf, kDI, nullptr);
        // blocked scan: local pass -> boundary fix -> full pass (y into xbuf)
        bscan_k<0><<<dim3(kDI/256, kG, kB2), 256, 0, stream>>>(
            tbuf, xhb, gateb, dblF, xbuf, PL, f_alog, b_alog, f_dd, b_dd);
        bfix_k<<<kB2 * kDI * kDS / 256, 256, 0, stream>>>(PL);
        bscan_k<1><<<dim3(kDI/256, kG, kB2), 256, 0, stream>>>(
            tbuf, xhb, gateb, dblF, xbuf, PL, f_alog, b_alog, f_dd, b_dd);
        // h += y @ ow  (A = y row-major)
        gemm_mfma<128,64,EPI_RESID,0,MODE_N,0,64><<<dim3(8, 64), 256, 0, stream>>>(
            xbuf, kDI, kDI, wOwF, wOwB, nullptr, nullptr, h, kDM, nullptr);
        // u = LN2(h) -> bf16
        ln_k<kDM,1><<<kROWS, 256, 0, stream>>>(h, f_n2w, b_n2w, f_n2b, b_n2b, ub);
        // ffn1: gelu(u @ w1 + b1) -> xbuf..tbuf slab bf16 (8192 x 2048)
        gemm_mfma<128,128,EPI_GELU,0,MODE_N,1,64><<<dim3(16, 64), 256, 0, stream>>>(
            ub, kDM, kDM, wW1F, wW1B, f_b1, b_b1, xbuf, 4*kDM, nullptr);
        // h += ffn1 @ w2 + b2  (128x64 tile -> 512 blocks)
        gemm_mfma<128,64,EPI_RESID_BIAS,0,MODE_N,0,64><<<dim3(8, 64), 256, 0, stream>>>(
            xbuf, 4*kDM, 4*kDM, wW2F, wW2B, f_b2, b_b2, h, kDM, nullptr);
    }

    // attention: hb = bf16(h); u = tanh(hb @ aw1 + ab1) bf16
    h2b_k<<<kROWS * kDM / 256, 256, 0, stream>>>(h, tbuf);
    // 64x128 tile -> 256 blocks
    gemm_mfma<64,128,EPI_TANH,0,MODE_N,1,64><<<dim3(2, 128), 256, 0, stream>>>(
        tbuf, kDM, kDM, wts + O_AW1, wts + O_AW1, ab1, ab1, ub, 256, nullptr);
    att_score_k<<<kROWS, 64, 0, stream>>>(ub, aw2, ab2, score);
    softmax_k<<<kB2, 256, 0, stream>>>(score, smw);
    hipMemsetAsync(zcat, 0, kB * 2 * kDM * sizeof(float), stream);
    pool_k<<<dim3(kB2, 32), 512, 0, stream>>>(smw, h, zcat);
    // out[0:4096] = LN(concat(zf, zb))
    ln_k<2*kDM,0><<<kB, 256, 0, stream>>>(zcat, nw, nw, nb, nb, out);
    // out[4096:8192] = 0.5*(af + flip(ab))
    att_out_k<<<kB * kN / 256, 256, 0, stream>>>(smw, out + kB * 2 * kDM);
}

// Round 9
// 656.810 us; speedup vs baseline: 1.4259x; 1.0439x over previous
//
#include <hip/hip_runtime.h>
#include <math.h>

constexpr int kDM   = 512;
constexpr int kDI   = 1024;
constexpr int kDS   = 16;
constexpr int kDC   = 4;
constexpr int kDTR  = 32;
constexpr int kL    = 2;
constexpr int kB    = 4;
constexpr int kN    = 1024;
constexpr int kB2   = 8;              // combined batch: rows 0-3 fwd, 4-7 bwd
constexpr int kROWS = kB2 * kN;       // 8192
constexpr int kMDIR = kB * kN;        // 4096 rows per direction

enum { EPI_NONE=0, EPI_SOFTPLUS=1, EPI_RESID=2, EPI_GELU=3, EPI_RESID_BIAS=4, EPI_TANH=5 };
enum { MODE_N=0, MODE_OTR=1, MODE_DBL=2, MODE_GATE=3 };

typedef __attribute__((ext_vector_type(8))) short bf16x8;
typedef __attribute__((ext_vector_type(4))) short bf16x4;
typedef __attribute__((ext_vector_type(4))) float f32x4;

__device__ __forceinline__ unsigned short f2bf(float f) {
    unsigned int u = __float_as_uint(f);
    return (unsigned short)((u + 0x7FFFu + ((u >> 16) & 1u)) >> 16);
}
__device__ __forceinline__ float b2f(unsigned short u) {
    return __uint_as_float((unsigned int)u << 16);
}

// Abramowitz-Stegun 7.1.26 erf: max err 1.5e-7 (+ ~1e-7 from v_rcp) --
// far below bf16 LSB (2^-8 rel), replaces branchy libm erff (~50 inst -> ~14).
__device__ __forceinline__ float erf_as(float x) {
    float ax = fabsf(x);
    float t  = __builtin_amdgcn_rcpf(1.f + 0.3275911f * ax);
    float p  = t * (0.254829592f + t * (-0.284496736f + t * (1.421413741f +
               t * (-1.453152027f + t * 1.061405429f))));
    float e  = __builtin_amdgcn_exp2f(ax * ax * -1.44269504f);
    float r  = 1.f - p * e;
    return __builtin_copysignf(r, x);
}

// global -> LDS 16-B DMA (one instruction, no VGPR round-trip)
#define GLD_LDS16(gsrc, ldst) \
    __builtin_amdgcn_global_load_lds((const __attribute__((address_space(1))) void*)(gsrc), \
                                     (__attribute__((address_space(3))) void*)(ldst), 16, 0, 0)

// ------------------------------------------------------- weight prep --------
struct WJobs { const float* s[13]; };
// job order: f_inw b_inw f_xpw b_xpw f_dtw b_dtw f_ow b_ow f_w1 b_w1 f_w2 b_w2 aw1
constexpr size_t O_INW_F = 0;
constexpr size_t O_INW_B = O_INW_F + 2u*512*2048;
constexpr size_t O_XPW_F = O_INW_B + 2u*512*2048;
constexpr size_t O_XPW_B = O_XPW_F + 2u*1024*64;
constexpr size_t O_DTW_F = O_XPW_B + 2u*1024*64;
constexpr size_t O_DTW_B = O_DTW_F + 2u*32*1024;
constexpr size_t O_OW_F  = O_DTW_B + 2u*32*1024;
constexpr size_t O_OW_B  = O_OW_F  + 2u*1024*512;
constexpr size_t O_W1_F  = O_OW_B  + 2u*1024*512;
constexpr size_t O_W1_B  = O_W1_F  + 2u*512*2048;
constexpr size_t O_W2_F  = O_W1_B  + 2u*512*2048;
constexpr size_t O_W2_B  = O_W2_F  + 2u*2048*512;
constexpr size_t O_AW1   = O_W2_B  + 2u*2048*512;
constexpr size_t O_WTOT  = O_AW1   + 1u*512*256;

__global__ __launch_bounds__(256) void wprep_k(WJobs jobs, unsigned short* __restrict__ dst)
{
    const int wK[13] = {512,512,1024,1024,32,32,1024,1024,512,512,2048,2048,512};
    const int wN[13] = {2048,2048,64,64,1024,1024,512,512,2048,2048,512,512,256};
    const int wL[13] = {2,2,2,2,2,2,2,2,2,2,2,2,1};
    int blk = blockIdx.x;
    int j = 0; int base = 0; size_t doff = 0;
    for (; j < 13; j++) {
        int nb = wL[j] * (wK[j] / 32) * (wN[j] / 32);
        if (blk < base + nb) break;
        base += nb;
        doff += (size_t)wL[j] * wK[j] * wN[j];
    }
    int rel = blk - base;
    int K = wK[j], N = wN[j];
    int tk = K / 32, tn = N / 32;
    int l = rel / (tk * tn); rel -= l * tk * tn;
    int kt = rel / tn, nt = rel - (rel / tn) * tn;
    const float* src = jobs.s[j] + (size_t)l * K * N;
    unsigned short* d = dst + doff + (size_t)l * K * N;
    __shared__ float tl[32][33];
    const int c = threadIdx.x & 31, rg = threadIdx.x >> 5;
#pragma unroll
    for (int rr = 0; rr < 4; rr++)
        tl[rg * 4 + rr][c] = src[(size_t)(kt * 32 + rg * 4 + rr) * N + nt * 32 + c];
    __syncthreads();
#pragma unroll
    for (int rr = 0; rr < 4; rr++)
        d[(size_t)(nt * 32 + rg * 4 + rr) * K + kt * 32 + c] = f2bf(tl[c][rg * 4 + rr]);
}

// ---------------------------------------------------------------- init h ----
__global__ __launch_bounds__(256) void init_h_k(const float* __restrict__ x,
                                                float* __restrict__ h)
{
    size_t idx = (size_t)blockIdx.x * 256 + threadIdx.x;   // kROWS*kDM
    int d  = idx & (kDM - 1);
    int t  = (idx >> 9) & (kN - 1);
    int bb = (int)(idx >> 19);
    int b = bb & 3, dir = bb >> 2;
    int ts = dir ? (kN - 1 - t) : t;
    h[idx] = x[((size_t)b * kN + ts) * kDM + d];
}

__global__ __launch_bounds__(256) void h2b_k(const float* __restrict__ h,
                                             unsigned short* __restrict__ o)
{
    size_t idx = (size_t)blockIdx.x * 256 + threadIdx.x;
    o[idx] = f2bf(h[idx]);
}

// ---------------------------------------------------------------- layernorm --
template<int DIM, int OBF>
__global__ __launch_bounds__(256) void ln_k(const float* __restrict__ x,
    const float* __restrict__ wf, const float* __restrict__ wb,
    const float* __restrict__ bf, const float* __restrict__ bbp,
    void* __restrict__ outv)
{
    const int row = blockIdx.x;
    const int tid = threadIdx.x;
    constexpr int PT = DIM / 256;
    const int dir = (row >= kMDIR) ? 1 : 0;
    const float* w = dir ? wb : wf;
    const float* b = dir ? bbp : bf;

    float v[PT];
    float s1 = 0.f, s2 = 0.f;
#pragma unroll
    for (int i = 0; i < PT; i++) {
        float t = x[(size_t)row * DIM + tid + i * 256];
        v[i] = t; s1 += t; s2 += t * t;
    }
    for (int o = 32; o > 0; o >>= 1) { s1 += __shfl_xor(s1, o, 64); s2 += __shfl_xor(s2, o, 64); }
    __shared__ float r1[4], r2[4];
    int wv = tid >> 6;
    if ((tid & 63) == 0) { r1[wv] = s1; r2[wv] = s2; }
    __syncthreads();
    s1 = r1[0] + r1[1] + r1[2] + r1[3];
    s2 = r2[0] + r2[1] + r2[2] + r2[3];
    float mu  = s1 / DIM;
    float var = s2 / DIM - mu * mu;
    float rr  = rsqrtf(var + 1e-5f);
#pragma unroll
    for (int i = 0; i < PT; i++) {
        int c = tid + i * 256;
        float o = (v[i] - mu) * rr * w[c] + b[c];
        if (OBF) ((unsigned short*)outv)[(size_t)row * DIM + c] = f2bf(o);
        else     ((float*)outv)[(size_t)row * DIM + c] = o;
    }
}

// ---------------------------------------------------------------- MFMA GEMM -
// C = A @ B (+bias)(+epilogue). A bf16 [M][lda], B^T bf16 [N][K].
// r18: NTH/WSN template params -- 512-thread (8-wave) blocks for the four
// large GEMMs. R7/R8 counters: OccupancyPercent 18% = ~1.5 waves/SIMD, so
// every lgkm/vmem wait is fully exposed (no co-resident wave to fill the
// bubble); the 2-phase prefetch only covers ~620 of ~900 cyc load latency.
// 8 waves/block at unchanged LDS (64/48 KB -> still 2 blocks/CU) doubles
// TLP to 4 waves/SIMD and halves per-wave acc VGPRs. Same tiles, same
// K-loop, same arithmetic order -> bit-identical output.
template<int BM, int BN, int EPI, int ATR, int MODE, int OBF, int KB,
         int NTH = 256, int WSN = 2>
__global__ __launch_bounds__(NTH) void gemm_mfma(
    const unsigned short* __restrict__ A, int lda, int K,
    const unsigned short* __restrict__ Btf, const unsigned short* __restrict__ Btb,
    const float* __restrict__ biasf, const float* __restrict__ biasb,
    void* __restrict__ Cv, int ldc, unsigned short* __restrict__ Ct)
{
    constexpr int SK  = 40;              // padded LDS row stride (old path)
    constexpr int KT  = KB / 32;         // 32-wide sub-tiles per stage
    constexpr int CPR = KB / 8;          // 8-elem chunks per row (old path)
    constexpr int WAVES = NTH / 64;
    constexpr int WSM = WAVES / WSN;
    constexpr int WM  = BM / WSM, WN = BN / WSN;
    constexpr int MT  = WM / 16, NT = WN / 16;
    constexpr int ASL = (BM * KB) / (NTH * 8);
    constexpr int BSL = (BN * KB) / (NTH * 8);
    constexpr int ABUF = BM * 64;        // one K-tile of A (ushorts)
    constexpr int BBUF = BN * 64;
    constexpr int ASZ = (KB == 64) ? 2 * ABUF : KT * BM * SK;
    constexpr int BSZ = (KB == 64) ? 2 * BBUF : KT * BN * SK;

    __shared__ __align__(16) unsigned short As[ASZ];
    __shared__ __align__(16) unsigned short Bs[BSZ];

    const int tid  = threadIdx.x;
    // ---- XCD swizzle (T1, bijective: nwg % 8 == 0 for every launch here) --
    const int gx   = gridDim.x;
    const int nwg  = gx * gridDim.y;
    const int lin  = blockIdx.x + blockIdx.y * gx;
    const int swz  = (lin & 7) * (nwg >> 3) + (lin >> 3);
    const int by   = swz / gx;
    const int bx   = swz - by * gx;
    const int n0   = bx * BN;
    const int row0 = by * BM;
    const int dir  = (row0 >= kMDIR) ? 1 : 0;
    const unsigned short* __restrict__ Bt = dir ? Btb : Btf;
    const float* bias = dir ? biasb : biasf;

    const int lane = tid & 63;
    const int wave = tid >> 6;
    const int wr = wave / WSN, wc = wave % WSN;
    const int ml = lane & 15, q = lane >> 4;

    f32x4 acc[MT][NT];
#pragma unroll
    for (int i = 0; i < MT; i++)
#pragma unroll
        for (int j = 0; j < NT; j++)
#pragma unroll
            for (int r = 0; r < 4; r++) acc[i][j][r] = 0.f;

    if constexpr (KB == 64) {
        // ---- 2-phase double-buffered DMA K-loop ----
        constexpr int ACW = (BM / 8) / WAVES;   // 1-KB chunks per wave (A)
        constexpr int BCW = (BN / 8) / WAVES;   // 1-KB chunks per wave (B)
        const int lrow = lane >> 3;                       // 0..7 row in chunk
        const int lcol = ((lane & 7) ^ (lrow & 7)) << 4;  // pre-swizzled col byte
        const char* aS[ACW ? ACW : 1];
        const char* bS[BCW ? BCW : 1];
#pragma unroll
        for (int ch = 0; ch < ACW; ch++) {
            const int chunk = wave * ACW + ch;
            aS[ch] = (const char*)A + (size_t)(row0 + chunk * 8 + lrow) * lda * 2 + lcol;
        }
#pragma unroll
        for (int ch = 0; ch < BCW; ch++) {
            const int chunk = wave * BCW + ch;
            bS[ch] = (const char*)Bt + (size_t)(n0 + chunk * 8 + lrow) * K * 2 + lcol;
        }
        const int axor = (ml & 7) << 3;  // read-side swizzle (ushort units)

        auto stage = [&](int buf) {
#pragma unroll
            for (int ch = 0; ch < ACW; ch++) {
                GLD_LDS16(aS[ch], &As[buf * ABUF + (wave * ACW + ch) * 512]);
                aS[ch] += 128;
            }
#pragma unroll
            for (int ch = 0; ch < BCW; ch++) {
                GLD_LDS16(bS[ch], &Bs[buf * BBUF + (wave * BCW + ch) * 512]);
                bS[ch] += 128;
            }
        };

        stage(0);
        __syncthreads();                 // buf0 staged (vmcnt(0) + barrier)
        const int NKT = K >> 6;
        int cur = 0;
        for (int t = 0; t < NKT; t++) {
            if (t + 1 < NKT) stage(cur ^ 1);   // prefetch BEFORE compute
#pragma unroll
            for (int kk = 0; kk < 2; kk++) {
                bf16x8 af[MT], bfr[NT];
#pragma unroll
                for (int i = 0; i < MT; i++)
                    af[i] = *(bf16x8*)&As[cur * ABUF + (wr * WM + i * 16 + ml) * 64 + ((kk * 32 + q * 8) ^ axor)];
#pragma unroll
                for (int j = 0; j < NT; j++)
                    bfr[j] = *(bf16x8*)&Bs[cur * BBUF + (wc * WN + j * 16 + ml) * 64 + ((kk * 32 + q * 8) ^ axor)];
#pragma unroll
                for (int i = 0; i < MT; i++)
#pragma unroll
                    for (int j = 0; j < NT; j++)
                        acc[i][j] = __builtin_amdgcn_mfma_f32_16x16x32_bf16(af[i], bfr[j], acc[i][j], 0, 0, 0);
            }
            __syncthreads();   // per-wave vmcnt(0): next buf staged; lgkm(0): cur reads done
            cur ^= 1;
        }
    } else {
        // ---- old reg-staging path (KB==32: dtw GEMM only, NTH==256) ----
        for (int kt = 0; kt < K; kt += KB) {
            bf16x8 a_ld[ASL ? ASL : 1];
#pragma unroll
            for (int r = 0; r < ASL; r++) {
                int i = tid + r * NTH;
                int m = i / CPR, c8 = (i % CPR) * 8;
                a_ld[r] = *(const bf16x8*)(A + (size_t)(row0 + m) * lda + kt + c8);
            }
            bf16x8 b_ld[BSL ? BSL : 1];
#pragma unroll
            for (int r = 0; r < BSL; r++) {
                int i = tid + r * NTH;
                int n = i / CPR, c8 = (i % CPR) * 8;
                b_ld[r] = *(const bf16x8*)(Bt + (size_t)(n0 + n) * K + kt + c8);
            }
            __syncthreads();
#pragma unroll
            for (int r = 0; r < ASL; r++) {
                int i = tid + r * NTH;
                int m = i / CPR, c8 = (i % CPR) * 8;
                *(bf16x8*)&As[((c8 >> 5) * BM + m) * SK + (c8 & 31)] = a_ld[r];
            }
#pragma unroll
            for (int r = 0; r < BSL; r++) {
                int i = tid + r * NTH;
                int n = i / CPR, c8 = (i % CPR) * 8;
                *(bf16x8*)&Bs[((c8 >> 5) * BN + n) * SK + (c8 & 31)] = b_ld[r];
            }
            __syncthreads();
#pragma unroll
            for (int kk = 0; kk < KT; kk++) {
                bf16x8 af[MT], bfr[NT];
#pragma unroll
                for (int i = 0; i < MT; i++)
                    af[i] = *(bf16x8*)&As[(kk * BM + wr * WM + i * 16 + ml) * SK + q * 8];
#pragma unroll
                for (int j = 0; j < NT; j++)
                    bfr[j] = *(bf16x8*)&Bs[(kk * BN + wc * WN + j * 16 + ml) * SK + q * 8];
#pragma unroll
                for (int i = 0; i < MT; i++)
#pragma unroll
                    for (int j = 0; j < NT; j++)
                        acc[i][j] = __builtin_amdgcn_mfma_f32_16x16x32_bf16(af[i], bfr[j], acc[i][j], 0, 0, 0);
            }
            __syncthreads();
        }
    }

    // ---- epilogue ----
    float* Cf = (float*)Cv;
    unsigned short* Cb = (unsigned short*)Cv;
#pragma unroll
    for (int j = 0; j < NT; j++) {
        int col = n0 + wc * WN + j * 16 + ml;
        float bv = 0.f;
        if (EPI == EPI_SOFTPLUS || EPI == EPI_GELU || EPI == EPI_RESID_BIAS || EPI == EPI_TANH)
            bv = bias[col];
#pragma unroll
        for (int i = 0; i < MT; i++) {
            int rw = row0 + wr * WM + i * 16 + q * 4;
            float v4[4];
#pragma unroll
            for (int r = 0; r < 4; r++) {
                float v = acc[i][j][r] + bv;
                if (EPI == EPI_SOFTPLUS) v = (v > 20.f) ? v : __logf(1.f + __expf(v));
                if (EPI == EPI_GELU)     v = 0.5f * v * (1.f + erf_as(v * 0.70710678118654752f));
                if (EPI == EPI_TANH)     v = tanhf(v);
                v4[r] = v;
            }
            if (MODE == MODE_GATE && n0 >= kDI) {
                // silu(z) -> gate row-major [row][kDI]
#pragma unroll
                for (int r = 0; r < 4; r++) {
                    float sv = v4[r] / (1.f + __expf(-v4[r]));
                    Ct[(size_t)(rw + r) * kDI + (col - kDI)] = f2bf(sv);
                }
            } else {
#pragma unroll
                for (int r = 0; r < 4; r++) {
                    size_t o = (size_t)(rw + r) * ldc + col;
                    if (EPI == EPI_RESID || EPI == EPI_RESID_BIAS) Cf[o] += v4[r];
                    else if (OBF) Cb[o] = f2bf(v4[r]);
                    else Cf[o] = v4[r];
                }
                if (MODE == MODE_DBL && col >= 32) {
                    float* F = (float*)Ct;          // dblF f32 [row][32]
#pragma unroll
                    for (int r = 0; r < 4; r++)
                        F[(size_t)(rw + r) * 32 + (col - 32)] = v4[r];
                }
            }
        }
    }
}

// ---------------------------------------------------------------- conv ------
// xb bf16 [row][kDI] (x-half) -> xh bf16 [row][kDI] = silu(causal conv + cb).
__global__ __launch_bounds__(256) void conv_k(const unsigned short* __restrict__ xb,
    const float* __restrict__ cwf, const float* __restrict__ cwb,
    const float* __restrict__ cbf, const float* __restrict__ cbb,
    unsigned short* __restrict__ xh)
{
    __shared__ float tl[67][33];
    const int t0 = blockIdx.x * 64, d0 = blockIdx.y * 32, bb = blockIdx.z;
    const int dir = bb >> 2;
    const float* cw = dir ? cwb : cwf;
    const float* cb = dir ? cbb : cbf;
    const int dl = threadIdx.x & 31, rl = threadIdx.x >> 5;
    const size_t base = (size_t)bb * kN * kDI + d0 + dl;
#pragma unroll
    for (int p = 0; p < 9; p++) {
        int r = p * 8 + rl;
        if (r < 67) {
            int ts = t0 + r - 3;
            tl[r][dl] = (ts >= 0) ? b2f(xb[base + (size_t)ts * kDI]) : 0.f;
        }
    }
    __syncthreads();
    const int gd = d0 + dl;
    float c0 = cw[gd*4+0], c1 = cw[gd*4+1], c2 = cw[gd*4+2], c3 = cw[gd*4+3];
    float bv = cb[gd];
#pragma unroll
    for (int jj = 0; jj < 8; jj++) {
        int tt = rl + 8 * jj;
        float acc = bv + c0*tl[tt][dl] + c1*tl[tt+1][dl] + c2*tl[tt+2][dl] + c3*tl[tt+3][dl];
        float o = acc / (1.f + __expf(-acc));
        xh[(size_t)(bb * kN + t0 + tt) * kDI + gd] = f2bf(o);
    }
}

// ---------------------------------------------------------------- scan ------
// r14 coalesced blocked scan (validated): h[16]-in-registers 3-pass
// decomposition, all streams [row][d] row-major.
constexpr int kG  = 32;           // groups per chain
constexpr int kTg = kN / kG;      // 32 timesteps per group

template<int PASS>
__global__ __launch_bounds__(256) void bscan_k(
    const unsigned short* __restrict__ dt,   // [row][kDI]
    const unsigned short* __restrict__ xh,   // [row][kDI]
    const unsigned short* __restrict__ gate, // [row][kDI]
    const float* __restrict__ dblF,          // [row][32] (B | C)
    unsigned short* __restrict__ y,          // [row][kDI]
    float* __restrict__ PL,                  // [bb][g][32 slots][kDI]
    const float* __restrict__ alogf, const float* __restrict__ alogb,
    const float* __restrict__ ddf,   const float* __restrict__ ddb)
{
    const int d  = blockIdx.x * 256 + threadIdx.x;   // 0..1023
    const int g  = blockIdx.y;                       // 0..31
    const int bb = blockIdx.z;                       // 0..7
    const int dir = bb >> 2;
    const float* alog = dir ? alogb : alogf;
    const float* ddp  = dir ? ddb  : ddf;

    float a2[16];
#pragma unroll
    for (int s = 0; s < 16; s += 4) {
        float4 al = *(const float4*)&alog[d * kDS + s];
        a2[s+0] = -__expf(al.x) * 1.44269504f;
        a2[s+1] = -__expf(al.y) * 1.44269504f;
        a2[s+2] = -__expf(al.z) * 1.44269504f;
        a2[s+3] = -__expf(al.w) * 1.44269504f;
    }

    const size_t plb = (size_t)(bb * kG + g) * 32 * kDI + d;   // slot stride kDI
    float h[16];
    if (PASS == 0) {
#pragma unroll
        for (int s = 0; s < 16; s++) h[s] = 0.f;
    } else {
#pragma unroll
        for (int s = 0; s < 16; s++) h[s] = PL[plb + (size_t)(16 + s) * kDI];
    }

    const int row0 = bb * kN + g * kTg;
    const unsigned short* pd = dt   + (size_t)row0 * kDI + d;
    const unsigned short* px = xh   + (size_t)row0 * kDI + d;
    const unsigned short* pg = gate + (size_t)row0 * kDI + d;
    const float* pbc = dblF + (size_t)row0 * 32;
    unsigned short* py = y + (size_t)row0 * kDI + d;
    const float ddv = ddp[d];
    float sdt = 0.f;

#pragma unroll 4
    for (int t = 0; t < kTg; t++) {
        float dtv = b2f(pd[(size_t)t * kDI]);
        float xvv = b2f(px[(size_t)t * kDI]);
        float dtx = dtv * xvv;
        const float* bc = pbc + t * 32;
        if (PASS == 0) {
            sdt += dtv;
#pragma unroll
            for (int s4 = 0; s4 < 4; s4++) {
                float4 Bq = *(const float4*)(bc + s4 * 4);
                h[s4*4+0] = __builtin_amdgcn_exp2f(dtv * a2[s4*4+0]) * h[s4*4+0] + dtx * Bq.x;
                h[s4*4+1] = __builtin_amdgcn_exp2f(dtv * a2[s4*4+1]) * h[s4*4+1] + dtx * Bq.y;
                h[s4*4+2] = __builtin_amdgcn_exp2f(dtv * a2[s4*4+2]) * h[s4*4+2] + dtx * Bq.z;
                h[s4*4+3] = __builtin_amdgcn_exp2f(dtv * a2[s4*4+3]) * h[s4*4+3] + dtx * Bq.w;
            }
        } else {
            float p = 0.f;
#pragma unroll
            for (int s4 = 0; s4 < 4; s4++) {
                float4 Bq = *(const float4*)(bc + s4 * 4);
                float4 Cq = *(const float4*)(bc + 16 + s4 * 4);
                h[s4*4+0] = __builtin_amdgcn_exp2f(dtv * a2[s4*4+0]) * h[s4*4+0] + dtx * Bq.x;
                p += h[s4*4+0] * Cq.x;
                h[s4*4+1] = __builtin_amdgcn_exp2f(dtv * a2[s4*4+1]) * h[s4*4+1] + dtx * Bq.y;
                p += h[s4*4+1] * Cq.y;
                h[s4*4+2] = __builtin_amdgcn_exp2f(dtv * a2[s4*4+2]) * h[s4*4+2] + dtx * Bq.z;
                p += h[s4*4+2] * Cq.z;
                h[s4*4+3] = __builtin_amdgcn_exp2f(dtv * a2[s4*4+3]) * h[s4*4+3] + dtx * Bq.w;
                p += h[s4*4+3] * Cq.w;
            }
            float gvv = b2f(pg[(size_t)t * kDI]);
            py[(size_t)t * kDI] = f2bf((p + ddv * xvv) * gvv);
        }
    }

    if (PASS == 0) {
#pragma unroll
        for (int s = 0; s < 16; s++) {
            PL[plb + (size_t)s * kDI]        = __builtin_amdgcn_exp2f(a2[s] * sdt);
            PL[plb + (size_t)(16 + s) * kDI] = h[s];
        }
    }
}

// boundary fix: h_in[chain][g] = scan of (P,L) over groups; rewrites L slot.
__global__ __launch_bounds__(256) void bfix_k(float* __restrict__ PL)
{
    const int idx = blockIdx.x * 256 + threadIdx.x;  // 16 s x 8 bb x 1024 d
    const int d  = idx & (kDI - 1);
    const int bb = (idx >> 10) & 7;
    const int s  = idx >> 13;
    float h = 0.f;
    for (int g = 0; g < kG; g++) {
        size_t base = (size_t)(bb * kG + g) * 32 * kDI + d;
        float P = PL[base + (size_t)s * kDI];
        float L = PL[base + (size_t)(16 + s) * kDI];
        PL[base + (size_t)(16 + s) * kDI] = h;   // h_in for pass C
        h = P * h + L;
    }
}

// ---------------------------------------------------------------- attention -
__global__ __launch_bounds__(64) void att_score_k(const unsigned short* __restrict__ tmp,
    const float* __restrict__ aw2, const float* __restrict__ ab2,
    float* __restrict__ score)
{
    int row = blockIdx.x, lane = threadIdx.x;
    float acc = 0.f;
#pragma unroll
    for (int j = 0; j < 4; j++)
        acc += b2f(tmp[(size_t)row * 256 + lane + j * 64]) * aw2[lane + j * 64];
    for (int o = 32; o > 0; o >>= 1) acc += __shfl_xor(acc, o, 64);
    if (lane == 0) score[row] = acc + ab2[0];
}

__global__ __launch_bounds__(256) void softmax_k(const float* __restrict__ score,
                                                 float* __restrict__ w)
{
    int bb = blockIdx.x, tid = threadIdx.x;
    float v[4]; float m = -1e30f;
#pragma unroll
    for (int i = 0; i < 4; i++) { v[i] = score[bb * kN + tid + i * 256]; m = fmaxf(m, v[i]); }
    for (int o = 32; o > 0; o >>= 1) m = fmaxf(m, __shfl_xor(m, o, 64));
    __shared__ float r1[4], r2[4];
    int wv = tid >> 6;
    if ((tid & 63) == 0) r1[wv] = m;
    __syncthreads();
    m = fmaxf(fmaxf(r1[0], r1[1]), fmaxf(r1[2], r1[3]));
    float s = 0.f;
#pragma unroll
    for (int i = 0; i < 4; i++) { v[i] = __expf(v[i] - m); s += v[i]; }
    for (int o = 32; o > 0; o >>= 1) s += __shfl_xor(s, o, 64);
    if ((tid & 63) == 0) r2[wv] = s;
    __syncthreads();
    s = r2[0] + r2[1] + r2[2] + r2[3];
    float inv = 1.f / s;
#pragma unroll
    for (int i = 0; i < 4; i++) w[bb * kN + tid + i * 256] = v[i] * inv;
}

__global__ __launch_bounds__(512) void pool_k(const float* __restrict__ w,
    const float* __restrict__ h, float* zcat)
{
    int bb = blockIdx.x, chunk = blockIdx.y;   // 8 x 32
    int d = threadIdx.x;
    float acc = 0.f;
    int n0 = chunk * 32;
    for (int n = n0; n < n0 + 32; n++)
        acc += w[bb * kN + n] * h[((size_t)bb * kN + n) * kDM + d];
    int b = bb & 3, dir = bb >> 2;
    atomicAdd(&zcat[b * (2 * kDM) + dir * kDM + d], acc);
}

__global__ __launch_bounds__(256) void att_out_k(const float* __restrict__ w,
                                                 float* __restrict__ out)
{
    int idx = blockIdx.x * 256 + threadIdx.x;  // kB*kN
    int b = idx >> 10, n = idx & 1023;
    out[idx] = 0.5f * (w[b * kN + n] + w[(b + 4) * kN + (kN - 1 - n)]);
}

// ---------------------------------------------------------------- launch ----
extern "C" void kernel_launch(void* const* d_in, const int* in_sizes, int n_in,
                              void* d_out, int out_size, void* d_ws, size_t ws_size,
                              hipStream_t stream)
{
    const float* x = (const float*)d_in[0];
    const float* fp[17]; const float* bp[17];
    for (int i = 0; i < 17; i++) { fp[i] = (const float*)d_in[1 + i]; bp[i] = (const float*)d_in[18 + i]; }
    const float* aw1 = (const float*)d_in[35];
    const float* ab1 = (const float*)d_in[36];
    const float* aw2 = (const float*)d_in[37];
    const float* ab2 = (const float*)d_in[38];
    const float* nw  = (const float*)d_in[39];
    const float* nb  = (const float*)d_in[40];
    float* out = (float*)d_out;

    float* h = (float*)d_ws;                                   // 8192*512 f32
    unsigned short* ub    = (unsigned short*)(h + (size_t)kROWS * kDM);  // 8192*512
    unsigned short* xbuf  = ub    + (size_t)kROWS * kDM;        // 8192*1024 (x-half / y / ffn1 lo)
    unsigned short* tbuf  = xbuf  + (size_t)kROWS * kDI;        // 8192*1024 (dt / ffn1 hi / hb)
    unsigned short* xhb   = tbuf  + (size_t)kROWS * kDI;        // 8192*1024 (xh row-major)
    unsigned short* gateb = xhb   + (size_t)kROWS * kDI;        // 8192*1024 (gate row-major)
    unsigned short* dbl   = gateb + (size_t)kROWS * kDI;        // 8192*64 bf16
    float* dblF  = (float*)(dbl + (size_t)kROWS * 64);          // 8192*32 f32 (B/C)
    float* score = dblF + (size_t)kROWS * 32;                   // 8192
    float* smw   = score + kROWS;                               // 8192
    float* zcat  = smw   + kROWS;                               // 4096
    unsigned short* wts  = (unsigned short*)(zcat + kB * 2 * kDM);
    float* PL = (float*)(wts + O_WTOT);                         // 8*32*32*1024 f32 = 32MB

    // ---- weight prep: fp32 [L][K][N] -> bf16 [L][N][K] (one launch) ----
    WJobs jobs;
    jobs.s[0] = fp[2];  jobs.s[1] = bp[2];
    jobs.s[2] = fp[5];  jobs.s[3] = bp[5];
    jobs.s[4] = fp[6];  jobs.s[5] = bp[6];
    jobs.s[6] = fp[10]; jobs.s[7] = bp[10];
    jobs.s[8] = fp[13]; jobs.s[9] = bp[13];
    jobs.s[10] = fp[15]; jobs.s[11] = bp[15];
    jobs.s[12] = aw1;
    int wblocks = 0;
    {
        const int wK[13] = {512,512,1024,1024,32,32,1024,1024,512,512,2048,2048,512};
        const int wN[13] = {2048,2048,64,64,1024,1024,512,512,2048,2048,512,512,256};
        const int wL[13] = {2,2,2,2,2,2,2,2,2,2,2,2,1};
        for (int j = 0; j < 13; j++) wblocks += wL[j] * (wK[j]/32) * (wN[j]/32);
    }
    wprep_k<<<wblocks, 256, 0, stream>>>(jobs, wts);

    init_h_k<<<kROWS * kDM / 256, 256, 0, stream>>>(x, h);

    for (int l = 0; l < kL; l++) {
        const float *f_n1w = fp[0]  + l * kDM,            *b_n1w = bp[0]  + l * kDM;
        const float *f_n1b = fp[1]  + l * kDM,            *b_n1b = bp[1]  + l * kDM;
        const float *f_cw  = fp[3]  + l * kDI * kDC,      *b_cw  = bp[3]  + l * kDI * kDC;
        const float *f_cb  = fp[4]  + l * kDI,            *b_cb  = bp[4]  + l * kDI;
        const float *f_dtb = fp[7]  + l * kDI,            *b_dtb = bp[7]  + l * kDI;
        const float *f_alog= fp[8]  + l * kDI * kDS,      *b_alog= bp[8]  + l * kDI * kDS;
        const float *f_dd  = fp[9]  + l * kDI,            *b_dd  = bp[9]  + l * kDI;
        const float *f_n2w = fp[11] + l * kDM,            *b_n2w = bp[11] + l * kDM;
        const float *f_n2b = fp[12] + l * kDM,            *b_n2b = bp[12] + l * kDM;
        const float *f_b1  = fp[14] + l * 4 * kDM,        *b_b1  = bp[14] + l * 4 * kDM;
        const float *f_b2  = fp[16] + l * kDM,            *b_b2  = bp[16] + l * kDM;

        const unsigned short *wInwF = wts + O_INW_F + (size_t)l * 2048 * 512;
        const unsigned short *wInwB = wts + O_INW_B + (size_t)l * 2048 * 512;
        const unsigned short *wXpwF = wts + O_XPW_F + (size_t)l * 64 * 1024;
        const unsigned short *wXpwB = wts + O_XPW_B + (size_t)l * 64 * 1024;
        const unsigned short *wDtwF = wts + O_DTW_F + (size_t)l * 1024 * 32;
        const unsigned short *wDtwB = wts + O_DTW_B + (size_t)l * 1024 * 32;
        const unsigned short *wOwF  = wts + O_OW_F  + (size_t)l * 512 * 1024;
        const unsigned short *wOwB  = wts + O_OW_B  + (size_t)l * 512 * 1024;
        const unsigned short *wW1F  = wts + O_W1_F  + (size_t)l * 2048 * 512;
        const unsigned short *wW1B  = wts + O_W1_B  + (size_t)l * 2048 * 512;
        const unsigned short *wW2F  = wts + O_W2_F  + (size_t)l * 512 * 2048;
        const unsigned short *wW2B  = wts + O_W2_B  + (size_t)l * 512 * 2048;

        // u = LN1(h) -> bf16
        ln_k<kDM,1><<<kROWS, 256, 0, stream>>>(h, f_n1w, b_n1w, f_n1b, b_n1b, ub);
        // x-half -> xbuf bf16 [row][kDI]; z-half -> gateb = silu(z) row-major
        // 512-thread / 8-wave blocks (2M x 4N): 4 waves/SIMD at 2 blocks/CU
        gemm_mfma<128,128,EPI_NONE,0,MODE_GATE,1,64,512,4><<<dim3(16, 64), 512, 0, stream>>>(
            ub, kDM, kDM, wInwF, wInwB, nullptr, nullptr, xbuf, kDI, gateb);
        // xh[row][kDI] = silu(conv(xbuf) + cb)  (row-major, no transpose)
        conv_k<<<dim3(kN/64, kDI/32, kB2), 256, 0, stream>>>(
            xbuf, f_cw, b_cw, f_cb, b_cb, xhb);
        // dbl = xh @ xpw (A row-major); cols>=32 also -> dblF f32 [row][32]
        gemm_mfma<32,64,EPI_NONE,0,MODE_DBL,1,64><<<dim3(1, 256), 256, 0, stream>>>(
            xhb, kDI, kDI, wXpwF, wXpwB, nullptr, nullptr, dbl, 64, (unsigned short*)dblF);
        // dt[row][kDI] = softplus(dbl[:, :32] @ dtw + dtb)  (row-major)
        gemm_mfma<128,128,EPI_SOFTPLUS,0,MODE_N,1,32><<<dim3(8, 64), 256, 0, stream>>>(
            dbl, 64, kDTR, wDtwF, wDtwB, f_dtb, b_dtb, tbuf, kDI, nullptr);
        // blocked scan: local pass -> boundary fix -> full pass (y into xbuf)
        bscan_k<0><<<dim3(kDI/256, kG, kB2), 256, 0, stream>>>(
            tbuf, xhb, gateb, dblF, xbuf, PL, f_alog, b_alog, f_dd, b_dd);
        bfix_k<<<kB2 * kDI * kDS / 256, 256, 0, stream>>>(PL);
        bscan_k<1><<<dim3(kDI/256, kG, kB2), 256, 0, stream>>>(
            tbuf, xhb, gateb, dblF, xbuf, PL, f_alog, b_alog, f_dd, b_dd);
        // h += y @ ow  (512-thread / 8-wave blocks, 4M x 2N)
        gemm_mfma<128,64,EPI_RESID,0,MODE_N,0,64,512,2><<<dim3(8, 64), 512, 0, stream>>>(
            xbuf, kDI, kDI, wOwF, wOwB, nullptr, nullptr, h, kDM, nullptr);
        // u = LN2(h) -> bf16
        ln_k<kDM,1><<<kROWS, 256, 0, stream>>>(h, f_n2w, b_n2w, f_n2b, b_n2b, ub);
        // ffn1: gelu(u @ w1 + b1) -> xbuf..tbuf slab bf16 (8192 x 2048)
        gemm_mfma<128,128,EPI_GELU,0,MODE_N,1,64,512,4><<<dim3(16, 64), 512, 0, stream>>>(
            ub, kDM, kDM, wW1F, wW1B, f_b1, b_b1, xbuf, 4*kDM, nullptr);
        // h += ffn1 @ w2 + b2  (512-thread / 8-wave blocks, 4M x 2N)
        gemm_mfma<128,64,EPI_RESID_BIAS,0,MODE_N,0,64,512,2><<<dim3(8, 64), 512, 0, stream>>>(
            xbuf, 4*kDM, 4*kDM, wW2F, wW2B, f_b2, b_b2, h, kDM, nullptr);
    }

    // attention: hb = bf16(h); u = tanh(hb @ aw1 + ab1) bf16
    h2b_k<<<kROWS * kDM / 256, 256, 0, stream>>>(h, tbuf);
    // 64x128 tile -> 256 blocks
    gemm_mfma<64,128,EPI_TANH,0,MODE_N,1,64><<<dim3(2, 128), 256, 0, stream>>>(
        tbuf, kDM, kDM, wts + O_AW1, wts + O_AW1, ab1, ab1, ub, 256, nullptr);
    att_score_k<<<kROWS, 64, 0, stream>>>(ub, aw2, ab2, score);
    softmax_k<<<kB2, 256, 0, stream>>>(score, smw);
    hipMemsetAsync(zcat, 0, kB * 2 * kDM * sizeof(float), stream);
    pool_k<<<dim3(kB2, 32), 512, 0, stream>>>(smw, h, zcat);
    // out[0:4096] = LN(concat(zf, zb))
    ln_k<2*kDM,0><<<kB, 256, 0, stream>>>(zcat, nw, nw, nb, nb, out);
    // out[4096:8192] = 0.5*(af + flip(ab))
    att_out_k<<<kB * kN / 256, 256, 0, stream>>>(smw, out + kB * 2 * kDM);
}